// Round 9
// baseline (2333.936 us; speedup 1.0000x reference)
//
#include <hip/hip_runtime.h>
#include <cstddef>

#define B_    256
#define TSUB  192
#define SEQ_  128
#define D_    768
#define H_    256
#define G_    1024   // 4*H
#define DH_   512    // 2*H

typedef __attribute__((ext_vector_type(4))) float f32x4;
typedef __attribute__((ext_vector_type(8))) short bf16x8;
typedef __attribute__((ext_vector_type(4))) unsigned short u16x4;

__device__ __forceinline__ float rcpf_(float x) { return __builtin_amdgcn_rcpf(x); }
__device__ __forceinline__ float sigf_(float x)  { return rcpf_(1.0f + __expf(-x)); }
__device__ __forceinline__ float tanhf_(float x) { return 1.0f - 2.0f * rcpf_(__expf(2.0f * x) + 1.0f); }

__device__ __forceinline__ unsigned short f2bf_(float x) {
    unsigned u = __builtin_bit_cast(unsigned, x);
    return (unsigned short)((u + 0x7fffu + ((u >> 16) & 1u)) >> 16);
}
__device__ __forceinline__ float bf2f_(unsigned short h) {
    return __builtin_bit_cast(float, (unsigned)h << 16);
}
__device__ __forceinline__ void gload_lds16(const void* g, void* l) {
    __builtin_amdgcn_global_load_lds(
        (const __attribute__((address_space(1))) unsigned int*)g,
        (__attribute__((address_space(3))) unsigned int*)l, 16, 0, 0);
}

// ---------------------------------------------------------------------------
// Kernel 1: scatter-average, fused hi/lo bf16 split.  One block per batch.
// Writes Acat0[M][1536] = [hi(768)|lo(768)] directly.
// ---------------------------------------------------------------------------
__global__ __launch_bounds__(256) void scatter_avg_kernel(
    const float* __restrict__ emb, const int* __restrict__ wid,
    unsigned short* __restrict__ acat)
{
    const int b   = blockIdx.x;
    const int tid = threadIdx.x;
    __shared__ int s_wid[TSUB];
    __shared__ int s_start[SEQ_ + 1];

    for (int i = tid; i < TSUB; i += 256) s_wid[i] = wid[b * TSUB + i];
    __syncthreads();
    for (int s = tid; s <= SEQ_; s += 256) {
        int cnt = 0;
        for (int t = 0; t < TSUB; ++t) cnt += (s_wid[t] < s) ? 1 : 0;
        s_start[s] = cnt;
    }
    __syncthreads();

    const float* eb = emb + (size_t)b * TSUB * D_;
    for (int s = 0; s < SEQ_; ++s) {
        const int st = s_start[s], en = s_start[s + 1];
        const float inv = (en > st) ? 1.0f / (float)(en - st) : 0.0f;
        unsigned short* o = acat + ((size_t)b * SEQ_ + s) * 1536;
        for (int d = tid; d < D_; d += 256) {
            float sum = 0.0f;
            for (int t = st; t < en; ++t) sum += eb[(size_t)t * D_ + d];
            const float x = sum * inv;
            const unsigned short hi = f2bf_(x);
            o[d]       = hi;
            o[768 + d] = f2bf_(x - bf2f_(hi));
        }
    }
}

// ---------------------------------------------------------------------------
// Kernel 2: weight split conversion  f32 W[N][K] -> bf16 Wcat[N][3K]=[hi|lo|hi]
// ---------------------------------------------------------------------------
__global__ __launch_bounds__(256) void convw_kernel(
    const float* __restrict__ W, unsigned short* __restrict__ out, int N, int K)
{
    const int idx = blockIdx.x * 256 + threadIdx.x;
    if (idx >= N * K) return;
    const int n = idx / K, k = idx - n * K;
    const float x = W[idx];
    const unsigned short hi = f2bf_(x);
    const float lo = x - bf2f_(hi);
    const size_t ro = (size_t)n * 3 * K;
    out[ro + k]         = hi;
    out[ro + K + k]     = f2bf_(lo);
    out[ro + 2 * K + k] = hi;
}

// ---------------------------------------------------------------------------
// Kernel 3: bias concat  bcat[n] = b_ih+b_hh for fwd (n<1024) / bwd rows.
// ---------------------------------------------------------------------------
__global__ __launch_bounds__(256) void biascat_kernel(
    const float* __restrict__ bihf, const float* __restrict__ bhhf,
    const float* __restrict__ bihb, const float* __restrict__ bhhb,
    float* __restrict__ o)
{
    const int i = blockIdx.x * 256 + threadIdx.x;   // 0..2047
    o[i] = (i < 1024) ? (bihf[i] + bhhf[i]) : (bihb[i - 1024] + bhhb[i - 1024]);
}

// ---------------------------------------------------------------------------
// Kernel 4: out init with class bias.  out (B,2,SEQ) flat.
// ---------------------------------------------------------------------------
__global__ __launch_bounds__(256) void outinit_kernel(
    const float* __restrict__ b_sbd, float* __restrict__ out)
{
    const int i = blockIdx.x * 256 + threadIdx.x;   // 0..65535
    out[i] = b_sbd[(i >> 7) & 1];
}

// ---------------------------------------------------------------------------
// Kernel 5: bf16 MFMA GEMM, 128x128 tile, BK=64 (32 MFMA per barrier pair),
// global_load_lds width-16.  Split precision:
//   C = act( Acat[M][2K]{hi|lo} x Wcat[N][3K]{hi|lo|hi} + bias )
// A-col mapping (K units!): kw<K -> ka=kw (hi*hi); K<=kw<2K -> ka=kw-K pairs
// Ahi(kw-K)... wait: Wlo cols [K,2K) pair A-HI cols [0,K): ka=kw-K;
// Whi2 cols [2K,3K) pair A-LO cols [K,2K): ka=kw-K.  So ka = kw<K ? kw : kw-K.
// ---------------------------------------------------------------------------
__global__ __launch_bounds__(256) void gemm_bf16_kernel(
    const unsigned short* __restrict__ A, const unsigned short* __restrict__ Wc,
    const float* __restrict__ bias, float* __restrict__ C,
    int M, int N, int K, int relu)
{
    const int KA = 2 * K, KW = 3 * K;
    const int NT64 = (3 * K) >> 6;
    const int n0 = blockIdx.x * 128;
    const int m0 = blockIdx.y * 128;
    const int tid  = threadIdx.x;
    const int wv   = tid >> 6;
    const int lane = tid & 63;
    const int lm   = lane & 15, lk = lane >> 4;
    const int wr   = wv >> 1,   wc = wv & 1;

    __shared__ unsigned short As[128 * 64];   // 16 KB, linear [row][64]
    __shared__ unsigned short Bs[128 * 64];   // 16 KB

    f32x4 acc[4][4];
#pragma unroll
    for (int i = 0; i < 4; ++i)
#pragma unroll
        for (int j = 0; j < 4; ++j) acc[i][j] = (f32x4){0.f, 0.f, 0.f, 0.f};

    for (int kt = 0; kt < NT64; ++kt) {
        const int kw = kt << 6;
        const int ka = (kw < K) ? kw : kw - K;   // <-- FIXED (was kw-2K pairing)
        __syncthreads();   // previous tile fully consumed
#pragma unroll
        for (int l = 0; l < 4; ++l) {
            const int e   = l * 256 + tid;     // 0..1023
            const int row = e >> 3;            // 0..127
            const int c8  = (e & 7) * 8;       // halfword col
            gload_lds16(A  + (size_t)(m0 + row) * KA + ka + c8, As + e * 8);
            gload_lds16(Wc + (size_t)(n0 + row) * KW + kw + c8, Bs + e * 8);
        }
        __syncthreads();   // staging complete

#pragma unroll
        for (int kh = 0; kh < 2; ++kh) {
            bf16x8 af[4], bfr[4];
#pragma unroll
            for (int mi = 0; mi < 4; ++mi)
                af[mi] = *(const bf16x8*)&As[(wr * 64 + mi * 16 + lm) * 64 + kh * 32 + lk * 8];
#pragma unroll
            for (int nj = 0; nj < 4; ++nj)
                bfr[nj] = *(const bf16x8*)&Bs[(wc * 64 + nj * 16 + lm) * 64 + kh * 32 + lk * 8];
#pragma unroll
            for (int mi = 0; mi < 4; ++mi)
#pragma unroll
                for (int nj = 0; nj < 4; ++nj)
                    acc[mi][nj] = __builtin_amdgcn_mfma_f32_16x16x32_bf16(
                        af[mi], bfr[nj], acc[mi][nj], 0, 0, 0);
        }
    }

#pragma unroll
    for (int mi = 0; mi < 4; ++mi)
#pragma unroll
        for (int nj = 0; nj < 4; ++nj) {
            const int gn = n0 + wc * 64 + nj * 16 + lm;
            const float bv = bias[gn];
#pragma unroll
            for (int r = 0; r < 4; ++r) {
                const int gm = m0 + wr * 64 + mi * 16 + lk * 4 + r;
                float v = acc[mi][nj][r] + bv;
                if (relu) v = fmaxf(v, 0.0f);
                C[(size_t)gm * N + gn] = v;
            }
        }
}

// ---------------------------------------------------------------------------
// Kernel 6: FF GEMM with FUSED logits epilogue.  Same GEMM body; instead of
// storing C, each block computes relu(C+b_ff) and reduces row x w_sbd over
// its 128-col n-range (16-lane shuffle groups), atomicAdd into out.
// out pre-initialized with b_sbd by outinit_kernel.
// ---------------------------------------------------------------------------
__global__ __launch_bounds__(256) void gemm_ff_logits_kernel(
    const unsigned short* __restrict__ A, const unsigned short* __restrict__ Wc,
    const float* __restrict__ bias, const float* __restrict__ w_sbd,
    float* __restrict__ out, int M, int N, int K)
{
    const int KA = 2 * K, KW = 3 * K;
    const int NT64 = (3 * K) >> 6;
    const int n0 = blockIdx.x * 128;
    const int m0 = blockIdx.y * 128;
    const int tid  = threadIdx.x;
    const int wv   = tid >> 6;
    const int lane = tid & 63;
    const int lm   = lane & 15, lk = lane >> 4;
    const int wr   = wv >> 1,   wc = wv & 1;

    __shared__ unsigned short As[128 * 64];
    __shared__ unsigned short Bs[128 * 64];

    f32x4 acc[4][4];
#pragma unroll
    for (int i = 0; i < 4; ++i)
#pragma unroll
        for (int j = 0; j < 4; ++j) acc[i][j] = (f32x4){0.f, 0.f, 0.f, 0.f};

    for (int kt = 0; kt < NT64; ++kt) {
        const int kw = kt << 6;
        const int ka = (kw < K) ? kw : kw - K;   // <-- FIXED
        __syncthreads();
#pragma unroll
        for (int l = 0; l < 4; ++l) {
            const int e   = l * 256 + tid;
            const int row = e >> 3;
            const int c8  = (e & 7) * 8;
            gload_lds16(A  + (size_t)(m0 + row) * KA + ka + c8, As + e * 8);
            gload_lds16(Wc + (size_t)(n0 + row) * KW + kw + c8, Bs + e * 8);
        }
        __syncthreads();

#pragma unroll
        for (int kh = 0; kh < 2; ++kh) {
            bf16x8 af[4], bfr[4];
#pragma unroll
            for (int mi = 0; mi < 4; ++mi)
                af[mi] = *(const bf16x8*)&As[(wr * 64 + mi * 16 + lm) * 64 + kh * 32 + lk * 8];
#pragma unroll
            for (int nj = 0; nj < 4; ++nj)
                bfr[nj] = *(const bf16x8*)&Bs[(wc * 64 + nj * 16 + lm) * 64 + kh * 32 + lk * 8];
#pragma unroll
            for (int mi = 0; mi < 4; ++mi)
#pragma unroll
                for (int nj = 0; nj < 4; ++nj)
                    acc[mi][nj] = __builtin_amdgcn_mfma_f32_16x16x32_bf16(
                        af[mi], bfr[nj], acc[mi][nj], 0, 0, 0);
        }
    }

    // epilogue: relu + logits partial over this block's 128 n-cols
#pragma unroll
    for (int mi = 0; mi < 4; ++mi) {
        float ls0[4] = {0.f, 0.f, 0.f, 0.f};
        float ls1[4] = {0.f, 0.f, 0.f, 0.f};
#pragma unroll
        for (int nj = 0; nj < 4; ++nj) {
            const int gn = n0 + wc * 64 + nj * 16 + lm;
            const float bv = bias[gn];
            const float w0 = w_sbd[gn];
            const float w1 = w_sbd[512 + gn];
#pragma unroll
            for (int r = 0; r < 4; ++r) {
                const float v = fmaxf(acc[mi][nj][r] + bv, 0.0f);
                ls0[r] += v * w0;
                ls1[r] += v * w1;
            }
        }
#pragma unroll
        for (int r = 0; r < 4; ++r) {
            float v0 = ls0[r], v1 = ls1[r];
#pragma unroll
            for (int msk = 1; msk < 16; msk <<= 1) {
                v0 += __shfl_xor(v0, msk);
                v1 += __shfl_xor(v1, msk);
            }
            if (lm == 0) {
                const int gm = m0 + wr * 64 + mi * 16 + lk * 4 + r;
                const int base = (gm >> 7) * 256 + (gm & 127);
                atomicAdd(&out[base], v0);
                atomicAdd(&out[base + 128], v1);
            }
        }
    }
}

// ---------------------------------------------------------------------------
// Kernel 7: swizzle four w_hh (1024x256 f32) into bf16 MFMA A-fragment order
// for the 8-wave LSTM.  [mat][wv 8][kt 8][fr 8][lane 64][e 8]
//   fr = g*2+s:  n = g*256 + wv*32 + s*16 + (lane&15)
//   k  = kt*32 + (lane>>4)*8 + e
// ---------------------------------------------------------------------------
__global__ __launch_bounds__(256) void wswz_kernel(
    const float* __restrict__ w0, const float* __restrict__ w1,
    const float* __restrict__ w2, const float* __restrict__ w3,
    short* __restrict__ out)
{
    const int idx  = blockIdx.x * 256 + threadIdx.x;    // 4*262144
    const int mat  = idx >> 18;
    const int i2   = idx & 262143;
    const int e    = i2 & 7;
    const int l    = (i2 >> 3) & 63;
    const int fr   = (i2 >> 9) & 7;
    const int kt   = (i2 >> 12) & 7;
    const int wv   = (i2 >> 15) & 7;
    const int g    = fr >> 1, s = fr & 1;
    const int n    = g * 256 + wv * 32 + s * 16 + (l & 15);
    const int k    = kt * 32 + ((l >> 4) << 3) + e;
    const float* w = (mat == 0) ? w0 : (mat == 1) ? w1 : (mat == 2) ? w2 : w3;
    out[idx] = (short)f2bf_(w[n * H_ + k]);
}

// ---------------------------------------------------------------------------
// Kernel 8: persistent bidirectional LSTM, bf16 MFMA, WEIGHT-RESIDENT,
// double-buffered h + single LDS-only barrier per step (r7-verified).
// xp read from merged xp_cat[M][2048] (dir*1024 offset).
// h written directly as Acat hi/lo bf16 into hcat[M][1024] = [hi512|lo512].
// ---------------------------------------------------------------------------
__global__ __launch_bounds__(512, 2) void lstm_kernel(
    const float* __restrict__ xpc,
    const short* __restrict__ wswf, const short* __restrict__ wswb,
    unsigned short* __restrict__ hcat)
{
    const int dir  = blockIdx.x >> 4;
    const int grp  = blockIdx.x & 15;
    const int tid  = threadIdx.x;
    const int wv   = tid >> 6;          // wave 0..7
    const int lane = tid & 63;
    const int lm   = lane & 15;
    const int lk   = lane >> 4;
    const float* xp  = xpc + dir * 1024;
    const short* wsw = dir ? wswb : wswf;
    const int b0 = grp * 16;
    const int b  = lm;                  // this lane's batch column

    __shared__ short lds_w[65536];      // 128 KB: [wv 8][kt2 2][fr 8][512]
    __shared__ short h_lds[2][16 * 256];// 2 x 8 KB, [b][k] bf16, XOR-swizzled

    // ---- one-time staging --------------------------------------------------
    for (int i = tid; i < 16 * 256 / 2; i += 512) ((int*)h_lds[0])[i] = 0;
#pragma unroll
    for (int kt2 = 0; kt2 < 2; ++kt2)
#pragma unroll
        for (int fr = 0; fr < 8; ++fr) {
            const short* src = wsw + (((wv * 8 + 4 + kt2) * 8 + fr) << 9) + lane * 8;
            gload_lds16(src, &lds_w[((wv * 2 + kt2) * 8 + fr) << 9]);
        }
    bf16x8 awr[4][8];
#pragma unroll
    for (int kt = 0; kt < 4; ++kt)
#pragma unroll
        for (int fr = 0; fr < 8; ++fr)
            awr[kt][fr] = *(const bf16x8*)(wsw + (((wv * 8 + kt) * 8 + fr) << 9) + lane * 8);

    float c_st[2][4];
#pragma unroll
    for (int s = 0; s < 2; ++s)
#pragma unroll
        for (int r = 0; r < 4; ++r) c_st[s][r] = 0.0f;

    int nof[8];
#pragma unroll
    for (int fr = 0; fr < 8; ++fr)
        nof[fr] = (fr >> 1) * 256 + wv * 32 + (fr & 1) * 16 + lk * 4;

    __syncthreads();   // one-time: full drain ok

    // prefetch xp for step 0
    f32x4 xpre[8];
    {
        const int t0 = dir ? (SEQ_ - 1) : 0;
        const float* xr = xp + ((size_t)(b0 + b) * SEQ_ + t0) * 2048;
#pragma unroll
        for (int fr = 0; fr < 8; ++fr) xpre[fr] = *(const f32x4*)(xr + nof[fr]);
    }

    int cur = 0;
    for (int step = 0; step < SEQ_; ++step) {
        const int t = dir ? (SEQ_ - 1 - step) : step;
        const char* hr = (const char*)h_lds[0] + cur * 8192;
        char*       hw = (char*)h_lds[0] + (cur ^ 1) * 8192;

        f32x4 acc[8];
#pragma unroll
        for (int fr = 0; fr < 8; ++fr) acc[fr] = xpre[fr];

        // issue streamed kt=6 loads now
        bf16x8 aws6[8];
#pragma unroll
        for (int fr = 0; fr < 8; ++fr)
            aws6[fr] = *(const bf16x8*)(wsw + (((wv * 8 + 6) * 8 + fr) << 9) + lane * 8);

        // kt 0..3: register-resident weights
#pragma unroll
        for (int kt = 0; kt < 4; ++kt) {
            const int off = b * 512 + (((kt * 32 + lk * 8) * 2) ^ ((b & 7) << 4));
            const bf16x8 bh = *(const bf16x8*)(hr + off);
#pragma unroll
            for (int fr = 0; fr < 8; ++fr)
                acc[fr] = __builtin_amdgcn_mfma_f32_16x16x32_bf16(
                    awr[kt][fr], bh, acc[fr], 0, 0, 0);
        }

        // kt 4..5: LDS-resident weights
#pragma unroll
        for (int kt2 = 0; kt2 < 2; ++kt2) {
            const int kt = 4 + kt2;
            const int off = b * 512 + (((kt * 32 + lk * 8) * 2) ^ ((b & 7) << 4));
            const bf16x8 bh = *(const bf16x8*)(hr + off);
            bf16x8 al[8];
#pragma unroll
            for (int fr = 0; fr < 8; ++fr)
                al[fr] = *(const bf16x8*)&lds_w[(((wv * 2 + kt2) * 8 + fr) << 9) + lane * 8];
#pragma unroll
            for (int fr = 0; fr < 8; ++fr)
                acc[fr] = __builtin_amdgcn_mfma_f32_16x16x32_bf16(
                    al[fr], bh, acc[fr], 0, 0, 0);
        }

        // issue streamed kt=7 loads
        bf16x8 aws7[8];
#pragma unroll
        for (int fr = 0; fr < 8; ++fr)
            aws7[fr] = *(const bf16x8*)(wsw + (((wv * 8 + 7) * 8 + fr) << 9) + lane * 8);

        // kt 6
        {
            const int off = b * 512 + (((6 * 32 + lk * 8) * 2) ^ ((b & 7) << 4));
            const bf16x8 bh = *(const bf16x8*)(hr + off);
#pragma unroll
            for (int fr = 0; fr < 8; ++fr)
                acc[fr] = __builtin_amdgcn_mfma_f32_16x16x32_bf16(
                    aws6[fr], bh, acc[fr], 0, 0, 0);
        }
        // kt 7
        {
            const int off = b * 512 + (((7 * 32 + lk * 8) * 2) ^ ((b & 7) << 4));
            const bf16x8 bh = *(const bf16x8*)(hr + off);
#pragma unroll
            for (int fr = 0; fr < 8; ++fr)
                acc[fr] = __builtin_amdgcn_mfma_f32_16x16x32_bf16(
                    aws7[fr], bh, acc[fr], 0, 0, 0);
        }

        // prefetch xp for next step (in flight across the barrier)
        {
            const int tn = dir ? (t > 0 ? t - 1 : 0) : (t < SEQ_ - 1 ? t + 1 : t);
            const float* xr = xp + ((size_t)(b0 + b) * SEQ_ + tn) * 2048;
#pragma unroll
            for (int fr = 0; fr < 8; ++fr) xpre[fr] = *(const f32x4*)(xr + nof[fr]);
        }

        // pointwise: fr=g*2+s -> i:acc[s], f:acc[2+s], g:acc[4+s], o:acc[6+s]
#pragma unroll
        for (int s = 0; s < 2; ++s) {
            u16x4 hb, hl;
#pragma unroll
            for (int r = 0; r < 4; ++r) {
                const float iv = sigf_(acc[s][r]);
                const float fv = sigf_(acc[2 + s][r]);
                const float gv = tanhf_(acc[4 + s][r]);
                const float ov = sigf_(acc[6 + s][r]);
                const float c  = fv * c_st[s][r] + iv * gv;
                c_st[s][r] = c;
                const float h  = ov * tanhf_(c);
                hb[r] = f2bf_(h);
                hl[r] = f2bf_(h - bf2f_(hb[r]));
            }
            const int j0  = wv * 32 + s * 16 + lk * 4;
            const int off = b * 512 + ((j0 * 2) ^ ((b & 7) << 4));
            *(u16x4*)(hw + off) = hb;
            unsigned short* hp = hcat + ((size_t)(b0 + b) * SEQ_ + t) * 1024 + dir * 256 + j0;
            *(u16x4*)hp         = hb;
            *(u16x4*)(hp + 512) = hl;
        }

        // single per-step barrier: LDS-only drain; vmem stays in flight
        asm volatile("s_waitcnt lgkmcnt(0)" ::: "memory");
        __builtin_amdgcn_s_barrier();
        cur ^= 1;
    }
}

// ---------------------------------------------------------------------------
extern "C" void kernel_launch(void* const* d_in, const int* in_sizes, int n_in,
                              void* d_out, int out_size, void* d_ws, size_t ws_size,
                              hipStream_t stream)
{
    const float* emb   = (const float*)d_in[0];
    const int*   wid   = (const int*)d_in[1];
    const float* w_ih[4] = {(const float*)d_in[2],  (const float*)d_in[6],
                            (const float*)d_in[10], (const float*)d_in[14]};
    const float* w_hh[4] = {(const float*)d_in[3],  (const float*)d_in[7],
                            (const float*)d_in[11], (const float*)d_in[15]};
    const float* b_ih[4] = {(const float*)d_in[4],  (const float*)d_in[8],
                            (const float*)d_in[12], (const float*)d_in[16]};
    const float* b_hh[4] = {(const float*)d_in[5],  (const float*)d_in[9],
                            (const float*)d_in[13], (const float*)d_in[17]};
    const float* w_ff  = (const float*)d_in[18];
    const float* b_ff  = (const float*)d_in[19];
    const float* w_sbd = (const float*)d_in[20];
    const float* b_sbd = (const float*)d_in[21];
    float* out = (float*)d_out;
    char*  ws  = (char*)d_ws;

    const int M = B_ * SEQ_;   // 32768

    // ---- workspace layout (bytes) ------------------------------------------
    const size_t OFF_R1  = 0;                       // Acat0 (100.7MB) -> hcat (67MB)
    const size_t OFF_XP  = 100663296;               // xp_cat [M][2048] f32 = 268.4MB
    const size_t OFF_WC  = OFF_XP + 268435456;      // Wcat pool 17.3MB
    const size_t OFF_WSW = OFF_WC + 17301504;       // 2MB swizzled w_hh
    const size_t OFF_BC  = OFF_WSW + 2097152;       // 2x2048 f32 bias concat

    unsigned short* Acat0 = (unsigned short*)(ws + OFF_R1);
    unsigned short* hcat  = (unsigned short*)(ws + OFF_R1);
    float* xpc  = (float*)(ws + OFF_XP);
    unsigned short* Wc0  = (unsigned short*)(ws + OFF_WC);              // 2048x2304
    unsigned short* Wc1  = Wc0 + (size_t)2048 * 2304;                   // 2048x1536
    unsigned short* Wcff = Wc1 + (size_t)2048 * 1536;                   // 512x1536
    short* wsw  = (short*)(ws + OFF_WSW);
    float* bc0  = (float*)(ws + OFF_BC);
    float* bc1  = bc0 + 2048;

    // ---- weight/bias conversions (independent of data path) ----------------
    wswz_kernel<<<4096, 256, 0, stream>>>(w_hh[0], w_hh[1], w_hh[2], w_hh[3], wsw);
    convw_kernel<<<(1024 * 768 + 255) / 256, 256, 0, stream>>>(w_ih[0], Wc0, 1024, 768);
    convw_kernel<<<(1024 * 768 + 255) / 256, 256, 0, stream>>>(w_ih[1], Wc0 + (size_t)1024 * 2304, 1024, 768);
    convw_kernel<<<(1024 * 512 + 255) / 256, 256, 0, stream>>>(w_ih[2], Wc1, 1024, 512);
    convw_kernel<<<(1024 * 512 + 255) / 256, 256, 0, stream>>>(w_ih[3], Wc1 + (size_t)1024 * 1536, 1024, 512);
    convw_kernel<<<(512 * 512 + 255) / 256, 256, 0, stream>>>(w_ff, Wcff, 512, 512);
    biascat_kernel<<<8, 256, 0, stream>>>(b_ih[0], b_hh[0], b_ih[1], b_hh[1], bc0);
    biascat_kernel<<<8, 256, 0, stream>>>(b_ih[2], b_hh[2], b_ih[3], b_hh[3], bc1);
    outinit_kernel<<<256, 256, 0, stream>>>(b_sbd, out);

    // ---- data path ----------------------------------------------------------
    scatter_avg_kernel<<<B_, 256, 0, stream>>>(emb, wid, Acat0);

    // layer-0 merged projection: [M][2048] = Acat0 x [Wc0f|Wc0b]
    gemm_bf16_kernel<<<dim3(2048 / 128, M / 128), 256, 0, stream>>>(
        Acat0, Wc0, bc0, xpc, M, 2048, 768, 0);

    lstm_kernel<<<32, 512, 0, stream>>>(xpc, wsw, wsw + 262144, hcat);

    // layer-1 merged projection
    gemm_bf16_kernel<<<dim3(2048 / 128, M / 128), 256, 0, stream>>>(
        hcat, Wc1, bc1, xpc, M, 2048, 512, 0);

    lstm_kernel<<<32, 512, 0, stream>>>(xpc, wsw + 2 * 262144, wsw + 3 * 262144, hcat);

    // FF + fused logits
    gemm_ff_logits_kernel<<<dim3(512 / 128, M / 128), 256, 0, stream>>>(
        hcat, Wcff, b_ff, w_sbd, out, M, 512, 512);
}

// Round 10
// 2069.070 us; speedup vs baseline: 1.1280x; 1.1280x over previous
//
#include <hip/hip_runtime.h>
#include <cstddef>

#define B_    256
#define TSUB  192
#define SEQ_  128
#define D_    768
#define H_    256
#define G_    1024   // 4*H
#define DH_   512    // 2*H

typedef __attribute__((ext_vector_type(4))) float f32x4;
typedef __attribute__((ext_vector_type(8))) short bf16x8;
typedef __attribute__((ext_vector_type(4))) unsigned short u16x4;

__device__ __forceinline__ float rcpf_(float x) { return __builtin_amdgcn_rcpf(x); }
__device__ __forceinline__ float sigf_(float x)  { return rcpf_(1.0f + __expf(-x)); }
__device__ __forceinline__ float tanhf_(float x) { return 1.0f - 2.0f * rcpf_(__expf(2.0f * x) + 1.0f); }

__device__ __forceinline__ unsigned short f2bf_(float x) {
    unsigned u = __builtin_bit_cast(unsigned, x);
    return (unsigned short)((u + 0x7fffu + ((u >> 16) & 1u)) >> 16);
}
__device__ __forceinline__ float bf2f_(unsigned short h) {
    return __builtin_bit_cast(float, (unsigned)h << 16);
}
__device__ __forceinline__ void gload_lds16(const void* g, void* l) {
    __builtin_amdgcn_global_load_lds(
        (const __attribute__((address_space(1))) unsigned int*)g,
        (__attribute__((address_space(3))) unsigned int*)l, 16, 0, 0);
}

// ---------------------------------------------------------------------------
// Kernel 1: scatter-average, fused hi/lo bf16 split.  One block per batch.
// Writes Acat0[M][1536] = [hi(768)|lo(768)] directly.
// ---------------------------------------------------------------------------
__global__ __launch_bounds__(256) void scatter_avg_kernel(
    const float* __restrict__ emb, const int* __restrict__ wid,
    unsigned short* __restrict__ acat)
{
    const int b   = blockIdx.x;
    const int tid = threadIdx.x;
    __shared__ int s_wid[TSUB];
    __shared__ int s_start[SEQ_ + 1];

    for (int i = tid; i < TSUB; i += 256) s_wid[i] = wid[b * TSUB + i];
    __syncthreads();
    for (int s = tid; s <= SEQ_; s += 256) {
        int cnt = 0;
        for (int t = 0; t < TSUB; ++t) cnt += (s_wid[t] < s) ? 1 : 0;
        s_start[s] = cnt;
    }
    __syncthreads();

    const float* eb = emb + (size_t)b * TSUB * D_;
    for (int s = 0; s < SEQ_; ++s) {
        const int st = s_start[s], en = s_start[s + 1];
        const float inv = (en > st) ? 1.0f / (float)(en - st) : 0.0f;
        unsigned short* o = acat + ((size_t)b * SEQ_ + s) * 1536;
        for (int d = tid; d < D_; d += 256) {
            float sum = 0.0f;
            for (int t = st; t < en; ++t) sum += eb[(size_t)t * D_ + d];
            const float x = sum * inv;
            const unsigned short hi = f2bf_(x);
            o[d]       = hi;
            o[768 + d] = f2bf_(x - bf2f_(hi));
        }
    }
}

// ---------------------------------------------------------------------------
// Kernel 2: weight split conversion  f32 W[N][K] -> bf16 Wcat[N][terms*K]
//   terms=3: [hi|lo|hi]  (pairs Ahi,Ahi,Alo)   terms=2: [hi|lo] (pairs Ahi,Ahi)
// ---------------------------------------------------------------------------
__global__ __launch_bounds__(256) void convw_kernel(
    const float* __restrict__ W, unsigned short* __restrict__ out,
    int N, int K, int terms)
{
    const int idx = blockIdx.x * 256 + threadIdx.x;
    if (idx >= N * K) return;
    const int n = idx / K, k = idx - n * K;
    const float x = W[idx];
    const unsigned short hi = f2bf_(x);
    const float lo = x - bf2f_(hi);
    const size_t ro = (size_t)n * terms * K;
    out[ro + k]     = hi;
    out[ro + K + k] = f2bf_(lo);
    if (terms == 3) out[ro + 2 * K + k] = hi;
}

// ---------------------------------------------------------------------------
// Kernel 3: bias concat  bcat[n] = b_ih+b_hh for fwd (n<1024) / bwd rows.
// ---------------------------------------------------------------------------
__global__ __launch_bounds__(256) void biascat_kernel(
    const float* __restrict__ bihf, const float* __restrict__ bhhf,
    const float* __restrict__ bihb, const float* __restrict__ bhhb,
    float* __restrict__ o)
{
    const int i = blockIdx.x * 256 + threadIdx.x;   // 0..2047
    o[i] = (i < 1024) ? (bihf[i] + bhhf[i]) : (bihb[i - 1024] + bhhb[i - 1024]);
}

// ---------------------------------------------------------------------------
// Kernel 4: out init with class bias.  out (B,2,SEQ) flat.
// ---------------------------------------------------------------------------
__global__ __launch_bounds__(256) void outinit_kernel(
    const float* __restrict__ b_sbd, float* __restrict__ out)
{
    const int i = blockIdx.x * 256 + threadIdx.x;   // 0..65535
    out[i] = b_sbd[(i >> 7) & 1];
}

// ---------------------------------------------------------------------------
// Kernel 5: bf16 MFMA GEMM, 128x128 tile, BK=64, global_load_lds width-16,
// XCD-swizzled 1D grid (nwg % 8 == 0).  Split precision:
//   C = act( A[M][KA] x Wcat[N][KW] + bias ),  ka = kw<K ? kw : kw-K.
// 3-term (KA=2K): Ahi*Whi + Ahi*Wlo + Alo*Whi.  2-term (KA=K): Ahi*(Whi+Wlo).
// ---------------------------------------------------------------------------
__global__ __launch_bounds__(256) void gemm_bf16_kernel(
    const unsigned short* __restrict__ A, const unsigned short* __restrict__ Wc,
    const float* __restrict__ bias, float* __restrict__ C,
    int M, int N, int K, int KA, int relu)
{
    const int KW = (gridDim.x, 0) ? 0 : 0;  // placeholder removed below
    (void)KW;
    const int KWr  = (KA == K) ? 2 * K : 3 * K;
    const int NT64 = KWr >> 6;
    const int ntn  = N >> 7;
    // XCD-aware swizzle: consecutive physical blocks on one XCD cover
    // consecutive swz ids -> same m-panel reused from that XCD's L2.
    const int id  = blockIdx.x;
    const int cpx = gridDim.x >> 3;
    const int swz = (id & 7) * cpx + (id >> 3);
    const int m0  = (swz / ntn) * 128;
    const int n0  = (swz % ntn) * 128;

    const int tid  = threadIdx.x;
    const int wv   = tid >> 6;
    const int lane = tid & 63;
    const int lm   = lane & 15, lk = lane >> 4;
    const int wr   = wv >> 1,   wc = wv & 1;

    __shared__ unsigned short As[128 * 64];   // 16 KB, linear [row][64]
    __shared__ unsigned short Bs[128 * 64];   // 16 KB

    f32x4 acc[4][4];
#pragma unroll
    for (int i = 0; i < 4; ++i)
#pragma unroll
        for (int j = 0; j < 4; ++j) acc[i][j] = (f32x4){0.f, 0.f, 0.f, 0.f};

    for (int kt = 0; kt < NT64; ++kt) {
        const int kw = kt << 6;
        const int ka = (kw < K) ? kw : kw - K;
        __syncthreads();   // previous tile fully consumed
#pragma unroll
        for (int l = 0; l < 4; ++l) {
            const int e   = l * 256 + tid;     // 0..1023
            const int row = e >> 3;            // 0..127
            const int c8  = (e & 7) * 8;       // halfword col
            gload_lds16(A  + (size_t)(m0 + row) * KA  + ka + c8, As + e * 8);
            gload_lds16(Wc + (size_t)(n0 + row) * KWr + kw + c8, Bs + e * 8);
        }
        __syncthreads();   // staging complete

#pragma unroll
        for (int kh = 0; kh < 2; ++kh) {
            bf16x8 af[4], bfr[4];
#pragma unroll
            for (int mi = 0; mi < 4; ++mi)
                af[mi] = *(const bf16x8*)&As[(wr * 64 + mi * 16 + lm) * 64 + kh * 32 + lk * 8];
#pragma unroll
            for (int nj = 0; nj < 4; ++nj)
                bfr[nj] = *(const bf16x8*)&Bs[(wc * 64 + nj * 16 + lm) * 64 + kh * 32 + lk * 8];
#pragma unroll
            for (int mi = 0; mi < 4; ++mi)
#pragma unroll
                for (int nj = 0; nj < 4; ++nj)
                    acc[mi][nj] = __builtin_amdgcn_mfma_f32_16x16x32_bf16(
                        af[mi], bfr[nj], acc[mi][nj], 0, 0, 0);
        }
    }

#pragma unroll
    for (int mi = 0; mi < 4; ++mi)
#pragma unroll
        for (int nj = 0; nj < 4; ++nj) {
            const int gn = n0 + wc * 64 + nj * 16 + lm;
            const float bv = bias[gn];
#pragma unroll
            for (int r = 0; r < 4; ++r) {
                const int gm = m0 + wr * 64 + mi * 16 + lk * 4 + r;
                float v = acc[mi][nj][r] + bv;
                if (relu) v = fmaxf(v, 0.0f);
                C[(size_t)gm * N + gn] = v;
            }
        }
}

// ---------------------------------------------------------------------------
// Kernel 6: FF GEMM (2-term, KA=K=512) with FUSED logits epilogue.
// ---------------------------------------------------------------------------
__global__ __launch_bounds__(256) void gemm_ff_logits_kernel(
    const unsigned short* __restrict__ A, const unsigned short* __restrict__ Wc,
    const float* __restrict__ bias, const float* __restrict__ w_sbd,
    float* __restrict__ out, int M, int N, int K)
{
    const int KA = K, KW = 2 * K;
    const int NT64 = KW >> 6;
    const int ntn  = N >> 7;
    const int id  = blockIdx.x;
    const int cpx = gridDim.x >> 3;
    const int swz = (id & 7) * cpx + (id >> 3);
    const int m0  = (swz / ntn) * 128;
    const int n0  = (swz % ntn) * 128;

    const int tid  = threadIdx.x;
    const int wv   = tid >> 6;
    const int lane = tid & 63;
    const int lm   = lane & 15, lk = lane >> 4;
    const int wr   = wv >> 1,   wc = wv & 1;

    __shared__ unsigned short As[128 * 64];
    __shared__ unsigned short Bs[128 * 64];

    f32x4 acc[4][4];
#pragma unroll
    for (int i = 0; i < 4; ++i)
#pragma unroll
        for (int j = 0; j < 4; ++j) acc[i][j] = (f32x4){0.f, 0.f, 0.f, 0.f};

    for (int kt = 0; kt < NT64; ++kt) {
        const int kw = kt << 6;
        const int ka = (kw < K) ? kw : kw - K;
        __syncthreads();
#pragma unroll
        for (int l = 0; l < 4; ++l) {
            const int e   = l * 256 + tid;
            const int row = e >> 3;
            const int c8  = (e & 7) * 8;
            gload_lds16(A  + (size_t)(m0 + row) * KA + ka + c8, As + e * 8);
            gload_lds16(Wc + (size_t)(n0 + row) * KW + kw + c8, Bs + e * 8);
        }
        __syncthreads();

#pragma unroll
        for (int kh = 0; kh < 2; ++kh) {
            bf16x8 af[4], bfr[4];
#pragma unroll
            for (int mi = 0; mi < 4; ++mi)
                af[mi] = *(const bf16x8*)&As[(wr * 64 + mi * 16 + lm) * 64 + kh * 32 + lk * 8];
#pragma unroll
            for (int nj = 0; nj < 4; ++nj)
                bfr[nj] = *(const bf16x8*)&Bs[(wc * 64 + nj * 16 + lm) * 64 + kh * 32 + lk * 8];
#pragma unroll
            for (int mi = 0; mi < 4; ++mi)
#pragma unroll
                for (int nj = 0; nj < 4; ++nj)
                    acc[mi][nj] = __builtin_amdgcn_mfma_f32_16x16x32_bf16(
                        af[mi], bfr[nj], acc[mi][nj], 0, 0, 0);
        }
    }

    // epilogue: relu + logits partial over this block's 128 n-cols
#pragma unroll
    for (int mi = 0; mi < 4; ++mi) {
        float ls0[4] = {0.f, 0.f, 0.f, 0.f};
        float ls1[4] = {0.f, 0.f, 0.f, 0.f};
#pragma unroll
        for (int nj = 0; nj < 4; ++nj) {
            const int gn = n0 + wc * 64 + nj * 16 + lm;
            const float bv = bias[gn];
            const float w0 = w_sbd[gn];
            const float w1 = w_sbd[512 + gn];
#pragma unroll
            for (int r = 0; r < 4; ++r) {
                const float v = fmaxf(acc[mi][nj][r] + bv, 0.0f);
                ls0[r] += v * w0;
                ls1[r] += v * w1;
            }
        }
#pragma unroll
        for (int r = 0; r < 4; ++r) {
            float v0 = ls0[r], v1 = ls1[r];
#pragma unroll
            for (int msk = 1; msk < 16; msk <<= 1) {
                v0 += __shfl_xor(v0, msk);
                v1 += __shfl_xor(v1, msk);
            }
            if (lm == 0) {
                const int gm = m0 + wr * 64 + mi * 16 + lk * 4 + r;
                const int base = (gm >> 7) * 256 + (gm & 127);
                atomicAdd(&out[base], v0);
                atomicAdd(&out[base + 128], v1);
            }
        }
    }
}

// ---------------------------------------------------------------------------
// Kernel 7: swizzle four w_hh (1024x256 f32) into bf16 MFMA A-fragment order
// for the 8-wave LSTM.  [mat][wv 8][kt 8][fr 8][lane 64][e 8]
//   fr = g*2+s:  n = g*256 + wv*32 + s*16 + (lane&15)
//   k  = kt*32 + (lane>>4)*8 + e
// ---------------------------------------------------------------------------
__global__ __launch_bounds__(256) void wswz_kernel(
    const float* __restrict__ w0, const float* __restrict__ w1,
    const float* __restrict__ w2, const float* __restrict__ w3,
    short* __restrict__ out)
{
    const int idx  = blockIdx.x * 256 + threadIdx.x;    // 4*262144
    const int mat  = idx >> 18;
    const int i2   = idx & 262143;
    const int e    = i2 & 7;
    const int l    = (i2 >> 3) & 63;
    const int fr   = (i2 >> 9) & 7;
    const int kt   = (i2 >> 12) & 7;
    const int wv   = (i2 >> 15) & 7;
    const int g    = fr >> 1, s = fr & 1;
    const int n    = g * 256 + wv * 32 + s * 16 + (l & 15);
    const int k    = kt * 32 + ((l >> 4) << 3) + e;
    const float* w = (mat == 0) ? w0 : (mat == 1) ? w1 : (mat == 2) ? w2 : w3;
    out[idx] = (short)f2bf_(w[n * H_ + k]);
}

// ---------------------------------------------------------------------------
// Kernel 8: persistent bidirectional LSTM, bf16 MFMA, WEIGHT-RESIDENT,
// double-buffered h + single LDS-only barrier per step (r7-verified).
// xp from merged xp_cat[M][2048] (dir*1024).  h -> hcat[M][512] bf16 (hi only;
// downstream GEMMs are A-bf16 2-term).
// ---------------------------------------------------------------------------
__global__ __launch_bounds__(512, 2) void lstm_kernel(
    const float* __restrict__ xpc,
    const short* __restrict__ wswf, const short* __restrict__ wswb,
    unsigned short* __restrict__ hcat)
{
    const int dir  = blockIdx.x >> 4;
    const int grp  = blockIdx.x & 15;
    const int tid  = threadIdx.x;
    const int wv   = tid >> 6;          // wave 0..7
    const int lane = tid & 63;
    const int lm   = lane & 15;
    const int lk   = lane >> 4;
    const float* xp  = xpc + dir * 1024;
    const short* wsw = dir ? wswb : wswf;
    const int b0 = grp * 16;
    const int b  = lm;                  // this lane's batch column

    __shared__ short lds_w[65536];      // 128 KB: [wv 8][kt2 2][fr 8][512]
    __shared__ short h_lds[2][16 * 256];// 2 x 8 KB, [b][k] bf16, XOR-swizzled

    // ---- one-time staging --------------------------------------------------
    for (int i = tid; i < 16 * 256 / 2; i += 512) ((int*)h_lds[0])[i] = 0;
#pragma unroll
    for (int kt2 = 0; kt2 < 2; ++kt2)
#pragma unroll
        for (int fr = 0; fr < 8; ++fr) {
            const short* src = wsw + (((wv * 8 + 4 + kt2) * 8 + fr) << 9) + lane * 8;
            gload_lds16(src, &lds_w[((wv * 2 + kt2) * 8 + fr) << 9]);
        }
    bf16x8 awr[4][8];
#pragma unroll
    for (int kt = 0; kt < 4; ++kt)
#pragma unroll
        for (int fr = 0; fr < 8; ++fr)
            awr[kt][fr] = *(const bf16x8*)(wsw + (((wv * 8 + kt) * 8 + fr) << 9) + lane * 8);

    float c_st[2][4];
#pragma unroll
    for (int s = 0; s < 2; ++s)
#pragma unroll
        for (int r = 0; r < 4; ++r) c_st[s][r] = 0.0f;

    int nof[8];
#pragma unroll
    for (int fr = 0; fr < 8; ++fr)
        nof[fr] = (fr >> 1) * 256 + wv * 32 + (fr & 1) * 16 + lk * 4;

    __syncthreads();   // one-time: full drain ok

    // prefetch xp for step 0
    f32x4 xpre[8];
    {
        const int t0 = dir ? (SEQ_ - 1) : 0;
        const float* xr = xp + ((size_t)(b0 + b) * SEQ_ + t0) * 2048;
#pragma unroll
        for (int fr = 0; fr < 8; ++fr) xpre[fr] = *(const f32x4*)(xr + nof[fr]);
    }

    int cur = 0;
    for (int step = 0; step < SEQ_; ++step) {
        const int t = dir ? (SEQ_ - 1 - step) : step;
        const char* hr = (const char*)h_lds[0] + cur * 8192;
        char*       hw = (char*)h_lds[0] + (cur ^ 1) * 8192;

        f32x4 acc[8];
#pragma unroll
        for (int fr = 0; fr < 8; ++fr) acc[fr] = xpre[fr];

        // issue streamed kt=6 loads now
        bf16x8 aws6[8];
#pragma unroll
        for (int fr = 0; fr < 8; ++fr)
            aws6[fr] = *(const bf16x8*)(wsw + (((wv * 8 + 6) * 8 + fr) << 9) + lane * 8);

        // kt 0..3: register-resident weights
#pragma unroll
        for (int kt = 0; kt < 4; ++kt) {
            const int off = b * 512 + (((kt * 32 + lk * 8) * 2) ^ ((b & 7) << 4));
            const bf16x8 bh = *(const bf16x8*)(hr + off);
#pragma unroll
            for (int fr = 0; fr < 8; ++fr)
                acc[fr] = __builtin_amdgcn_mfma_f32_16x16x32_bf16(
                    awr[kt][fr], bh, acc[fr], 0, 0, 0);
        }

        // kt 4..5: LDS-resident weights
#pragma unroll
        for (int kt2 = 0; kt2 < 2; ++kt2) {
            const int kt = 4 + kt2;
            const int off = b * 512 + (((kt * 32 + lk * 8) * 2) ^ ((b & 7) << 4));
            const bf16x8 bh = *(const bf16x8*)(hr + off);
            bf16x8 al[8];
#pragma unroll
            for (int fr = 0; fr < 8; ++fr)
                al[fr] = *(const bf16x8*)&lds_w[(((wv * 2 + kt2) * 8 + fr) << 9) + lane * 8];
#pragma unroll
            for (int fr = 0; fr < 8; ++fr)
                acc[fr] = __builtin_amdgcn_mfma_f32_16x16x32_bf16(
                    al[fr], bh, acc[fr], 0, 0, 0);
        }

        // issue streamed kt=7 loads
        bf16x8 aws7[8];
#pragma unroll
        for (int fr = 0; fr < 8; ++fr)
            aws7[fr] = *(const bf16x8*)(wsw + (((wv * 8 + 7) * 8 + fr) << 9) + lane * 8);

        // kt 6
        {
            const int off = b * 512 + (((6 * 32 + lk * 8) * 2) ^ ((b & 7) << 4));
            const bf16x8 bh = *(const bf16x8*)(hr + off);
#pragma unroll
            for (int fr = 0; fr < 8; ++fr)
                acc[fr] = __builtin_amdgcn_mfma_f32_16x16x32_bf16(
                    aws6[fr], bh, acc[fr], 0, 0, 0);
        }
        // kt 7
        {
            const int off = b * 512 + (((7 * 32 + lk * 8) * 2) ^ ((b & 7) << 4));
            const bf16x8 bh = *(const bf16x8*)(hr + off);
#pragma unroll
            for (int fr = 0; fr < 8; ++fr)
                acc[fr] = __builtin_amdgcn_mfma_f32_16x16x32_bf16(
                    aws7[fr], bh, acc[fr], 0, 0, 0);
        }

        // prefetch xp for next step (in flight across the barrier)
        {
            const int tn = dir ? (t > 0 ? t - 1 : 0) : (t < SEQ_ - 1 ? t + 1 : t);
            const float* xr = xp + ((size_t)(b0 + b) * SEQ_ + tn) * 2048;
#pragma unroll
            for (int fr = 0; fr < 8; ++fr) xpre[fr] = *(const f32x4*)(xr + nof[fr]);
        }

        // pointwise: fr=g*2+s -> i:acc[s], f:acc[2+s], g:acc[4+s], o:acc[6+s]
#pragma unroll
        for (int s = 0; s < 2; ++s) {
            u16x4 hb;
#pragma unroll
            for (int r = 0; r < 4; ++r) {
                const float iv = sigf_(acc[s][r]);
                const float fv = sigf_(acc[2 + s][r]);
                const float gv = tanhf_(acc[4 + s][r]);
                const float ov = sigf_(acc[6 + s][r]);
                const float c  = fv * c_st[s][r] + iv * gv;
                c_st[s][r] = c;
                hb[r] = f2bf_(ov * tanhf_(c));
            }
            const int j0  = wv * 32 + s * 16 + lk * 4;
            const int off = b * 512 + ((j0 * 2) ^ ((b & 7) << 4));
            *(u16x4*)(hw + off) = hb;
            *(u16x4*)&hcat[((size_t)(b0 + b) * SEQ_ + t) * 512 + dir * 256 + j0] = hb;
        }

        // single per-step barrier: LDS-only drain; vmem stays in flight
        asm volatile("s_waitcnt lgkmcnt(0)" ::: "memory");
        __builtin_amdgcn_s_barrier();
        cur ^= 1;
    }
}

// ---------------------------------------------------------------------------
extern "C" void kernel_launch(void* const* d_in, const int* in_sizes, int n_in,
                              void* d_out, int out_size, void* d_ws, size_t ws_size,
                              hipStream_t stream)
{
    const float* emb   = (const float*)d_in[0];
    const int*   wid   = (const int*)d_in[1];
    const float* w_ih[4] = {(const float*)d_in[2],  (const float*)d_in[6],
                            (const float*)d_in[10], (const float*)d_in[14]};
    const float* w_hh[4] = {(const float*)d_in[3],  (const float*)d_in[7],
                            (const float*)d_in[11], (const float*)d_in[15]};
    const float* b_ih[4] = {(const float*)d_in[4],  (const float*)d_in[8],
                            (const float*)d_in[12], (const float*)d_in[16]};
    const float* b_hh[4] = {(const float*)d_in[5],  (const float*)d_in[9],
                            (const float*)d_in[13], (const float*)d_in[17]};
    const float* w_ff  = (const float*)d_in[18];
    const float* b_ff  = (const float*)d_in[19];
    const float* w_sbd = (const float*)d_in[20];
    const float* b_sbd = (const float*)d_in[21];
    float* out = (float*)d_out;
    char*  ws  = (char*)d_ws;

    const int M = B_ * SEQ_;   // 32768

    // ---- workspace layout (bytes) ------------------------------------------
    const size_t OFF_R1  = 0;                       // Acat0 (100.7MB) -> hcat (33.6MB)
    const size_t OFF_XP  = 100663296;               // xp_cat [M][2048] f32 = 268.4MB
    const size_t OFF_WC  = OFF_XP + 268435456;      // Wcat pool
    const size_t OFF_WSW = OFF_WC + 17301504;       // 2MB swizzled w_hh
    const size_t OFF_BC  = OFF_WSW + 2097152;       // 2x2048 f32 bias concat

    unsigned short* Acat0 = (unsigned short*)(ws + OFF_R1);
    unsigned short* hcat  = (unsigned short*)(ws + OFF_R1);
    float* xpc  = (float*)(ws + OFF_XP);
    unsigned short* Wc0  = (unsigned short*)(ws + OFF_WC);              // 2048x2304 (3-term)
    unsigned short* Wc1  = Wc0 + (size_t)2048 * 2304;                   // 2048x1024 (2-term)
    unsigned short* Wcff = Wc1 + (size_t)2048 * 1024;                   // 512x1024  (2-term)
    short* wsw  = (short*)(ws + OFF_WSW);
    float* bc0  = (float*)(ws + OFF_BC);
    float* bc1  = bc0 + 2048;

    // ---- weight/bias conversions (independent of data path) ----------------
    wswz_kernel<<<4096, 256, 0, stream>>>(w_hh[0], w_hh[1], w_hh[2], w_hh[3], wsw);
    convw_kernel<<<(1024 * 768 + 255) / 256, 256, 0, stream>>>(w_ih[0], Wc0, 1024, 768, 3);
    convw_kernel<<<(1024 * 768 + 255) / 256, 256, 0, stream>>>(w_ih[1], Wc0 + (size_t)1024 * 2304, 1024, 768, 3);
    convw_kernel<<<(1024 * 512 + 255) / 256, 256, 0, stream>>>(w_ih[2], Wc1, 1024, 512, 2);
    convw_kernel<<<(1024 * 512 + 255) / 256, 256, 0, stream>>>(w_ih[3], Wc1 + (size_t)1024 * 1024, 1024, 512, 2);
    convw_kernel<<<(512 * 512 + 255) / 256, 256, 0, stream>>>(w_ff, Wcff, 512, 512, 2);
    biascat_kernel<<<8, 256, 0, stream>>>(b_ih[0], b_hh[0], b_ih[1], b_hh[1], bc0);
    biascat_kernel<<<8, 256, 0, stream>>>(b_ih[2], b_hh[2], b_ih[3], b_hh[3], bc1);
    outinit_kernel<<<256, 256, 0, stream>>>(b_sbd, out);

    // ---- data path ----------------------------------------------------------
    scatter_avg_kernel<<<B_, 256, 0, stream>>>(emb, wid, Acat0);

    // layer-0 merged projection (3-term, KA=2K=1536): [M][2048]
    gemm_bf16_kernel<<<(2048 / 128) * (M / 128), 256, 0, stream>>>(
        Acat0, Wc0, bc0, xpc, M, 2048, 768, 1536, 0);

    lstm_kernel<<<32, 512, 0, stream>>>(xpc, wsw, wsw + 262144, hcat);

    // layer-1 merged projection (2-term, A = hcat bf16, KA=K=512)
    gemm_bf16_kernel<<<(2048 / 128) * (M / 128), 256, 0, stream>>>(
        hcat, Wc1, bc1, xpc, M, 2048, 512, 512, 0);

    lstm_kernel<<<32, 512, 0, stream>>>(xpc, wsw + 2 * 262144, wsw + 3 * 262144, hcat);

    // FF + fused logits (2-term)
    gemm_ff_logits_kernel<<<(512 / 128) * (M / 128), 256, 0, stream>>>(
        hcat, Wcff, b_ff, w_sbd, out, M, 512, 512);
}

// Round 11
// 1954.314 us; speedup vs baseline: 1.1942x; 1.0587x over previous
//
#include <hip/hip_runtime.h>
#include <cstddef>

#define B_    256
#define TSUB  192
#define SEQ_  128
#define D_    768
#define H_    256
#define G_    1024   // 4*H
#define DH_   512    // 2*H

typedef __attribute__((ext_vector_type(4))) float f32x4;
typedef __attribute__((ext_vector_type(8))) short bf16x8;
typedef __attribute__((ext_vector_type(4))) unsigned short u16x4;

__device__ __forceinline__ float rcpf_(float x) { return __builtin_amdgcn_rcpf(x); }
__device__ __forceinline__ float sigf_(float x)  { return rcpf_(1.0f + __expf(-x)); }
__device__ __forceinline__ float tanhf_(float x) { return 1.0f - 2.0f * rcpf_(__expf(2.0f * x) + 1.0f); }

__device__ __forceinline__ unsigned short f2bf_(float x) {
    unsigned u = __builtin_bit_cast(unsigned, x);
    return (unsigned short)((u + 0x7fffu + ((u >> 16) & 1u)) >> 16);
}
__device__ __forceinline__ float bf2f_(unsigned short h) {
    return __builtin_bit_cast(float, (unsigned)h << 16);
}
__device__ __forceinline__ void gload_lds16(const void* g, void* l) {
    __builtin_amdgcn_global_load_lds(
        (const __attribute__((address_space(1))) unsigned int*)g,
        (__attribute__((address_space(3))) unsigned int*)l, 16, 0, 0);
}

// ---------------------------------------------------------------------------
// Kernel 1: scatter-average, fused hi/lo bf16 split.  One block per batch.
// Writes Acat0[M][1536] = [hi(768)|lo(768)] directly.
// ---------------------------------------------------------------------------
__global__ __launch_bounds__(256) void scatter_avg_kernel(
    const float* __restrict__ emb, const int* __restrict__ wid,
    unsigned short* __restrict__ acat)
{
    const int b   = blockIdx.x;
    const int tid = threadIdx.x;
    __shared__ int s_wid[TSUB];
    __shared__ int s_start[SEQ_ + 1];

    for (int i = tid; i < TSUB; i += 256) s_wid[i] = wid[b * TSUB + i];
    __syncthreads();
    for (int s = tid; s <= SEQ_; s += 256) {
        int cnt = 0;
        for (int t = 0; t < TSUB; ++t) cnt += (s_wid[t] < s) ? 1 : 0;
        s_start[s] = cnt;
    }
    __syncthreads();

    const float* eb = emb + (size_t)b * TSUB * D_;
    for (int s = 0; s < SEQ_; ++s) {
        const int st = s_start[s], en = s_start[s + 1];
        const float inv = (en > st) ? 1.0f / (float)(en - st) : 0.0f;
        unsigned short* o = acat + ((size_t)b * SEQ_ + s) * 1536;
        for (int d = tid; d < D_; d += 256) {
            float sum = 0.0f;
            for (int t = st; t < en; ++t) sum += eb[(size_t)t * D_ + d];
            const float x = sum * inv;
            const unsigned short hi = f2bf_(x);
            o[d]       = hi;
            o[768 + d] = f2bf_(x - bf2f_(hi));
        }
    }
}

// ---------------------------------------------------------------------------
// Kernel 2: weight split conversion  f32 W[N][K] -> bf16 Wcat[N][terms*K]
//   terms=3: [hi|lo|hi]  (pairs Ahi,Ahi,Alo)   terms=2: [hi|lo] (pairs Ahi,Ahi)
// ---------------------------------------------------------------------------
__global__ __launch_bounds__(256) void convw_kernel(
    const float* __restrict__ W, unsigned short* __restrict__ out,
    int N, int K, int terms)
{
    const int idx = blockIdx.x * 256 + threadIdx.x;
    if (idx >= N * K) return;
    const int n = idx / K, k = idx - n * K;
    const float x = W[idx];
    const unsigned short hi = f2bf_(x);
    const float lo = x - bf2f_(hi);
    const size_t ro = (size_t)n * terms * K;
    out[ro + k]     = hi;
    out[ro + K + k] = f2bf_(lo);
    if (terms == 3) out[ro + 2 * K + k] = hi;
}

// ---------------------------------------------------------------------------
// Kernel 3: bias concat  bcat[n] = b_ih+b_hh for fwd (n<1024) / bwd rows.
// ---------------------------------------------------------------------------
__global__ __launch_bounds__(256) void biascat_kernel(
    const float* __restrict__ bihf, const float* __restrict__ bhhf,
    const float* __restrict__ bihb, const float* __restrict__ bhhb,
    float* __restrict__ o)
{
    const int i = blockIdx.x * 256 + threadIdx.x;   // 0..2047
    o[i] = (i < 1024) ? (bihf[i] + bhhf[i]) : (bihb[i - 1024] + bhhb[i - 1024]);
}

// ---------------------------------------------------------------------------
// Kernel 4: out init with class bias.  out (B,2,SEQ) flat.
// ---------------------------------------------------------------------------
__global__ __launch_bounds__(256) void outinit_kernel(
    const float* __restrict__ b_sbd, float* __restrict__ out)
{
    const int i = blockIdx.x * 256 + threadIdx.x;   // 0..65535
    out[i] = b_sbd[(i >> 7) & 1];
}

// ---------------------------------------------------------------------------
// Kernel 5: bf16 MFMA GEMM, 128x128 tile, BK=64, global_load_lds width-16,
// XCD-swizzled 1D grid.  LDS rows are 128 B -> naive ds_read_b128 is a
// 16-way bank conflict (r10 PMC: 1.13e8 conflict cycles).  Fix = T2
// both-sides XOR swizzle, rule-#21 compliant: LDS dest stays LINEAR
// (global_load_lds requirement); the global SOURCE chunk is permuted
// c -> c^(row&7) at staging, and reads use chunk q^(row&7).
//   C = act( A[M][KA] x Wcat[N][KW] + bias ),  ka = kw<K ? kw : kw-K.
// ---------------------------------------------------------------------------
__global__ __launch_bounds__(256) void gemm_bf16_kernel(
    const unsigned short* __restrict__ A, const unsigned short* __restrict__ Wc,
    const float* __restrict__ bias, float* __restrict__ C,
    int M, int N, int K, int KA, int relu)
{
    const int KWr  = (KA == K) ? 2 * K : 3 * K;
    const int NT64 = KWr >> 6;
    const int ntn  = N >> 7;
    const int id  = blockIdx.x;
    const int cpx = gridDim.x >> 3;
    const int swz = (id & 7) * cpx + (id >> 3);
    const int m0  = (swz / ntn) * 128;
    const int n0  = (swz % ntn) * 128;

    const int tid  = threadIdx.x;
    const int wv   = tid >> 6;
    const int lane = tid & 63;
    const int lm   = lane & 15, lk = lane >> 4;
    const int wr   = wv >> 1,   wc = wv & 1;

    __shared__ unsigned short As[128 * 64];   // 16 KB, [row][64], src-swizzled
    __shared__ unsigned short Bs[128 * 64];   // 16 KB

    const int sx = lm & 7;                    // read-side row XOR key

    f32x4 acc[4][4];
#pragma unroll
    for (int i = 0; i < 4; ++i)
#pragma unroll
        for (int j = 0; j < 4; ++j) acc[i][j] = (f32x4){0.f, 0.f, 0.f, 0.f};

    for (int kt = 0; kt < NT64; ++kt) {
        const int kw = kt << 6;
        const int ka = (kw < K) ? kw : kw - K;
        __syncthreads();   // previous tile fully consumed
#pragma unroll
        for (int l = 0; l < 4; ++l) {
            const int e   = l * 256 + tid;            // 0..1023
            const int row = e >> 3;                   // 0..127
            const int cs8 = (((e & 7) ^ (row & 7)) << 3);   // swizzled src chunk
            gload_lds16(A  + (size_t)(m0 + row) * KA  + ka + cs8, As + e * 8);
            gload_lds16(Wc + (size_t)(n0 + row) * KWr + kw + cs8, Bs + e * 8);
        }
        __syncthreads();   // staging complete

#pragma unroll
        for (int kh = 0; kh < 2; ++kh) {
            const int q = ((kh * 4 + lk) ^ sx) * 8;   // swizzled read chunk
            bf16x8 af[4], bfr[4];
#pragma unroll
            for (int mi = 0; mi < 4; ++mi)
                af[mi] = *(const bf16x8*)&As[(wr * 64 + mi * 16 + lm) * 64 + q];
#pragma unroll
            for (int nj = 0; nj < 4; ++nj)
                bfr[nj] = *(const bf16x8*)&Bs[(wc * 64 + nj * 16 + lm) * 64 + q];
#pragma unroll
            for (int mi = 0; mi < 4; ++mi)
#pragma unroll
                for (int nj = 0; nj < 4; ++nj)
                    acc[mi][nj] = __builtin_amdgcn_mfma_f32_16x16x32_bf16(
                        af[mi], bfr[nj], acc[mi][nj], 0, 0, 0);
        }
    }

#pragma unroll
    for (int mi = 0; mi < 4; ++mi)
#pragma unroll
        for (int nj = 0; nj < 4; ++nj) {
            const int gn = n0 + wc * 64 + nj * 16 + lm;
            const float bv = bias[gn];
#pragma unroll
            for (int r = 0; r < 4; ++r) {
                const int gm = m0 + wr * 64 + mi * 16 + lk * 4 + r;
                float v = acc[mi][nj][r] + bv;
                if (relu) v = fmaxf(v, 0.0f);
                C[(size_t)gm * N + gn] = v;
            }
        }
}

// ---------------------------------------------------------------------------
// Kernel 6: FF GEMM (2-term, KA=K=512) with FUSED logits epilogue.
// Same T2 source/read swizzle as kernel 5.
// ---------------------------------------------------------------------------
__global__ __launch_bounds__(256) void gemm_ff_logits_kernel(
    const unsigned short* __restrict__ A, const unsigned short* __restrict__ Wc,
    const float* __restrict__ bias, const float* __restrict__ w_sbd,
    float* __restrict__ out, int M, int N, int K)
{
    const int KA = K, KW = 2 * K;
    const int NT64 = KW >> 6;
    const int ntn  = N >> 7;
    const int id  = blockIdx.x;
    const int cpx = gridDim.x >> 3;
    const int swz = (id & 7) * cpx + (id >> 3);
    const int m0  = (swz / ntn) * 128;
    const int n0  = (swz % ntn) * 128;

    const int tid  = threadIdx.x;
    const int wv   = tid >> 6;
    const int lane = tid & 63;
    const int lm   = lane & 15, lk = lane >> 4;
    const int wr   = wv >> 1,   wc = wv & 1;

    __shared__ unsigned short As[128 * 64];
    __shared__ unsigned short Bs[128 * 64];

    const int sx = lm & 7;

    f32x4 acc[4][4];
#pragma unroll
    for (int i = 0; i < 4; ++i)
#pragma unroll
        for (int j = 0; j < 4; ++j) acc[i][j] = (f32x4){0.f, 0.f, 0.f, 0.f};

    for (int kt = 0; kt < NT64; ++kt) {
        const int kw = kt << 6;
        const int ka = (kw < K) ? kw : kw - K;
        __syncthreads();
#pragma unroll
        for (int l = 0; l < 4; ++l) {
            const int e   = l * 256 + tid;
            const int row = e >> 3;
            const int cs8 = (((e & 7) ^ (row & 7)) << 3);
            gload_lds16(A  + (size_t)(m0 + row) * KA + ka + cs8, As + e * 8);
            gload_lds16(Wc + (size_t)(n0 + row) * KW + kw + cs8, Bs + e * 8);
        }
        __syncthreads();

#pragma unroll
        for (int kh = 0; kh < 2; ++kh) {
            const int q = ((kh * 4 + lk) ^ sx) * 8;
            bf16x8 af[4], bfr[4];
#pragma unroll
            for (int mi = 0; mi < 4; ++mi)
                af[mi] = *(const bf16x8*)&As[(wr * 64 + mi * 16 + lm) * 64 + q];
#pragma unroll
            for (int nj = 0; nj < 4; ++nj)
                bfr[nj] = *(const bf16x8*)&Bs[(wc * 64 + nj * 16 + lm) * 64 + q];
#pragma unroll
            for (int mi = 0; mi < 4; ++mi)
#pragma unroll
                for (int nj = 0; nj < 4; ++nj)
                    acc[mi][nj] = __builtin_amdgcn_mfma_f32_16x16x32_bf16(
                        af[mi], bfr[nj], acc[mi][nj], 0, 0, 0);
        }
    }

    // epilogue: relu + logits partial over this block's 128 n-cols
#pragma unroll
    for (int mi = 0; mi < 4; ++mi) {
        float ls0[4] = {0.f, 0.f, 0.f, 0.f};
        float ls1[4] = {0.f, 0.f, 0.f, 0.f};
#pragma unroll
        for (int nj = 0; nj < 4; ++nj) {
            const int gn = n0 + wc * 64 + nj * 16 + lm;
            const float bv = bias[gn];
            const float w0 = w_sbd[gn];
            const float w1 = w_sbd[512 + gn];
#pragma unroll
            for (int r = 0; r < 4; ++r) {
                const float v = fmaxf(acc[mi][nj][r] + bv, 0.0f);
                ls0[r] += v * w0;
                ls1[r] += v * w1;
            }
        }
#pragma unroll
        for (int r = 0; r < 4; ++r) {
            float v0 = ls0[r], v1 = ls1[r];
#pragma unroll
            for (int msk = 1; msk < 16; msk <<= 1) {
                v0 += __shfl_xor(v0, msk);
                v1 += __shfl_xor(v1, msk);
            }
            if (lm == 0) {
                const int gm = m0 + wr * 64 + mi * 16 + lk * 4 + r;
                const int base = (gm >> 7) * 256 + (gm & 127);
                atomicAdd(&out[base], v0);
                atomicAdd(&out[base + 128], v1);
            }
        }
    }
}

// ---------------------------------------------------------------------------
// Kernel 7: swizzle four w_hh (1024x256 f32) into bf16 MFMA A-fragment order
// for the 8-wave LSTM.  [mat][wv 8][kt 8][fr 8][lane 64][e 8]
//   fr = g*2+s:  n = g*256 + wv*32 + s*16 + (lane&15)
//   k  = kt*32 + (lane>>4)*8 + e
// ---------------------------------------------------------------------------
__global__ __launch_bounds__(256) void wswz_kernel(
    const float* __restrict__ w0, const float* __restrict__ w1,
    const float* __restrict__ w2, const float* __restrict__ w3,
    short* __restrict__ out)
{
    const int idx  = blockIdx.x * 256 + threadIdx.x;    // 4*262144
    const int mat  = idx >> 18;
    const int i2   = idx & 262143;
    const int e    = i2 & 7;
    const int l    = (i2 >> 3) & 63;
    const int fr   = (i2 >> 9) & 7;
    const int kt   = (i2 >> 12) & 7;
    const int wv   = (i2 >> 15) & 7;
    const int g    = fr >> 1, s = fr & 1;
    const int n    = g * 256 + wv * 32 + s * 16 + (l & 15);
    const int k    = kt * 32 + ((l >> 4) << 3) + e;
    const float* w = (mat == 0) ? w0 : (mat == 1) ? w1 : (mat == 2) ? w2 : w3;
    out[idx] = (short)f2bf_(w[n * H_ + k]);
}

// ---------------------------------------------------------------------------
// Kernel 8: persistent bidirectional LSTM, bf16 MFMA, WEIGHT-RESIDENT,
// double-buffered h + single LDS-only barrier per step (r7-verified).
// xp from merged xp_cat[M][2048] (dir*1024).  h -> hcat[M][512] bf16.
// ---------------------------------------------------------------------------
__global__ __launch_bounds__(512, 2) void lstm_kernel(
    const float* __restrict__ xpc,
    const short* __restrict__ wswf, const short* __restrict__ wswb,
    unsigned short* __restrict__ hcat)
{
    const int dir  = blockIdx.x >> 4;
    const int grp  = blockIdx.x & 15;
    const int tid  = threadIdx.x;
    const int wv   = tid >> 6;          // wave 0..7
    const int lane = tid & 63;
    const int lm   = lane & 15;
    const int lk   = lane >> 4;
    const float* xp  = xpc + dir * 1024;
    const short* wsw = dir ? wswb : wswf;
    const int b0 = grp * 16;
    const int b  = lm;                  // this lane's batch column

    __shared__ short lds_w[65536];      // 128 KB: [wv 8][kt2 2][fr 8][512]
    __shared__ short h_lds[2][16 * 256];// 2 x 8 KB, [b][k] bf16, XOR-swizzled

    // ---- one-time staging --------------------------------------------------
    for (int i = tid; i < 16 * 256 / 2; i += 512) ((int*)h_lds[0])[i] = 0;
#pragma unroll
    for (int kt2 = 0; kt2 < 2; ++kt2)
#pragma unroll
        for (int fr = 0; fr < 8; ++fr) {
            const short* src = wsw + (((wv * 8 + 4 + kt2) * 8 + fr) << 9) + lane * 8;
            gload_lds16(src, &lds_w[((wv * 2 + kt2) * 8 + fr) << 9]);
        }
    bf16x8 awr[4][8];
#pragma unroll
    for (int kt = 0; kt < 4; ++kt)
#pragma unroll
        for (int fr = 0; fr < 8; ++fr)
            awr[kt][fr] = *(const bf16x8*)(wsw + (((wv * 8 + kt) * 8 + fr) << 9) + lane * 8);

    float c_st[2][4];
#pragma unroll
    for (int s = 0; s < 2; ++s)
#pragma unroll
        for (int r = 0; r < 4; ++r) c_st[s][r] = 0.0f;

    int nof[8];
#pragma unroll
    for (int fr = 0; fr < 8; ++fr)
        nof[fr] = (fr >> 1) * 256 + wv * 32 + (fr & 1) * 16 + lk * 4;

    __syncthreads();   // one-time: full drain ok

    // prefetch xp for step 0
    f32x4 xpre[8];
    {
        const int t0 = dir ? (SEQ_ - 1) : 0;
        const float* xr = xp + ((size_t)(b0 + b) * SEQ_ + t0) * 2048;
#pragma unroll
        for (int fr = 0; fr < 8; ++fr) xpre[fr] = *(const f32x4*)(xr + nof[fr]);
    }

    int cur = 0;
    for (int step = 0; step < SEQ_; ++step) {
        const int t = dir ? (SEQ_ - 1 - step) : step;
        const char* hr = (const char*)h_lds[0] + cur * 8192;
        char*       hw = (char*)h_lds[0] + (cur ^ 1) * 8192;

        f32x4 acc[8];
#pragma unroll
        for (int fr = 0; fr < 8; ++fr) acc[fr] = xpre[fr];

        // issue streamed kt=6 loads now
        bf16x8 aws6[8];
#pragma unroll
        for (int fr = 0; fr < 8; ++fr)
            aws6[fr] = *(const bf16x8*)(wsw + (((wv * 8 + 6) * 8 + fr) << 9) + lane * 8);

        // kt 0..3: register-resident weights
#pragma unroll
        for (int kt = 0; kt < 4; ++kt) {
            const int off = b * 512 + (((kt * 32 + lk * 8) * 2) ^ ((b & 7) << 4));
            const bf16x8 bh = *(const bf16x8*)(hr + off);
#pragma unroll
            for (int fr = 0; fr < 8; ++fr)
                acc[fr] = __builtin_amdgcn_mfma_f32_16x16x32_bf16(
                    awr[kt][fr], bh, acc[fr], 0, 0, 0);
        }

        // kt 4..5: LDS-resident weights
#pragma unroll
        for (int kt2 = 0; kt2 < 2; ++kt2) {
            const int kt = 4 + kt2;
            const int off = b * 512 + (((kt * 32 + lk * 8) * 2) ^ ((b & 7) << 4));
            const bf16x8 bh = *(const bf16x8*)(hr + off);
            bf16x8 al[8];
#pragma unroll
            for (int fr = 0; fr < 8; ++fr)
                al[fr] = *(const bf16x8*)&lds_w[(((wv * 2 + kt2) * 8 + fr) << 9) + lane * 8];
#pragma unroll
            for (int fr = 0; fr < 8; ++fr)
                acc[fr] = __builtin_amdgcn_mfma_f32_16x16x32_bf16(
                    al[fr], bh, acc[fr], 0, 0, 0);
        }

        // issue streamed kt=7 loads
        bf16x8 aws7[8];
#pragma unroll
        for (int fr = 0; fr < 8; ++fr)
            aws7[fr] = *(const bf16x8*)(wsw + (((wv * 8 + 7) * 8 + fr) << 9) + lane * 8);

        // kt 6
        {
            const int off = b * 512 + (((6 * 32 + lk * 8) * 2) ^ ((b & 7) << 4));
            const bf16x8 bh = *(const bf16x8*)(hr + off);
#pragma unroll
            for (int fr = 0; fr < 8; ++fr)
                acc[fr] = __builtin_amdgcn_mfma_f32_16x16x32_bf16(
                    aws6[fr], bh, acc[fr], 0, 0, 0);
        }
        // kt 7
        {
            const int off = b * 512 + (((7 * 32 + lk * 8) * 2) ^ ((b & 7) << 4));
            const bf16x8 bh = *(const bf16x8*)(hr + off);
#pragma unroll
            for (int fr = 0; fr < 8; ++fr)
                acc[fr] = __builtin_amdgcn_mfma_f32_16x16x32_bf16(
                    aws7[fr], bh, acc[fr], 0, 0, 0);
        }

        // prefetch xp for next step (in flight across the barrier)
        {
            const int tn = dir ? (t > 0 ? t - 1 : 0) : (t < SEQ_ - 1 ? t + 1 : t);
            const float* xr = xp + ((size_t)(b0 + b) * SEQ_ + tn) * 2048;
#pragma unroll
            for (int fr = 0; fr < 8; ++fr) xpre[fr] = *(const f32x4*)(xr + nof[fr]);
        }

        // pointwise: fr=g*2+s -> i:acc[s], f:acc[2+s], g:acc[4+s], o:acc[6+s]
#pragma unroll
        for (int s = 0; s < 2; ++s) {
            u16x4 hb;
#pragma unroll
            for (int r = 0; r < 4; ++r) {
                const float iv = sigf_(acc[s][r]);
                const float fv = sigf_(acc[2 + s][r]);
                const float gv = tanhf_(acc[4 + s][r]);
                const float ov = sigf_(acc[6 + s][r]);
                const float c  = fv * c_st[s][r] + iv * gv;
                c_st[s][r] = c;
                hb[r] = f2bf_(ov * tanhf_(c));
            }
            const int j0  = wv * 32 + s * 16 + lk * 4;
            const int off = b * 512 + ((j0 * 2) ^ ((b & 7) << 4));
            *(u16x4*)(hw + off) = hb;
            *(u16x4*)&hcat[((size_t)(b0 + b) * SEQ_ + t) * 512 + dir * 256 + j0] = hb;
        }

        // single per-step barrier: LDS-only drain; vmem stays in flight
        asm volatile("s_waitcnt lgkmcnt(0)" ::: "memory");
        __builtin_amdgcn_s_barrier();
        cur ^= 1;
    }
}

// ---------------------------------------------------------------------------
extern "C" void kernel_launch(void* const* d_in, const int* in_sizes, int n_in,
                              void* d_out, int out_size, void* d_ws, size_t ws_size,
                              hipStream_t stream)
{
    const float* emb   = (const float*)d_in[0];
    const int*   wid   = (const int*)d_in[1];
    const float* w_ih[4] = {(const float*)d_in[2],  (const float*)d_in[6],
                            (const float*)d_in[10], (const float*)d_in[14]};
    const float* w_hh[4] = {(const float*)d_in[3],  (const float*)d_in[7],
                            (const float*)d_in[11], (const float*)d_in[15]};
    const float* b_ih[4] = {(const float*)d_in[4],  (const float*)d_in[8],
                            (const float*)d_in[12], (const float*)d_in[16]};
    const float* b_hh[4] = {(const float*)d_in[5],  (const float*)d_in[9],
                            (const float*)d_in[13], (const float*)d_in[17]};
    const float* w_ff  = (const float*)d_in[18];
    const float* b_ff  = (const float*)d_in[19];
    const float* w_sbd = (const float*)d_in[20];
    const float* b_sbd = (const float*)d_in[21];
    float* out = (float*)d_out;
    char*  ws  = (char*)d_ws;

    const int M = B_ * SEQ_;   // 32768

    // ---- workspace layout (bytes) ------------------------------------------
    const size_t OFF_R1  = 0;                       // Acat0 (100.7MB) -> hcat (33.6MB)
    const size_t OFF_XP  = 100663296;               // xp_cat [M][2048] f32 = 268.4MB
    const size_t OFF_WC  = OFF_XP + 268435456;      // Wcat pool
    const size_t OFF_WSW = OFF_WC + 17301504;       // 2MB swizzled w_hh
    const size_t OFF_BC  = OFF_WSW + 2097152;       // 2x2048 f32 bias concat

    unsigned short* Acat0 = (unsigned short*)(ws + OFF_R1);
    unsigned short* hcat  = (unsigned short*)(ws + OFF_R1);
    float* xpc  = (float*)(ws + OFF_XP);
    unsigned short* Wc0  = (unsigned short*)(ws + OFF_WC);              // 2048x2304 (3-term)
    unsigned short* Wc1  = Wc0 + (size_t)2048 * 2304;                   // 2048x1024 (2-term)
    unsigned short* Wcff = Wc1 + (size_t)2048 * 1024;                   // 512x1024  (2-term)
    short* wsw  = (short*)(ws + OFF_WSW);
    float* bc0  = (float*)(ws + OFF_BC);
    float* bc1  = bc0 + 2048;

    // ---- weight/bias conversions (independent of data path) ----------------
    wswz_kernel<<<4096, 256, 0, stream>>>(w_hh[0], w_hh[1], w_hh[2], w_hh[3], wsw);
    convw_kernel<<<(1024 * 768 + 255) / 256, 256, 0, stream>>>(w_ih[0], Wc0, 1024, 768, 3);
    convw_kernel<<<(1024 * 768 + 255) / 256, 256, 0, stream>>>(w_ih[1], Wc0 + (size_t)1024 * 2304, 1024, 768, 3);
    convw_kernel<<<(1024 * 512 + 255) / 256, 256, 0, stream>>>(w_ih[2], Wc1, 1024, 512, 2);
    convw_kernel<<<(1024 * 512 + 255) / 256, 256, 0, stream>>>(w_ih[3], Wc1 + (size_t)1024 * 1024, 1024, 512, 2);
    convw_kernel<<<(512 * 512 + 255) / 256, 256, 0, stream>>>(w_ff, Wcff, 512, 512, 2);
    biascat_kernel<<<8, 256, 0, stream>>>(b_ih[0], b_hh[0], b_ih[1], b_hh[1], bc0);
    biascat_kernel<<<8, 256, 0, stream>>>(b_ih[2], b_hh[2], b_ih[3], b_hh[3], bc1);
    outinit_kernel<<<256, 256, 0, stream>>>(b_sbd, out);

    // ---- data path ----------------------------------------------------------
    scatter_avg_kernel<<<B_, 256, 0, stream>>>(emb, wid, Acat0);

    // layer-0 merged projection (3-term, KA=2K=1536): [M][2048]
    gemm_bf16_kernel<<<(2048 / 128) * (M / 128), 256, 0, stream>>>(
        Acat0, Wc0, bc0, xpc, M, 2048, 768, 1536, 0);

    lstm_kernel<<<32, 512, 0, stream>>>(xpc, wsw, wsw + 262144, hcat);

    // layer-1 merged projection (2-term, A = hcat bf16, KA=K=512)
    gemm_bf16_kernel<<<(2048 / 128) * (M / 128), 256, 0, stream>>>(
        hcat, Wc1, bc1, xpc, M, 2048, 512, 512, 0);

    lstm_kernel<<<32, 512, 0, stream>>>(xpc, wsw + 2 * 262144, wsw + 3 * 262144, hcat);

    // FF + fused logits (2-term)
    gemm_ff_logits_kernel<<<(512 / 128) * (M / 128), 256, 0, stream>>>(
        hcat, Wcff, b_ff, w_sbd, out, M, 512, 512);
}

// Round 12
// 1858.863 us; speedup vs baseline: 1.2556x; 1.0513x over previous
//
#include <hip/hip_runtime.h>
#include <cstddef>

#define B_    256
#define TSUB  192
#define SEQ_  128
#define D_    768
#define H_    256
#define G_    1024   // 4*H
#define DH_   512    // 2*H

typedef __attribute__((ext_vector_type(4))) float f32x4;
typedef __attribute__((ext_vector_type(8))) short bf16x8;
typedef __attribute__((ext_vector_type(4))) unsigned short u16x4;

__device__ __forceinline__ float rcpf_(float x) { return __builtin_amdgcn_rcpf(x); }
__device__ __forceinline__ float sigf_(float x)  { return rcpf_(1.0f + __expf(-x)); }
__device__ __forceinline__ float tanhf_(float x) { return 1.0f - 2.0f * rcpf_(__expf(2.0f * x) + 1.0f); }

__device__ __forceinline__ unsigned short f2bf_(float x) {
    unsigned u = __builtin_bit_cast(unsigned, x);
    return (unsigned short)((u + 0x7fffu + ((u >> 16) & 1u)) >> 16);
}
__device__ __forceinline__ float bf2f_(unsigned short h) {
    return __builtin_bit_cast(float, (unsigned)h << 16);
}
__device__ __forceinline__ void gload_lds16(const void* g, void* l) {
    __builtin_amdgcn_global_load_lds(
        (const __attribute__((address_space(1))) unsigned int*)g,
        (__attribute__((address_space(3))) unsigned int*)l, 16, 0, 0);
}

// ---------------------------------------------------------------------------
// Kernel 1: scatter-average, fused hi/lo bf16 split.  One block per batch.
// Writes Acat0[M][1536] = [hi(768)|lo(768)] directly.
// ---------------------------------------------------------------------------
__global__ __launch_bounds__(256) void scatter_avg_kernel(
    const float* __restrict__ emb, const int* __restrict__ wid,
    unsigned short* __restrict__ acat)
{
    const int b   = blockIdx.x;
    const int tid = threadIdx.x;
    __shared__ int s_wid[TSUB];
    __shared__ int s_start[SEQ_ + 1];

    for (int i = tid; i < TSUB; i += 256) s_wid[i] = wid[b * TSUB + i];
    __syncthreads();
    for (int s = tid; s <= SEQ_; s += 256) {
        int cnt = 0;
        for (int t = 0; t < TSUB; ++t) cnt += (s_wid[t] < s) ? 1 : 0;
        s_start[s] = cnt;
    }
    __syncthreads();

    const float* eb = emb + (size_t)b * TSUB * D_;
    for (int s = 0; s < SEQ_; ++s) {
        const int st = s_start[s], en = s_start[s + 1];
        const float inv = (en > st) ? 1.0f / (float)(en - st) : 0.0f;
        unsigned short* o = acat + ((size_t)b * SEQ_ + s) * 1536;
        for (int d = tid; d < D_; d += 256) {
            float sum = 0.0f;
            for (int t = st; t < en; ++t) sum += eb[(size_t)t * D_ + d];
            const float x = sum * inv;
            const unsigned short hi = f2bf_(x);
            o[d]       = hi;
            o[768 + d] = f2bf_(x - bf2f_(hi));
        }
    }
}

// ---------------------------------------------------------------------------
// Kernel 2: weight split conversion  f32 W[N][K] -> bf16 Wcat[N][terms*K]
//   terms=3: [hi|lo|hi]  (pairs Ahi,Ahi,Alo)   terms=2: [hi|lo] (pairs Ahi,Ahi)
// ---------------------------------------------------------------------------
__global__ __launch_bounds__(256) void convw_kernel(
    const float* __restrict__ W, unsigned short* __restrict__ out,
    int N, int K, int terms)
{
    const int idx = blockIdx.x * 256 + threadIdx.x;
    if (idx >= N * K) return;
    const int n = idx / K, k = idx - n * K;
    const float x = W[idx];
    const unsigned short hi = f2bf_(x);
    const float lo = x - bf2f_(hi);
    const size_t ro = (size_t)n * terms * K;
    out[ro + k]     = hi;
    out[ro + K + k] = f2bf_(lo);
    if (terms == 3) out[ro + 2 * K + k] = hi;
}

// ---------------------------------------------------------------------------
// Kernel 3: bias concat  bcat[n] = b_ih+b_hh for fwd (n<1024) / bwd rows.
// ---------------------------------------------------------------------------
__global__ __launch_bounds__(256) void biascat_kernel(
    const float* __restrict__ bihf, const float* __restrict__ bhhf,
    const float* __restrict__ bihb, const float* __restrict__ bhhb,
    float* __restrict__ o)
{
    const int i = blockIdx.x * 256 + threadIdx.x;   // 0..2047
    o[i] = (i < 1024) ? (bihf[i] + bhhf[i]) : (bihb[i - 1024] + bhhb[i - 1024]);
}

// ---------------------------------------------------------------------------
// Kernel 4: out init with class bias.  out (B,2,SEQ) flat.
// ---------------------------------------------------------------------------
__global__ __launch_bounds__(256) void outinit_kernel(
    const float* __restrict__ b_sbd, float* __restrict__ out)
{
    const int i = blockIdx.x * 256 + threadIdx.x;   // 0..65535
    out[i] = b_sbd[(i >> 7) & 1];
}

// ---------------------------------------------------------------------------
// Kernel 5: bf16 MFMA GEMM, 128x128 tile, BK=64, global_load_lds width-16,
// XCD-swizzled 1D grid, T2 both-sides XOR swizzle (r11-verified).
//   C_bf16 = A[M][KA] x Wcat[N][KW] + bias,  ka = kw<K ? kw : kw-K.
// Output is bf16 (gate pre-activations for the LSTM).
// ---------------------------------------------------------------------------
__global__ __launch_bounds__(256) void gemm_bf16_kernel(
    const unsigned short* __restrict__ A, const unsigned short* __restrict__ Wc,
    const float* __restrict__ bias, unsigned short* __restrict__ C,
    int M, int N, int K, int KA)
{
    const int KWr  = (KA == K) ? 2 * K : 3 * K;
    const int NT64 = KWr >> 6;
    const int ntn  = N >> 7;
    const int id  = blockIdx.x;
    const int cpx = gridDim.x >> 3;
    const int swz = (id & 7) * cpx + (id >> 3);
    const int m0  = (swz / ntn) * 128;
    const int n0  = (swz % ntn) * 128;

    const int tid  = threadIdx.x;
    const int wv   = tid >> 6;
    const int lane = tid & 63;
    const int lm   = lane & 15, lk = lane >> 4;
    const int wr   = wv >> 1,   wc = wv & 1;

    __shared__ unsigned short As[128 * 64];   // 16 KB, [row][64], src-swizzled
    __shared__ unsigned short Bs[128 * 64];   // 16 KB

    const int sx = lm & 7;                    // read-side row XOR key

    f32x4 acc[4][4];
#pragma unroll
    for (int i = 0; i < 4; ++i)
#pragma unroll
        for (int j = 0; j < 4; ++j) acc[i][j] = (f32x4){0.f, 0.f, 0.f, 0.f};

    for (int kt = 0; kt < NT64; ++kt) {
        const int kw = kt << 6;
        const int ka = (kw < K) ? kw : kw - K;
        __syncthreads();   // previous tile fully consumed
#pragma unroll
        for (int l = 0; l < 4; ++l) {
            const int e   = l * 256 + tid;            // 0..1023
            const int row = e >> 3;                   // 0..127
            const int cs8 = (((e & 7) ^ (row & 7)) << 3);   // swizzled src chunk
            gload_lds16(A  + (size_t)(m0 + row) * KA  + ka + cs8, As + e * 8);
            gload_lds16(Wc + (size_t)(n0 + row) * KWr + kw + cs8, Bs + e * 8);
        }
        __syncthreads();   // staging complete

#pragma unroll
        for (int kh = 0; kh < 2; ++kh) {
            const int q = ((kh * 4 + lk) ^ sx) * 8;   // swizzled read chunk
            bf16x8 af[4], bfr[4];
#pragma unroll
            for (int mi = 0; mi < 4; ++mi)
                af[mi] = *(const bf16x8*)&As[(wr * 64 + mi * 16 + lm) * 64 + q];
#pragma unroll
            for (int nj = 0; nj < 4; ++nj)
                bfr[nj] = *(const bf16x8*)&Bs[(wc * 64 + nj * 16 + lm) * 64 + q];
#pragma unroll
            for (int mi = 0; mi < 4; ++mi)
#pragma unroll
                for (int nj = 0; nj < 4; ++nj)
                    acc[mi][nj] = __builtin_amdgcn_mfma_f32_16x16x32_bf16(
                        af[mi], bfr[nj], acc[mi][nj], 0, 0, 0);
        }
    }

#pragma unroll
    for (int mi = 0; mi < 4; ++mi)
#pragma unroll
        for (int nj = 0; nj < 4; ++nj) {
            const int gn = n0 + wc * 64 + nj * 16 + lm;
            const float bv = bias[gn];
#pragma unroll
            for (int r = 0; r < 4; ++r) {
                const int gm = m0 + wr * 64 + mi * 16 + lk * 4 + r;
                C[(size_t)gm * N + gn] = f2bf_(acc[mi][nj][r] + bv);
            }
        }
}

// ---------------------------------------------------------------------------
// Kernel 6: FF GEMM (2-term, KA=K=512) with FUSED logits epilogue.
// Same T2 source/read swizzle as kernel 5.
// ---------------------------------------------------------------------------
__global__ __launch_bounds__(256) void gemm_ff_logits_kernel(
    const unsigned short* __restrict__ A, const unsigned short* __restrict__ Wc,
    const float* __restrict__ bias, const float* __restrict__ w_sbd,
    float* __restrict__ out, int M, int N, int K)
{
    const int KA = K, KW = 2 * K;
    const int NT64 = KW >> 6;
    const int ntn  = N >> 7;
    const int id  = blockIdx.x;
    const int cpx = gridDim.x >> 3;
    const int swz = (id & 7) * cpx + (id >> 3);
    const int m0  = (swz / ntn) * 128;
    const int n0  = (swz % ntn) * 128;

    const int tid  = threadIdx.x;
    const int wv   = tid >> 6;
    const int lane = tid & 63;
    const int lm   = lane & 15, lk = lane >> 4;
    const int wr   = wv >> 1,   wc = wv & 1;

    __shared__ unsigned short As[128 * 64];
    __shared__ unsigned short Bs[128 * 64];

    const int sx = lm & 7;

    f32x4 acc[4][4];
#pragma unroll
    for (int i = 0; i < 4; ++i)
#pragma unroll
        for (int j = 0; j < 4; ++j) acc[i][j] = (f32x4){0.f, 0.f, 0.f, 0.f};

    for (int kt = 0; kt < NT64; ++kt) {
        const int kw = kt << 6;
        const int ka = (kw < K) ? kw : kw - K;
        __syncthreads();
#pragma unroll
        for (int l = 0; l < 4; ++l) {
            const int e   = l * 256 + tid;
            const int row = e >> 3;
            const int cs8 = (((e & 7) ^ (row & 7)) << 3);
            gload_lds16(A  + (size_t)(m0 + row) * KA + ka + cs8, As + e * 8);
            gload_lds16(Wc + (size_t)(n0 + row) * KW + kw + cs8, Bs + e * 8);
        }
        __syncthreads();

#pragma unroll
        for (int kh = 0; kh < 2; ++kh) {
            const int q = ((kh * 4 + lk) ^ sx) * 8;
            bf16x8 af[4], bfr[4];
#pragma unroll
            for (int mi = 0; mi < 4; ++mi)
                af[mi] = *(const bf16x8*)&As[(wr * 64 + mi * 16 + lm) * 64 + q];
#pragma unroll
            for (int nj = 0; nj < 4; ++nj)
                bfr[nj] = *(const bf16x8*)&Bs[(wc * 64 + nj * 16 + lm) * 64 + q];
#pragma unroll
            for (int mi = 0; mi < 4; ++mi)
#pragma unroll
                for (int nj = 0; nj < 4; ++nj)
                    acc[mi][nj] = __builtin_amdgcn_mfma_f32_16x16x32_bf16(
                        af[mi], bfr[nj], acc[mi][nj], 0, 0, 0);
        }
    }

    // epilogue: relu + logits partial over this block's 128 n-cols
#pragma unroll
    for (int mi = 0; mi < 4; ++mi) {
        float ls0[4] = {0.f, 0.f, 0.f, 0.f};
        float ls1[4] = {0.f, 0.f, 0.f, 0.f};
#pragma unroll
        for (int nj = 0; nj < 4; ++nj) {
            const int gn = n0 + wc * 64 + nj * 16 + lm;
            const float bv = bias[gn];
            const float w0 = w_sbd[gn];
            const float w1 = w_sbd[512 + gn];
#pragma unroll
            for (int r = 0; r < 4; ++r) {
                const float v = fmaxf(acc[mi][nj][r] + bv, 0.0f);
                ls0[r] += v * w0;
                ls1[r] += v * w1;
            }
        }
#pragma unroll
        for (int r = 0; r < 4; ++r) {
            float v0 = ls0[r], v1 = ls1[r];
#pragma unroll
            for (int msk = 1; msk < 16; msk <<= 1) {
                v0 += __shfl_xor(v0, msk);
                v1 += __shfl_xor(v1, msk);
            }
            if (lm == 0) {
                const int gm = m0 + wr * 64 + mi * 16 + lk * 4 + r;
                const int base = (gm >> 7) * 256 + (gm & 127);
                atomicAdd(&out[base], v0);
                atomicAdd(&out[base + 128], v1);
            }
        }
    }
}

// ---------------------------------------------------------------------------
// Kernel 7: swizzle four w_hh (1024x256 f32) into bf16 MFMA A-fragment order
// for the 8-wave LSTM.  [mat][wv 8][kt 8][fr 8][lane 64][e 8]
//   fr = g*2+s:  n = g*256 + wv*32 + s*16 + (lane&15)
//   k  = kt*32 + (lane>>4)*8 + e
// ---------------------------------------------------------------------------
__global__ __launch_bounds__(256) void wswz_kernel(
    const float* __restrict__ w0, const float* __restrict__ w1,
    const float* __restrict__ w2, const float* __restrict__ w3,
    short* __restrict__ out)
{
    const int idx  = blockIdx.x * 256 + threadIdx.x;    // 4*262144
    const int mat  = idx >> 18;
    const int i2   = idx & 262143;
    const int e    = i2 & 7;
    const int l    = (i2 >> 3) & 63;
    const int fr   = (i2 >> 9) & 7;
    const int kt   = (i2 >> 12) & 7;
    const int wv   = (i2 >> 15) & 7;
    const int g    = fr >> 1, s = fr & 1;
    const int n    = g * 256 + wv * 32 + s * 16 + (l & 15);
    const int k    = kt * 32 + ((l >> 4) << 3) + e;
    const float* w = (mat == 0) ? w0 : (mat == 1) ? w1 : (mat == 2) ? w2 : w3;
    out[idx] = (short)f2bf_(w[n * H_ + k]);
}

// ---------------------------------------------------------------------------
// Kernel 8: persistent bidirectional LSTM, bf16 MFMA, WEIGHT-RESIDENT,
// double-buffered h + single LDS-only barrier per step (r7-verified).
// xp now bf16 [M][2048] (dir*1024 offset): u16x4 loads + shift-convert.
// h -> hcat[M][512] bf16.
// ---------------------------------------------------------------------------
__global__ __launch_bounds__(512, 2) void lstm_kernel(
    const unsigned short* __restrict__ xpc,
    const short* __restrict__ wswf, const short* __restrict__ wswb,
    unsigned short* __restrict__ hcat)
{
    const int dir  = blockIdx.x >> 4;
    const int grp  = blockIdx.x & 15;
    const int tid  = threadIdx.x;
    const int wv   = tid >> 6;          // wave 0..7
    const int lane = tid & 63;
    const int lm   = lane & 15;
    const int lk   = lane >> 4;
    const unsigned short* xp = xpc + dir * 1024;
    const short* wsw = dir ? wswb : wswf;
    const int b0 = grp * 16;
    const int b  = lm;                  // this lane's batch column

    __shared__ short lds_w[65536];      // 128 KB: [wv 8][kt2 2][fr 8][512]
    __shared__ short h_lds[2][16 * 256];// 2 x 8 KB, [b][k] bf16, XOR-swizzled

    // ---- one-time staging --------------------------------------------------
    for (int i = tid; i < 16 * 256 / 2; i += 512) ((int*)h_lds[0])[i] = 0;
#pragma unroll
    for (int kt2 = 0; kt2 < 2; ++kt2)
#pragma unroll
        for (int fr = 0; fr < 8; ++fr) {
            const short* src = wsw + (((wv * 8 + 4 + kt2) * 8 + fr) << 9) + lane * 8;
            gload_lds16(src, &lds_w[((wv * 2 + kt2) * 8 + fr) << 9]);
        }
    bf16x8 awr[4][8];
#pragma unroll
    for (int kt = 0; kt < 4; ++kt)
#pragma unroll
        for (int fr = 0; fr < 8; ++fr)
            awr[kt][fr] = *(const bf16x8*)(wsw + (((wv * 8 + kt) * 8 + fr) << 9) + lane * 8);

    float c_st[2][4];
#pragma unroll
    for (int s = 0; s < 2; ++s)
#pragma unroll
        for (int r = 0; r < 4; ++r) c_st[s][r] = 0.0f;

    int nof[8];
#pragma unroll
    for (int fr = 0; fr < 8; ++fr)
        nof[fr] = (fr >> 1) * 256 + wv * 32 + (fr & 1) * 16 + lk * 4;

    __syncthreads();   // one-time: full drain ok

    // prefetch xp for step 0 (bf16)
    u16x4 xpre[8];
    {
        const int t0 = dir ? (SEQ_ - 1) : 0;
        const unsigned short* xr = xp + ((size_t)(b0 + b) * SEQ_ + t0) * 2048;
#pragma unroll
        for (int fr = 0; fr < 8; ++fr) xpre[fr] = *(const u16x4*)(xr + nof[fr]);
    }

    int cur = 0;
    for (int step = 0; step < SEQ_; ++step) {
        const int t = dir ? (SEQ_ - 1 - step) : step;
        const char* hr = (const char*)h_lds[0] + cur * 8192;
        char*       hw = (char*)h_lds[0] + (cur ^ 1) * 8192;

        f32x4 acc[8];
#pragma unroll
        for (int fr = 0; fr < 8; ++fr)
#pragma unroll
            for (int r = 0; r < 4; ++r) acc[fr][r] = bf2f_(xpre[fr][r]);

        // issue streamed kt=6 loads now
        bf16x8 aws6[8];
#pragma unroll
        for (int fr = 0; fr < 8; ++fr)
            aws6[fr] = *(const bf16x8*)(wsw + (((wv * 8 + 6) * 8 + fr) << 9) + lane * 8);

        // kt 0..3: register-resident weights
#pragma unroll
        for (int kt = 0; kt < 4; ++kt) {
            const int off = b * 512 + (((kt * 32 + lk * 8) * 2) ^ ((b & 7) << 4));
            const bf16x8 bh = *(const bf16x8*)(hr + off);
#pragma unroll
            for (int fr = 0; fr < 8; ++fr)
                acc[fr] = __builtin_amdgcn_mfma_f32_16x16x32_bf16(
                    awr[kt][fr], bh, acc[fr], 0, 0, 0);
        }

        // kt 4..5: LDS-resident weights
#pragma unroll
        for (int kt2 = 0; kt2 < 2; ++kt2) {
            const int kt = 4 + kt2;
            const int off = b * 512 + (((kt * 32 + lk * 8) * 2) ^ ((b & 7) << 4));
            const bf16x8 bh = *(const bf16x8*)(hr + off);
            bf16x8 al[8];
#pragma unroll
            for (int fr = 0; fr < 8; ++fr)
                al[fr] = *(const bf16x8*)&lds_w[(((wv * 2 + kt2) * 8 + fr) << 9) + lane * 8];
#pragma unroll
            for (int fr = 0; fr < 8; ++fr)
                acc[fr] = __builtin_amdgcn_mfma_f32_16x16x32_bf16(
                    al[fr], bh, acc[fr], 0, 0, 0);
        }

        // issue streamed kt=7 loads
        bf16x8 aws7[8];
#pragma unroll
        for (int fr = 0; fr < 8; ++fr)
            aws7[fr] = *(const bf16x8*)(wsw + (((wv * 8 + 7) * 8 + fr) << 9) + lane * 8);

        // kt 6
        {
            const int off = b * 512 + (((6 * 32 + lk * 8) * 2) ^ ((b & 7) << 4));
            const bf16x8 bh = *(const bf16x8*)(hr + off);
#pragma unroll
            for (int fr = 0; fr < 8; ++fr)
                acc[fr] = __builtin_amdgcn_mfma_f32_16x16x32_bf16(
                    aws6[fr], bh, acc[fr], 0, 0, 0);
        }
        // kt 7
        {
            const int off = b * 512 + (((7 * 32 + lk * 8) * 2) ^ ((b & 7) << 4));
            const bf16x8 bh = *(const bf16x8*)(hr + off);
#pragma unroll
            for (int fr = 0; fr < 8; ++fr)
                acc[fr] = __builtin_amdgcn_mfma_f32_16x16x32_bf16(
                    aws7[fr], bh, acc[fr], 0, 0, 0);
        }

        // prefetch xp for next step (in flight across the barrier)
        {
            const int tn = dir ? (t > 0 ? t - 1 : 0) : (t < SEQ_ - 1 ? t + 1 : t);
            const unsigned short* xr = xp + ((size_t)(b0 + b) * SEQ_ + tn) * 2048;
#pragma unroll
            for (int fr = 0; fr < 8; ++fr) xpre[fr] = *(const u16x4*)(xr + nof[fr]);
        }

        // pointwise: fr=g*2+s -> i:acc[s], f:acc[2+s], g:acc[4+s], o:acc[6+s]
#pragma unroll
        for (int s = 0; s < 2; ++s) {
            u16x4 hb;
#pragma unroll
            for (int r = 0; r < 4; ++r) {
                const float iv = sigf_(acc[s][r]);
                const float fv = sigf_(acc[2 + s][r]);
                const float gv = tanhf_(acc[4 + s][r]);
                const float ov = sigf_(acc[6 + s][r]);
                const float c  = fv * c_st[s][r] + iv * gv;
                c_st[s][r] = c;
                hb[r] = f2bf_(ov * tanhf_(c));
            }
            const int j0  = wv * 32 + s * 16 + lk * 4;
            const int off = b * 512 + ((j0 * 2) ^ ((b & 7) << 4));
            *(u16x4*)(hw + off) = hb;
            *(u16x4*)&hcat[((size_t)(b0 + b) * SEQ_ + t) * 512 + dir * 256 + j0] = hb;
        }

        // single per-step barrier: LDS-only drain; vmem stays in flight
        asm volatile("s_waitcnt lgkmcnt(0)" ::: "memory");
        __builtin_amdgcn_s_barrier();
        cur ^= 1;
    }
}

// ---------------------------------------------------------------------------
extern "C" void kernel_launch(void* const* d_in, const int* in_sizes, int n_in,
                              void* d_out, int out_size, void* d_ws, size_t ws_size,
                              hipStream_t stream)
{
    const float* emb   = (const float*)d_in[0];
    const int*   wid   = (const int*)d_in[1];
    const float* w_ih[4] = {(const float*)d_in[2],  (const float*)d_in[6],
                            (const float*)d_in[10], (const float*)d_in[14]};
    const float* w_hh[4] = {(const float*)d_in[3],  (const float*)d_in[7],
                            (const float*)d_in[11], (const float*)d_in[15]};
    const float* b_ih[4] = {(const float*)d_in[4],  (const float*)d_in[8],
                            (const float*)d_in[12], (const float*)d_in[16]};
    const float* b_hh[4] = {(const float*)d_in[5],  (const float*)d_in[9],
                            (const float*)d_in[13], (const float*)d_in[17]};
    const float* w_ff  = (const float*)d_in[18];
    const float* b_ff  = (const float*)d_in[19];
    const float* w_sbd = (const float*)d_in[20];
    const float* b_sbd = (const float*)d_in[21];
    float* out = (float*)d_out;
    char*  ws  = (char*)d_ws;

    const int M = B_ * SEQ_;   // 32768

    // ---- workspace layout (bytes) ------------------------------------------
    const size_t OFF_R1  = 0;                       // Acat0 (100.7MB) -> hcat (33.6MB)
    const size_t OFF_XP  = 100663296;               // xp_cat [M][2048] bf16 = 134.2MB
    const size_t OFF_WC  = OFF_XP + 268435456;      // Wcat pool
    const size_t OFF_WSW = OFF_WC + 17301504;       // 2MB swizzled w_hh
    const size_t OFF_BC  = OFF_WSW + 2097152;       // 2x2048 f32 bias concat

    unsigned short* Acat0 = (unsigned short*)(ws + OFF_R1);
    unsigned short* hcat  = (unsigned short*)(ws + OFF_R1);
    unsigned short* xpc   = (unsigned short*)(ws + OFF_XP);
    unsigned short* Wc0  = (unsigned short*)(ws + OFF_WC);              // 2048x2304 (3-term)
    unsigned short* Wc1  = Wc0 + (size_t)2048 * 2304;                   // 2048x1024 (2-term)
    unsigned short* Wcff = Wc1 + (size_t)2048 * 1024;                   // 512x1024  (2-term)
    short* wsw  = (short*)(ws + OFF_WSW);
    float* bc0  = (float*)(ws + OFF_BC);
    float* bc1  = bc0 + 2048;

    // ---- weight/bias conversions (independent of data path) ----------------
    wswz_kernel<<<4096, 256, 0, stream>>>(w_hh[0], w_hh[1], w_hh[2], w_hh[3], wsw);
    convw_kernel<<<(1024 * 768 + 255) / 256, 256, 0, stream>>>(w_ih[0], Wc0, 1024, 768, 3);
    convw_kernel<<<(1024 * 768 + 255) / 256, 256, 0, stream>>>(w_ih[1], Wc0 + (size_t)1024 * 2304, 1024, 768, 3);
    convw_kernel<<<(1024 * 512 + 255) / 256, 256, 0, stream>>>(w_ih[2], Wc1, 1024, 512, 2);
    convw_kernel<<<(1024 * 512 + 255) / 256, 256, 0, stream>>>(w_ih[3], Wc1 + (size_t)1024 * 1024, 1024, 512, 2);
    convw_kernel<<<(512 * 512 + 255) / 256, 256, 0, stream>>>(w_ff, Wcff, 512, 512, 2);
    biascat_kernel<<<8, 256, 0, stream>>>(b_ih[0], b_hh[0], b_ih[1], b_hh[1], bc0);
    biascat_kernel<<<8, 256, 0, stream>>>(b_ih[2], b_hh[2], b_ih[3], b_hh[3], bc1);
    outinit_kernel<<<256, 256, 0, stream>>>(b_sbd, out);

    // ---- data path ----------------------------------------------------------
    scatter_avg_kernel<<<B_, 256, 0, stream>>>(emb, wid, Acat0);

    // layer-0 merged projection (3-term, KA=2K=1536): [M][2048] bf16
    gemm_bf16_kernel<<<(2048 / 128) * (M / 128), 256, 0, stream>>>(
        Acat0, Wc0, bc0, xpc, M, 2048, 768, 1536);

    lstm_kernel<<<32, 512, 0, stream>>>(xpc, wsw, wsw + 262144, hcat);

    // layer-1 merged projection (2-term, A = hcat bf16, KA=K=512)
    gemm_bf16_kernel<<<(2048 / 128) * (M / 128), 256, 0, stream>>>(
        hcat, Wc1, bc1, xpc, M, 2048, 512, 512);

    lstm_kernel<<<32, 512, 0, stream>>>(xpc, wsw + 2 * 262144, wsw + 3 * 262144, hcat);

    // FF + fused logits (2-term)
    gemm_ff_logits_kernel<<<(512 / 128) * (M / 128), 256, 0, stream>>>(
        hcat, Wcff, b_ff, w_sbd, out, M, 512, 512);
}

// Round 13
// 1623.033 us; speedup vs baseline: 1.4380x; 1.1453x over previous
//
#include <hip/hip_runtime.h>
#include <cstddef>

#define B_    256
#define TSUB  192
#define SEQ_  128
#define D_    768
#define H_    256
#define G_    1024   // 4*H
#define DH_   512    // 2*H

typedef __attribute__((ext_vector_type(4))) float f32x4;
typedef __attribute__((ext_vector_type(8))) short bf16x8;
typedef __attribute__((ext_vector_type(4))) unsigned short u16x4;

__device__ __forceinline__ float rcpf_(float x) { return __builtin_amdgcn_rcpf(x); }
__device__ __forceinline__ float sigf_(float x)  { return rcpf_(1.0f + __expf(-x)); }
__device__ __forceinline__ float tanhf_(float x) { return 1.0f - 2.0f * rcpf_(__expf(2.0f * x) + 1.0f); }

__device__ __forceinline__ unsigned short f2bf_(float x) {
    unsigned u = __builtin_bit_cast(unsigned, x);
    return (unsigned short)((u + 0x7fffu + ((u >> 16) & 1u)) >> 16);
}
__device__ __forceinline__ float bf2f_(unsigned short h) {
    return __builtin_bit_cast(float, (unsigned)h << 16);
}
__device__ __forceinline__ void gload_lds16(const void* g, void* l) {
    __builtin_amdgcn_global_load_lds(
        (const __attribute__((address_space(1))) unsigned int*)g,
        (__attribute__((address_space(3))) unsigned int*)l, 16, 0, 0);
}

// ---------------------------------------------------------------------------
// Kernel 1: scatter-average -> bf16.  Writes A0[M][768] (hi only; L0 GEMM is
// now 2-term: A bf16 x W[hi|lo], r12 measured xp-bf16 rounding dominates).
// ---------------------------------------------------------------------------
__global__ __launch_bounds__(256) void scatter_avg_kernel(
    const float* __restrict__ emb, const int* __restrict__ wid,
    unsigned short* __restrict__ a0)
{
    const int b   = blockIdx.x;
    const int tid = threadIdx.x;
    __shared__ int s_wid[TSUB];
    __shared__ int s_start[SEQ_ + 1];

    for (int i = tid; i < TSUB; i += 256) s_wid[i] = wid[b * TSUB + i];
    __syncthreads();
    for (int s = tid; s <= SEQ_; s += 256) {
        int cnt = 0;
        for (int t = 0; t < TSUB; ++t) cnt += (s_wid[t] < s) ? 1 : 0;
        s_start[s] = cnt;
    }
    __syncthreads();

    const float* eb = emb + (size_t)b * TSUB * D_;
    for (int s = 0; s < SEQ_; ++s) {
        const int st = s_start[s], en = s_start[s + 1];
        const float inv = (en > st) ? 1.0f / (float)(en - st) : 0.0f;
        unsigned short* o = a0 + ((size_t)b * SEQ_ + s) * D_;
        for (int d = tid; d < D_; d += 256) {
            float sum = 0.0f;
            for (int t = st; t < en; ++t) sum += eb[(size_t)t * D_ + d];
            o[d] = f2bf_(sum * inv);
        }
    }
}

// ---------------------------------------------------------------------------
// Kernel 2: weight conversion  f32 W[N][K] -> bf16 Wcat[N][terms*K]
//   terms=2: [hi|lo] (both pair A)   terms=1: [hi] plain bf16
// ---------------------------------------------------------------------------
__global__ __launch_bounds__(256) void convw_kernel(
    const float* __restrict__ W, unsigned short* __restrict__ out,
    int N, int K, int terms)
{
    const int idx = blockIdx.x * 256 + threadIdx.x;
    if (idx >= N * K) return;
    const int n = idx / K, k = idx - n * K;
    const float x = W[idx];
    const unsigned short hi = f2bf_(x);
    const size_t ro = (size_t)n * terms * K;
    out[ro + k] = hi;
    if (terms == 2) out[ro + K + k] = f2bf_(x - bf2f_(hi));
}

// ---------------------------------------------------------------------------
// Kernel 3: bias concat  bcat[n] = b_ih+b_hh for fwd (n<1024) / bwd rows.
// ---------------------------------------------------------------------------
__global__ __launch_bounds__(256) void biascat_kernel(
    const float* __restrict__ bihf, const float* __restrict__ bhhf,
    const float* __restrict__ bihb, const float* __restrict__ bhhb,
    float* __restrict__ o)
{
    const int i = blockIdx.x * 256 + threadIdx.x;   // 0..2047
    o[i] = (i < 1024) ? (bihf[i] + bhhf[i]) : (bihb[i - 1024] + bhhb[i - 1024]);
}

// ---------------------------------------------------------------------------
// Kernel 4: out init with class bias.  out (B,2,SEQ) flat.
// ---------------------------------------------------------------------------
__global__ __launch_bounds__(256) void outinit_kernel(
    const float* __restrict__ b_sbd, float* __restrict__ out)
{
    const int i = blockIdx.x * 256 + threadIdx.x;   // 0..65535
    out[i] = b_sbd[(i >> 7) & 1];
}

// ---------------------------------------------------------------------------
// Kernel 5: bf16 MFMA GEMM, 128x128 tile, BK=64, global_load_lds width-16,
// XCD-swizzled 1D grid, T2 both-sides XOR swizzle (r11-verified).
//   C_bf16 = A[M][KA] x Wcat[N][KW] + bias,  ka = kw<K ? kw : kw-K.
// KA=K & KW=2K : 2-term Ahi*(Whi+Wlo).   KA=K & KW=K : plain bf16 GEMM.
// ---------------------------------------------------------------------------
__global__ __launch_bounds__(256) void gemm_bf16_kernel(
    const unsigned short* __restrict__ A, const unsigned short* __restrict__ Wc,
    const float* __restrict__ bias, unsigned short* __restrict__ C,
    int M, int N, int K, int KA, int KW)
{
    const int NT64 = KW >> 6;
    const int ntn  = N >> 7;
    const int id  = blockIdx.x;
    const int cpx = gridDim.x >> 3;
    const int swz = (id & 7) * cpx + (id >> 3);
    const int m0  = (swz / ntn) * 128;
    const int n0  = (swz % ntn) * 128;

    const int tid  = threadIdx.x;
    const int wv   = tid >> 6;
    const int lane = tid & 63;
    const int lm   = lane & 15, lk = lane >> 4;
    const int wr   = wv >> 1,   wc = wv & 1;

    __shared__ unsigned short As[128 * 64];   // 16 KB, [row][64], src-swizzled
    __shared__ unsigned short Bs[128 * 64];   // 16 KB

    const int sx = lm & 7;                    // read-side row XOR key

    f32x4 acc[4][4];
#pragma unroll
    for (int i = 0; i < 4; ++i)
#pragma unroll
        for (int j = 0; j < 4; ++j) acc[i][j] = (f32x4){0.f, 0.f, 0.f, 0.f};

    for (int kt = 0; kt < NT64; ++kt) {
        const int kw = kt << 6;
        const int ka = (kw < K) ? kw : kw - K;
        __syncthreads();   // previous tile fully consumed
#pragma unroll
        for (int l = 0; l < 4; ++l) {
            const int e   = l * 256 + tid;            // 0..1023
            const int row = e >> 3;                   // 0..127
            const int cs8 = (((e & 7) ^ (row & 7)) << 3);   // swizzled src chunk
            gload_lds16(A  + (size_t)(m0 + row) * KA + ka + cs8, As + e * 8);
            gload_lds16(Wc + (size_t)(n0 + row) * KW + kw + cs8, Bs + e * 8);
        }
        __syncthreads();   // staging complete

#pragma unroll
        for (int kh = 0; kh < 2; ++kh) {
            const int q = ((kh * 4 + lk) ^ sx) * 8;   // swizzled read chunk
            bf16x8 af[4], bfr[4];
#pragma unroll
            for (int mi = 0; mi < 4; ++mi)
                af[mi] = *(const bf16x8*)&As[(wr * 64 + mi * 16 + lm) * 64 + q];
#pragma unroll
            for (int nj = 0; nj < 4; ++nj)
                bfr[nj] = *(const bf16x8*)&Bs[(wc * 64 + nj * 16 + lm) * 64 + q];
#pragma unroll
            for (int mi = 0; mi < 4; ++mi)
#pragma unroll
                for (int nj = 0; nj < 4; ++nj)
                    acc[mi][nj] = __builtin_amdgcn_mfma_f32_16x16x32_bf16(
                        af[mi], bfr[nj], acc[mi][nj], 0, 0, 0);
        }
    }

#pragma unroll
    for (int mi = 0; mi < 4; ++mi)
#pragma unroll
        for (int nj = 0; nj < 4; ++nj) {
            const int gn = n0 + wc * 64 + nj * 16 + lm;
            const float bv = bias[gn];
#pragma unroll
            for (int r = 0; r < 4; ++r) {
                const int gm = m0 + wr * 64 + mi * 16 + lk * 4 + r;
                C[(size_t)gm * N + gn] = f2bf_(acc[mi][nj][r] + bv);
            }
        }
}

// ---------------------------------------------------------------------------
// Kernel 6: FF GEMM (1-term, KA=KW=K=512) with FUSED logits epilogue.
// ---------------------------------------------------------------------------
__global__ __launch_bounds__(256) void gemm_ff_logits_kernel(
    const unsigned short* __restrict__ A, const unsigned short* __restrict__ Wc,
    const float* __restrict__ bias, const float* __restrict__ w_sbd,
    float* __restrict__ out, int M, int N, int K)
{
    const int KA = K, KW = K;
    const int NT64 = KW >> 6;
    const int ntn  = N >> 7;
    const int id  = blockIdx.x;
    const int cpx = gridDim.x >> 3;
    const int swz = (id & 7) * cpx + (id >> 3);
    const int m0  = (swz / ntn) * 128;
    const int n0  = (swz % ntn) * 128;

    const int tid  = threadIdx.x;
    const int wv   = tid >> 6;
    const int lane = tid & 63;
    const int lm   = lane & 15, lk = lane >> 4;
    const int wr   = wv >> 1,   wc = wv & 1;

    __shared__ unsigned short As[128 * 64];
    __shared__ unsigned short Bs[128 * 64];

    const int sx = lm & 7;

    f32x4 acc[4][4];
#pragma unroll
    for (int i = 0; i < 4; ++i)
#pragma unroll
        for (int j = 0; j < 4; ++j) acc[i][j] = (f32x4){0.f, 0.f, 0.f, 0.f};

    for (int kt = 0; kt < NT64; ++kt) {
        const int kw = kt << 6;
        __syncthreads();
#pragma unroll
        for (int l = 0; l < 4; ++l) {
            const int e   = l * 256 + tid;
            const int row = e >> 3;
            const int cs8 = (((e & 7) ^ (row & 7)) << 3);
            gload_lds16(A  + (size_t)(m0 + row) * KA + kw + cs8, As + e * 8);
            gload_lds16(Wc + (size_t)(n0 + row) * KW + kw + cs8, Bs + e * 8);
        }
        __syncthreads();

#pragma unroll
        for (int kh = 0; kh < 2; ++kh) {
            const int q = ((kh * 4 + lk) ^ sx) * 8;
            bf16x8 af[4], bfr[4];
#pragma unroll
            for (int mi = 0; mi < 4; ++mi)
                af[mi] = *(const bf16x8*)&As[(wr * 64 + mi * 16 + lm) * 64 + q];
#pragma unroll
            for (int nj = 0; nj < 4; ++nj)
                bfr[nj] = *(const bf16x8*)&Bs[(wc * 64 + nj * 16 + lm) * 64 + q];
#pragma unroll
            for (int mi = 0; mi < 4; ++mi)
#pragma unroll
                for (int nj = 0; nj < 4; ++nj)
                    acc[mi][nj] = __builtin_amdgcn_mfma_f32_16x16x32_bf16(
                        af[mi], bfr[nj], acc[mi][nj], 0, 0, 0);
        }
    }

    // epilogue: relu + logits partial over this block's 128 n-cols
#pragma unroll
    for (int mi = 0; mi < 4; ++mi) {
        float ls0[4] = {0.f, 0.f, 0.f, 0.f};
        float ls1[4] = {0.f, 0.f, 0.f, 0.f};
#pragma unroll
        for (int nj = 0; nj < 4; ++nj) {
            const int gn = n0 + wc * 64 + nj * 16 + lm;
            const float bv = bias[gn];
            const float w0 = w_sbd[gn];
            const float w1 = w_sbd[512 + gn];
#pragma unroll
            for (int r = 0; r < 4; ++r) {
                const float v = fmaxf(acc[mi][nj][r] + bv, 0.0f);
                ls0[r] += v * w0;
                ls1[r] += v * w1;
            }
        }
#pragma unroll
        for (int r = 0; r < 4; ++r) {
            float v0 = ls0[r], v1 = ls1[r];
#pragma unroll
            for (int msk = 1; msk < 16; msk <<= 1) {
                v0 += __shfl_xor(v0, msk);
                v1 += __shfl_xor(v1, msk);
            }
            if (lm == 0) {
                const int gm = m0 + wr * 64 + mi * 16 + lk * 4 + r;
                const int base = (gm >> 7) * 256 + (gm & 127);
                atomicAdd(&out[base], v0);
                atomicAdd(&out[base + 128], v1);
            }
        }
    }
}

// ---------------------------------------------------------------------------
// Kernel 7: swizzle four w_hh (1024x256 f32) into bf16 MFMA A-fragment order
// for the 8-wave LSTM.  [mat][wv 8][kt 8][fr 8][lane 64][e 8]
//   fr = g*2+s:  n = g*256 + wv*32 + s*16 + (lane&15)
//   k  = kt*32 + (lane>>4)*8 + e
// ---------------------------------------------------------------------------
__global__ __launch_bounds__(256) void wswz_kernel(
    const float* __restrict__ w0, const float* __restrict__ w1,
    const float* __restrict__ w2, const float* __restrict__ w3,
    short* __restrict__ out)
{
    const int idx  = blockIdx.x * 256 + threadIdx.x;    // 4*262144
    const int mat  = idx >> 18;
    const int i2   = idx & 262143;
    const int e    = i2 & 7;
    const int l    = (i2 >> 3) & 63;
    const int fr   = (i2 >> 9) & 7;
    const int kt   = (i2 >> 12) & 7;
    const int wv   = (i2 >> 15) & 7;
    const int g    = fr >> 1, s = fr & 1;
    const int n    = g * 256 + wv * 32 + s * 16 + (l & 15);
    const int k    = kt * 32 + ((l >> 4) << 3) + e;
    const float* w = (mat == 0) ? w0 : (mat == 1) ? w1 : (mat == 2) ? w2 : w3;
    out[idx] = (short)f2bf_(w[n * H_ + k]);
}

// ---------------------------------------------------------------------------
// Kernel 8: persistent bidirectional LSTM, bf16 MFMA, WEIGHT-RESIDENT,
// double-buffered h + single LDS-only barrier per step (r7-verified).
// xp bf16 [M][2048] (dir*1024 offset).  h -> hcat[M][512] bf16.
// (byte-identical to the r12-verified kernel)
// ---------------------------------------------------------------------------
__global__ __launch_bounds__(512, 2) void lstm_kernel(
    const unsigned short* __restrict__ xpc,
    const short* __restrict__ wswf, const short* __restrict__ wswb,
    unsigned short* __restrict__ hcat)
{
    const int dir  = blockIdx.x >> 4;
    const int grp  = blockIdx.x & 15;
    const int tid  = threadIdx.x;
    const int wv   = tid >> 6;          // wave 0..7
    const int lane = tid & 63;
    const int lm   = lane & 15;
    const int lk   = lane >> 4;
    const unsigned short* xp = xpc + dir * 1024;
    const short* wsw = dir ? wswb : wswf;
    const int b0 = grp * 16;
    const int b  = lm;                  // this lane's batch column

    __shared__ short lds_w[65536];      // 128 KB: [wv 8][kt2 2][fr 8][512]
    __shared__ short h_lds[2][16 * 256];// 2 x 8 KB, [b][k] bf16, XOR-swizzled

    // ---- one-time staging --------------------------------------------------
    for (int i = tid; i < 16 * 256 / 2; i += 512) ((int*)h_lds[0])[i] = 0;
#pragma unroll
    for (int kt2 = 0; kt2 < 2; ++kt2)
#pragma unroll
        for (int fr = 0; fr < 8; ++fr) {
            const short* src = wsw + (((wv * 8 + 4 + kt2) * 8 + fr) << 9) + lane * 8;
            gload_lds16(src, &lds_w[((wv * 2 + kt2) * 8 + fr) << 9]);
        }
    bf16x8 awr[4][8];
#pragma unroll
    for (int kt = 0; kt < 4; ++kt)
#pragma unroll
        for (int fr = 0; fr < 8; ++fr)
            awr[kt][fr] = *(const bf16x8*)(wsw + (((wv * 8 + kt) * 8 + fr) << 9) + lane * 8);

    float c_st[2][4];
#pragma unroll
    for (int s = 0; s < 2; ++s)
#pragma unroll
        for (int r = 0; r < 4; ++r) c_st[s][r] = 0.0f;

    int nof[8];
#pragma unroll
    for (int fr = 0; fr < 8; ++fr)
        nof[fr] = (fr >> 1) * 256 + wv * 32 + (fr & 1) * 16 + lk * 4;

    __syncthreads();   // one-time: full drain ok

    // prefetch xp for step 0 (bf16)
    u16x4 xpre[8];
    {
        const int t0 = dir ? (SEQ_ - 1) : 0;
        const unsigned short* xr = xp + ((size_t)(b0 + b) * SEQ_ + t0) * 2048;
#pragma unroll
        for (int fr = 0; fr < 8; ++fr) xpre[fr] = *(const u16x4*)(xr + nof[fr]);
    }

    int cur = 0;
    for (int step = 0; step < SEQ_; ++step) {
        const int t = dir ? (SEQ_ - 1 - step) : step;
        const char* hr = (const char*)h_lds[0] + cur * 8192;
        char*       hw = (char*)h_lds[0] + (cur ^ 1) * 8192;

        f32x4 acc[8];
#pragma unroll
        for (int fr = 0; fr < 8; ++fr)
#pragma unroll
            for (int r = 0; r < 4; ++r) acc[fr][r] = bf2f_(xpre[fr][r]);

        // issue streamed kt=6 loads now
        bf16x8 aws6[8];
#pragma unroll
        for (int fr = 0; fr < 8; ++fr)
            aws6[fr] = *(const bf16x8*)(wsw + (((wv * 8 + 6) * 8 + fr) << 9) + lane * 8);

        // kt 0..3: register-resident weights
#pragma unroll
        for (int kt = 0; kt < 4; ++kt) {
            const int off = b * 512 + (((kt * 32 + lk * 8) * 2) ^ ((b & 7) << 4));
            const bf16x8 bh = *(const bf16x8*)(hr + off);
#pragma unroll
            for (int fr = 0; fr < 8; ++fr)
                acc[fr] = __builtin_amdgcn_mfma_f32_16x16x32_bf16(
                    awr[kt][fr], bh, acc[fr], 0, 0, 0);
        }

        // kt 4..5: LDS-resident weights
#pragma unroll
        for (int kt2 = 0; kt2 < 2; ++kt2) {
            const int kt = 4 + kt2;
            const int off = b * 512 + (((kt * 32 + lk * 8) * 2) ^ ((b & 7) << 4));
            const bf16x8 bh = *(const bf16x8*)(hr + off);
            bf16x8 al[8];
#pragma unroll
            for (int fr = 0; fr < 8; ++fr)
                al[fr] = *(const bf16x8*)&lds_w[(((wv * 2 + kt2) * 8 + fr) << 9) + lane * 8];
#pragma unroll
            for (int fr = 0; fr < 8; ++fr)
                acc[fr] = __builtin_amdgcn_mfma_f32_16x16x32_bf16(
                    al[fr], bh, acc[fr], 0, 0, 0);
        }

        // issue streamed kt=7 loads
        bf16x8 aws7[8];
#pragma unroll
        for (int fr = 0; fr < 8; ++fr)
            aws7[fr] = *(const bf16x8*)(wsw + (((wv * 8 + 7) * 8 + fr) << 9) + lane * 8);

        // kt 6
        {
            const int off = b * 512 + (((6 * 32 + lk * 8) * 2) ^ ((b & 7) << 4));
            const bf16x8 bh = *(const bf16x8*)(hr + off);
#pragma unroll
            for (int fr = 0; fr < 8; ++fr)
                acc[fr] = __builtin_amdgcn_mfma_f32_16x16x32_bf16(
                    aws6[fr], bh, acc[fr], 0, 0, 0);
        }
        // kt 7
        {
            const int off = b * 512 + (((7 * 32 + lk * 8) * 2) ^ ((b & 7) << 4));
            const bf16x8 bh = *(const bf16x8*)(hr + off);
#pragma unroll
            for (int fr = 0; fr < 8; ++fr)
                acc[fr] = __builtin_amdgcn_mfma_f32_16x16x32_bf16(
                    aws7[fr], bh, acc[fr], 0, 0, 0);
        }

        // prefetch xp for next step (in flight across the barrier)
        {
            const int tn = dir ? (t > 0 ? t - 1 : 0) : (t < SEQ_ - 1 ? t + 1 : t);
            const unsigned short* xr = xp + ((size_t)(b0 + b) * SEQ_ + tn) * 2048;
#pragma unroll
            for (int fr = 0; fr < 8; ++fr) xpre[fr] = *(const u16x4*)(xr + nof[fr]);
        }

        // pointwise: fr=g*2+s -> i:acc[s], f:acc[2+s], g:acc[4+s], o:acc[6+s]
#pragma unroll
        for (int s = 0; s < 2; ++s) {
            u16x4 hb;
#pragma unroll
            for (int r = 0; r < 4; ++r) {
                const float iv = sigf_(acc[s][r]);
                const float fv = sigf_(acc[2 + s][r]);
                const float gv = tanhf_(acc[4 + s][r]);
                const float ov = sigf_(acc[6 + s][r]);
                const float c  = fv * c_st[s][r] + iv * gv;
                c_st[s][r] = c;
                hb[r] = f2bf_(ov * tanhf_(c));
            }
            const int j0  = wv * 32 + s * 16 + lk * 4;
            const int off = b * 512 + ((j0 * 2) ^ ((b & 7) << 4));
            *(u16x4*)(hw + off) = hb;
            *(u16x4*)&hcat[((size_t)(b0 + b) * SEQ_ + t) * 512 + dir * 256 + j0] = hb;
        }

        // single per-step barrier: LDS-only drain; vmem stays in flight
        asm volatile("s_waitcnt lgkmcnt(0)" ::: "memory");
        __builtin_amdgcn_s_barrier();
        cur ^= 1;
    }
}

// ---------------------------------------------------------------------------
extern "C" void kernel_launch(void* const* d_in, const int* in_sizes, int n_in,
                              void* d_out, int out_size, void* d_ws, size_t ws_size,
                              hipStream_t stream)
{
    const float* emb   = (const float*)d_in[0];
    const int*   wid   = (const int*)d_in[1];
    const float* w_ih[4] = {(const float*)d_in[2],  (const float*)d_in[6],
                            (const float*)d_in[10], (const float*)d_in[14]};
    const float* w_hh[4] = {(const float*)d_in[3],  (const float*)d_in[7],
                            (const float*)d_in[11], (const float*)d_in[15]};
    const float* b_ih[4] = {(const float*)d_in[4],  (const float*)d_in[8],
                            (const float*)d_in[12], (const float*)d_in[16]};
    const float* b_hh[4] = {(const float*)d_in[5],  (const float*)d_in[9],
                            (const float*)d_in[13], (const float*)d_in[17]};
    const float* w_ff  = (const float*)d_in[18];
    const float* b_ff  = (const float*)d_in[19];
    const float* w_sbd = (const float*)d_in[20];
    const float* b_sbd = (const float*)d_in[21];
    float* out = (float*)d_out;
    char*  ws  = (char*)d_ws;

    const int M = B_ * SEQ_;   // 32768

    // ---- workspace layout (bytes) ------------------------------------------
    const size_t OFF_R1  = 0;                       // A0 (50.3MB) / hcat (33.6MB)
    const size_t OFF_XP  = 100663296;               // xp_cat [M][2048] bf16 = 134.2MB
    const size_t OFF_WC  = OFF_XP + 268435456;      // Wcat pool
    const size_t OFF_WSW = OFF_WC + 17301504;       // 2MB swizzled w_hh
    const size_t OFF_BC  = OFF_WSW + 2097152;       // 2x2048 f32 bias concat

    unsigned short* A0   = (unsigned short*)(ws + OFF_R1);
    unsigned short* hcat = (unsigned short*)(ws + OFF_R1);
    unsigned short* xpc  = (unsigned short*)(ws + OFF_XP);
    unsigned short* Wc0  = (unsigned short*)(ws + OFF_WC);              // 2048x1536 (2-term)
    unsigned short* Wc1  = Wc0 + (size_t)2048 * 1536;                   // 2048x512  (1-term)
    unsigned short* Wcff = Wc1 + (size_t)2048 * 512;                    // 512x512   (1-term)
    short* wsw  = (short*)(ws + OFF_WSW);
    float* bc0  = (float*)(ws + OFF_BC);
    float* bc1  = bc0 + 2048;

    // ---- weight/bias conversions (independent of data path) ----------------
    wswz_kernel<<<4096, 256, 0, stream>>>(w_hh[0], w_hh[1], w_hh[2], w_hh[3], wsw);
    convw_kernel<<<(1024 * 768 + 255) / 256, 256, 0, stream>>>(w_ih[0], Wc0, 1024, 768, 2);
    convw_kernel<<<(1024 * 768 + 255) / 256, 256, 0, stream>>>(w_ih[1], Wc0 + (size_t)1024 * 1536, 1024, 768, 2);
    convw_kernel<<<(1024 * 512 + 255) / 256, 256, 0, stream>>>(w_ih[2], Wc1, 1024, 512, 1);
    convw_kernel<<<(1024 * 512 + 255) / 256, 256, 0, stream>>>(w_ih[3], Wc1 + (size_t)1024 * 512, 1024, 512, 1);
    convw_kernel<<<(512 * 512 + 255) / 256, 256, 0, stream>>>(w_ff, Wcff, 512, 512, 1);
    biascat_kernel<<<8, 256, 0, stream>>>(b_ih[0], b_hh[0], b_ih[1], b_hh[1], bc0);
    biascat_kernel<<<8, 256, 0, stream>>>(b_ih[2], b_hh[2], b_ih[3], b_hh[3], bc1);
    outinit_kernel<<<256, 256, 0, stream>>>(b_sbd, out);

    // ---- data path ----------------------------------------------------------
    scatter_avg_kernel<<<B_, 256, 0, stream>>>(emb, wid, A0);

    // layer-0 merged projection (2-term: KA=768, KW=1536): [M][2048] bf16
    gemm_bf16_kernel<<<(2048 / 128) * (M / 128), 256, 0, stream>>>(
        A0, Wc0, bc0, xpc, M, 2048, 768, 768, 1536);

    lstm_kernel<<<32, 512, 0, stream>>>(xpc, wsw, wsw + 262144, hcat);

    // layer-1 merged projection (1-term: KA=KW=512)
    gemm_bf16_kernel<<<(2048 / 128) * (M / 128), 256, 0, stream>>>(
        hcat, Wc1, bc1, xpc, M, 2048, 512, 512, 512);

    lstm_kernel<<<32, 512, 0, stream>>>(xpc, wsw + 2 * 262144, wsw + 3 * 262144, hcat);

    // FF + fused logits (1-term)
    gemm_ff_logits_kernel<<<(512 / 128) * (M / 128), 256, 0, stream>>>(
        hcat, Wcff, b_ff, w_sbd, out, M, 512, 512);
}

// Round 14
// 1596.709 us; speedup vs baseline: 1.4617x; 1.0165x over previous
//
#include <hip/hip_runtime.h>
#include <cstddef>

#define B_    256
#define TSUB  192
#define SEQ_  128
#define D_    768
#define H_    256
#define G_    1024   // 4*H
#define DH_   512    // 2*H

typedef __attribute__((ext_vector_type(4))) float f32x4;
typedef __attribute__((ext_vector_type(8))) short bf16x8;
typedef __attribute__((ext_vector_type(4))) unsigned short u16x4;

__device__ __forceinline__ float rcpf_(float x) { return __builtin_amdgcn_rcpf(x); }
__device__ __forceinline__ float sigf_(float x)  { return rcpf_(1.0f + __expf(-x)); }
__device__ __forceinline__ float tanhf_(float x) { return 1.0f - 2.0f * rcpf_(__expf(2.0f * x) + 1.0f); }

__device__ __forceinline__ unsigned short f2bf_(float x) {
    unsigned u = __builtin_bit_cast(unsigned, x);
    return (unsigned short)((u + 0x7fffu + ((u >> 16) & 1u)) >> 16);
}
__device__ __forceinline__ float bf2f_(unsigned short h) {
    return __builtin_bit_cast(float, (unsigned)h << 16);
}
__device__ __forceinline__ void gload_lds16(const void* g, void* l) {
    __builtin_amdgcn_global_load_lds(
        (const __attribute__((address_space(1))) unsigned int*)g,
        (__attribute__((address_space(3))) unsigned int*)l, 16, 0, 0);
}

// ---------------------------------------------------------------------------
// Kernel 1: scatter-average -> bf16.  4 blocks per batch (32-slot quarters).
// ---------------------------------------------------------------------------
__global__ __launch_bounds__(256) void scatter_avg_kernel(
    const float* __restrict__ emb, const int* __restrict__ wid,
    unsigned short* __restrict__ a0)
{
    const int b   = blockIdx.x >> 2;
    const int qo  = (blockIdx.x & 3) * 32;
    const int tid = threadIdx.x;
    __shared__ int s_wid[TSUB];
    __shared__ int s_start[SEQ_ + 1];

    for (int i = tid; i < TSUB; i += 256) s_wid[i] = wid[b * TSUB + i];
    __syncthreads();
    for (int s = tid; s <= SEQ_; s += 256) {
        int cnt = 0;
        for (int t = 0; t < TSUB; ++t) cnt += (s_wid[t] < s) ? 1 : 0;
        s_start[s] = cnt;
    }
    __syncthreads();

    const float* eb = emb + (size_t)b * TSUB * D_;
    for (int s = qo; s < qo + 32; ++s) {
        const int st = s_start[s], en = s_start[s + 1];
        const float inv = (en > st) ? 1.0f / (float)(en - st) : 0.0f;
        unsigned short* o = a0 + ((size_t)b * SEQ_ + s) * D_;
        for (int d = tid; d < D_; d += 256) {
            float sum = 0.0f;
            for (int t = st; t < en; ++t) sum += eb[(size_t)t * D_ + d];
            o[d] = f2bf_(sum * inv);
        }
    }
}

// ---------------------------------------------------------------------------
// Kernel 2: weight conversion  f32 W[N][K] -> bf16 Wcat[N][terms*K]
// ---------------------------------------------------------------------------
__global__ __launch_bounds__(256) void convw_kernel(
    const float* __restrict__ W, unsigned short* __restrict__ out,
    int N, int K, int terms)
{
    const int idx = blockIdx.x * 256 + threadIdx.x;
    if (idx >= N * K) return;
    const int n = idx / K, k = idx - n * K;
    const float x = W[idx];
    const unsigned short hi = f2bf_(x);
    const size_t ro = (size_t)n * terms * K;
    out[ro + k] = hi;
    if (terms == 2) out[ro + K + k] = f2bf_(x - bf2f_(hi));
}

// ---------------------------------------------------------------------------
// Kernel 3: bias concat
// ---------------------------------------------------------------------------
__global__ __launch_bounds__(256) void biascat_kernel(
    const float* __restrict__ bihf, const float* __restrict__ bhhf,
    const float* __restrict__ bihb, const float* __restrict__ bhhb,
    float* __restrict__ o)
{
    const int i = blockIdx.x * 256 + threadIdx.x;
    o[i] = (i < 1024) ? (bihf[i] + bhhf[i]) : (bihb[i - 1024] + bhhb[i - 1024]);
}

// ---------------------------------------------------------------------------
// Kernel 4: out init with class bias.  out (B,2,SEQ) flat.
// ---------------------------------------------------------------------------
__global__ __launch_bounds__(256) void outinit_kernel(
    const float* __restrict__ b_sbd, float* __restrict__ out)
{
    const int i = blockIdx.x * 256 + threadIdx.x;
    out[i] = b_sbd[(i >> 7) & 1];
}

// ---------------------------------------------------------------------------
// Kernel 5: bf16 MFMA GEMM (r11/r13-verified: 128x128, BK=64, gload_lds16,
// XCD swizzle, T2 both-sides XOR swizzle).  ka = kw<K ? kw : kw-K.
// ---------------------------------------------------------------------------
__global__ __launch_bounds__(256) void gemm_bf16_kernel(
    const unsigned short* __restrict__ A, const unsigned short* __restrict__ Wc,
    const float* __restrict__ bias, unsigned short* __restrict__ C,
    int M, int N, int K, int KA, int KW)
{
    const int NT64 = KW >> 6;
    const int ntn  = N >> 7;
    const int id  = blockIdx.x;
    const int cpx = gridDim.x >> 3;
    const int swz = (id & 7) * cpx + (id >> 3);
    const int m0  = (swz / ntn) * 128;
    const int n0  = (swz % ntn) * 128;

    const int tid  = threadIdx.x;
    const int wv   = tid >> 6;
    const int lane = tid & 63;
    const int lm   = lane & 15, lk = lane >> 4;
    const int wr   = wv >> 1,   wc = wv & 1;

    __shared__ unsigned short As[128 * 64];
    __shared__ unsigned short Bs[128 * 64];

    const int sx = lm & 7;

    f32x4 acc[4][4];
#pragma unroll
    for (int i = 0; i < 4; ++i)
#pragma unroll
        for (int j = 0; j < 4; ++j) acc[i][j] = (f32x4){0.f, 0.f, 0.f, 0.f};

    for (int kt = 0; kt < NT64; ++kt) {
        const int kw = kt << 6;
        const int ka = (kw < K) ? kw : kw - K;
        __syncthreads();
#pragma unroll
        for (int l = 0; l < 4; ++l) {
            const int e   = l * 256 + tid;
            const int row = e >> 3;
            const int cs8 = (((e & 7) ^ (row & 7)) << 3);
            gload_lds16(A  + (size_t)(m0 + row) * KA + ka + cs8, As + e * 8);
            gload_lds16(Wc + (size_t)(n0 + row) * KW + kw + cs8, Bs + e * 8);
        }
        __syncthreads();

#pragma unroll
        for (int kh = 0; kh < 2; ++kh) {
            const int q = ((kh * 4 + lk) ^ sx) * 8;
            bf16x8 af[4], bfr[4];
#pragma unroll
            for (int mi = 0; mi < 4; ++mi)
                af[mi] = *(const bf16x8*)&As[(wr * 64 + mi * 16 + lm) * 64 + q];
#pragma unroll
            for (int nj = 0; nj < 4; ++nj)
                bfr[nj] = *(const bf16x8*)&Bs[(wc * 64 + nj * 16 + lm) * 64 + q];
#pragma unroll
            for (int mi = 0; mi < 4; ++mi)
#pragma unroll
                for (int nj = 0; nj < 4; ++nj)
                    acc[mi][nj] = __builtin_amdgcn_mfma_f32_16x16x32_bf16(
                        af[mi], bfr[nj], acc[mi][nj], 0, 0, 0);
        }
    }

#pragma unroll
    for (int mi = 0; mi < 4; ++mi)
#pragma unroll
        for (int nj = 0; nj < 4; ++nj) {
            const int gn = n0 + wc * 64 + nj * 16 + lm;
            const float bv = bias[gn];
#pragma unroll
            for (int r = 0; r < 4; ++r) {
                const int gm = m0 + wr * 64 + mi * 16 + lk * 4 + r;
                C[(size_t)gm * N + gn] = f2bf_(acc[mi][nj][r] + bv);
            }
        }
}

// ---------------------------------------------------------------------------
// Kernel 6: FF GEMM (1-term) with FUSED logits epilogue (r13-verified).
// ---------------------------------------------------------------------------
__global__ __launch_bounds__(256) void gemm_ff_logits_kernel(
    const unsigned short* __restrict__ A, const unsigned short* __restrict__ Wc,
    const float* __restrict__ bias, const float* __restrict__ w_sbd,
    float* __restrict__ out, int M, int N, int K)
{
    const int KA = K, KW = K;
    const int NT64 = KW >> 6;
    const int ntn  = N >> 7;
    const int id  = blockIdx.x;
    const int cpx = gridDim.x >> 3;
    const int swz = (id & 7) * cpx + (id >> 3);
    const int m0  = (swz / ntn) * 128;
    const int n0  = (swz % ntn) * 128;

    const int tid  = threadIdx.x;
    const int wv   = tid >> 6;
    const int lane = tid & 63;
    const int lm   = lane & 15, lk = lane >> 4;
    const int wr   = wv >> 1,   wc = wv & 1;

    __shared__ unsigned short As[128 * 64];
    __shared__ unsigned short Bs[128 * 64];

    const int sx = lm & 7;

    f32x4 acc[4][4];
#pragma unroll
    for (int i = 0; i < 4; ++i)
#pragma unroll
        for (int j = 0; j < 4; ++j) acc[i][j] = (f32x4){0.f, 0.f, 0.f, 0.f};

    for (int kt = 0; kt < NT64; ++kt) {
        const int kw = kt << 6;
        __syncthreads();
#pragma unroll
        for (int l = 0; l < 4; ++l) {
            const int e   = l * 256 + tid;
            const int row = e >> 3;
            const int cs8 = (((e & 7) ^ (row & 7)) << 3);
            gload_lds16(A  + (size_t)(m0 + row) * KA + kw + cs8, As + e * 8);
            gload_lds16(Wc + (size_t)(n0 + row) * KW + kw + cs8, Bs + e * 8);
        }
        __syncthreads();

#pragma unroll
        for (int kh = 0; kh < 2; ++kh) {
            const int q = ((kh * 4 + lk) ^ sx) * 8;
            bf16x8 af[4], bfr[4];
#pragma unroll
            for (int mi = 0; mi < 4; ++mi)
                af[mi] = *(const bf16x8*)&As[(wr * 64 + mi * 16 + lm) * 64 + q];
#pragma unroll
            for (int nj = 0; nj < 4; ++nj)
                bfr[nj] = *(const bf16x8*)&Bs[(wc * 64 + nj * 16 + lm) * 64 + q];
#pragma unroll
            for (int mi = 0; mi < 4; ++mi)
#pragma unroll
                for (int nj = 0; nj < 4; ++nj)
                    acc[mi][nj] = __builtin_amdgcn_mfma_f32_16x16x32_bf16(
                        af[mi], bfr[nj], acc[mi][nj], 0, 0, 0);
        }
    }

#pragma unroll
    for (int mi = 0; mi < 4; ++mi) {
        float ls0[4] = {0.f, 0.f, 0.f, 0.f};
        float ls1[4] = {0.f, 0.f, 0.f, 0.f};
#pragma unroll
        for (int nj = 0; nj < 4; ++nj) {
            const int gn = n0 + wc * 64 + nj * 16 + lm;
            const float bv = bias[gn];
            const float w0 = w_sbd[gn];
            const float w1 = w_sbd[512 + gn];
#pragma unroll
            for (int r = 0; r < 4; ++r) {
                const float v = fmaxf(acc[mi][nj][r] + bv, 0.0f);
                ls0[r] += v * w0;
                ls1[r] += v * w1;
            }
        }
#pragma unroll
        for (int r = 0; r < 4; ++r) {
            float v0 = ls0[r], v1 = ls1[r];
#pragma unroll
            for (int msk = 1; msk < 16; msk <<= 1) {
                v0 += __shfl_xor(v0, msk);
                v1 += __shfl_xor(v1, msk);
            }
            if (lm == 0) {
                const int gm = m0 + wr * 64 + mi * 16 + lk * 4 + r;
                const int base = (gm >> 7) * 256 + (gm & 127);
                atomicAdd(&out[base], v0);
                atomicAdd(&out[base + 128], v1);
            }
        }
    }
}

// ---------------------------------------------------------------------------
// Kernel 7: swizzle four w_hh into LSTM A-fragment order (r6-verified).
// ---------------------------------------------------------------------------
__global__ __launch_bounds__(256) void wswz_kernel(
    const float* __restrict__ w0, const float* __restrict__ w1,
    const float* __restrict__ w2, const float* __restrict__ w3,
    short* __restrict__ out)
{
    const int idx  = blockIdx.x * 256 + threadIdx.x;
    const int mat  = idx >> 18;
    const int i2   = idx & 262143;
    const int e    = i2 & 7;
    const int l    = (i2 >> 3) & 63;
    const int fr   = (i2 >> 9) & 7;
    const int kt   = (i2 >> 12) & 7;
    const int wv   = (i2 >> 15) & 7;
    const int g    = fr >> 1, s = fr & 1;
    const int n    = g * 256 + wv * 32 + s * 16 + (l & 15);
    const int k    = kt * 32 + ((l >> 4) << 3) + e;
    const float* w = (mat == 0) ? w0 : (mat == 1) ? w1 : (mat == 2) ? w2 : w3;
    out[idx] = (short)f2bf_(w[n * H_ + k]);
}

// ---------------------------------------------------------------------------
// Kernel 8: persistent bidirectional LSTM (r12-verified structure).
// r14 change: kt7 weight-load issue hoisted before the kt4-5 LDS section and
// xp(t+1) prefetch hoisted to the step top — more latency cover for the
// streamed loads; math/addresses identical.
// ---------------------------------------------------------------------------
__global__ __launch_bounds__(512, 2) void lstm_kernel(
    const unsigned short* __restrict__ xpc,
    const short* __restrict__ wswf, const short* __restrict__ wswb,
    unsigned short* __restrict__ hcat)
{
    const int dir  = blockIdx.x >> 4;
    const int grp  = blockIdx.x & 15;
    const int tid  = threadIdx.x;
    const int wv   = tid >> 6;
    const int lane = tid & 63;
    const int lm   = lane & 15;
    const int lk   = lane >> 4;
    const unsigned short* xp = xpc + dir * 1024;
    const short* wsw = dir ? wswb : wswf;
    const int b0 = grp * 16;
    const int b  = lm;

    __shared__ short lds_w[65536];
    __shared__ short h_lds[2][16 * 256];

    for (int i = tid; i < 16 * 256 / 2; i += 512) ((int*)h_lds[0])[i] = 0;
#pragma unroll
    for (int kt2 = 0; kt2 < 2; ++kt2)
#pragma unroll
        for (int fr = 0; fr < 8; ++fr) {
            const short* src = wsw + (((wv * 8 + 4 + kt2) * 8 + fr) << 9) + lane * 8;
            gload_lds16(src, &lds_w[((wv * 2 + kt2) * 8 + fr) << 9]);
        }
    bf16x8 awr[4][8];
#pragma unroll
    for (int kt = 0; kt < 4; ++kt)
#pragma unroll
        for (int fr = 0; fr < 8; ++fr)
            awr[kt][fr] = *(const bf16x8*)(wsw + (((wv * 8 + kt) * 8 + fr) << 9) + lane * 8);

    float c_st[2][4];
#pragma unroll
    for (int s = 0; s < 2; ++s)
#pragma unroll
        for (int r = 0; r < 4; ++r) c_st[s][r] = 0.0f;

    int nof[8];
#pragma unroll
    for (int fr = 0; fr < 8; ++fr)
        nof[fr] = (fr >> 1) * 256 + wv * 32 + (fr & 1) * 16 + lk * 4;

    __syncthreads();

    u16x4 xpre[8];
    {
        const int t0 = dir ? (SEQ_ - 1) : 0;
        const unsigned short* xr = xp + ((size_t)(b0 + b) * SEQ_ + t0) * 2048;
#pragma unroll
        for (int fr = 0; fr < 8; ++fr) xpre[fr] = *(const u16x4*)(xr + nof[fr]);
    }

    int cur = 0;
    for (int step = 0; step < SEQ_; ++step) {
        const int t = dir ? (SEQ_ - 1 - step) : step;
        const char* hr = (const char*)h_lds[0] + cur * 8192;
        char*       hw = (char*)h_lds[0] + (cur ^ 1) * 8192;

        f32x4 acc[8];
#pragma unroll
        for (int fr = 0; fr < 8; ++fr)
#pragma unroll
            for (int r = 0; r < 4; ++r) acc[fr][r] = bf2f_(xpre[fr][r]);

        // issue next-step xp prefetch NOW (max cover: full step in flight)
        {
            const int tn = dir ? (t > 0 ? t - 1 : 0) : (t < SEQ_ - 1 ? t + 1 : t);
            const unsigned short* xr = xp + ((size_t)(b0 + b) * SEQ_ + tn) * 2048;
#pragma unroll
            for (int fr = 0; fr < 8; ++fr) xpre[fr] = *(const u16x4*)(xr + nof[fr]);
        }

        // issue streamed kt=6 loads
        bf16x8 aws6[8];
#pragma unroll
        for (int fr = 0; fr < 8; ++fr)
            aws6[fr] = *(const bf16x8*)(wsw + (((wv * 8 + 6) * 8 + fr) << 9) + lane * 8);

        // kt 0..3: register-resident weights
#pragma unroll
        for (int kt = 0; kt < 4; ++kt) {
            const int off = b * 512 + (((kt * 32 + lk * 8) * 2) ^ ((b & 7) << 4));
            const bf16x8 bh = *(const bf16x8*)(hr + off);
#pragma unroll
            for (int fr = 0; fr < 8; ++fr)
                acc[fr] = __builtin_amdgcn_mfma_f32_16x16x32_bf16(
                    awr[kt][fr], bh, acc[fr], 0, 0, 0);
        }

        // issue streamed kt=7 loads (hoisted: covered by kt4-6 MFMA + LDS)
        bf16x8 aws7[8];
#pragma unroll
        for (int fr = 0; fr < 8; ++fr)
            aws7[fr] = *(const bf16x8*)(wsw + (((wv * 8 + 7) * 8 + fr) << 9) + lane * 8);

        // kt 4..5: LDS-resident weights
#pragma unroll
        for (int kt2 = 0; kt2 < 2; ++kt2) {
            const int kt = 4 + kt2;
            const int off = b * 512 + (((kt * 32 + lk * 8) * 2) ^ ((b & 7) << 4));
            const bf16x8 bh = *(const bf16x8*)(hr + off);
            bf16x8 al[8];
#pragma unroll
            for (int fr = 0; fr < 8; ++fr)
                al[fr] = *(const bf16x8*)&lds_w[(((wv * 2 + kt2) * 8 + fr) << 9) + lane * 8];
#pragma unroll
            for (int fr = 0; fr < 8; ++fr)
                acc[fr] = __builtin_amdgcn_mfma_f32_16x16x32_bf16(
                    al[fr], bh, acc[fr], 0, 0, 0);
        }

        // kt 6
        {
            const int off = b * 512 + (((6 * 32 + lk * 8) * 2) ^ ((b & 7) << 4));
            const bf16x8 bh = *(const bf16x8*)(hr + off);
#pragma unroll
            for (int fr = 0; fr < 8; ++fr)
                acc[fr] = __builtin_amdgcn_mfma_f32_16x16x32_bf16(
                    aws6[fr], bh, acc[fr], 0, 0, 0);
        }
        // kt 7
        {
            const int off = b * 512 + (((7 * 32 + lk * 8) * 2) ^ ((b & 7) << 4));
            const bf16x8 bh = *(const bf16x8*)(hr + off);
#pragma unroll
            for (int fr = 0; fr < 8; ++fr)
                acc[fr] = __builtin_amdgcn_mfma_f32_16x16x32_bf16(
                    aws7[fr], bh, acc[fr], 0, 0, 0);
        }

        // pointwise
#pragma unroll
        for (int s = 0; s < 2; ++s) {
            u16x4 hb;
#pragma unroll
            for (int r = 0; r < 4; ++r) {
                const float iv = sigf_(acc[s][r]);
                const float fv = sigf_(acc[2 + s][r]);
                const float gv = tanhf_(acc[4 + s][r]);
                const float ov = sigf_(acc[6 + s][r]);
                const float c  = fv * c_st[s][r] + iv * gv;
                c_st[s][r] = c;
                hb[r] = f2bf_(ov * tanhf_(c));
            }
            const int j0  = wv * 32 + s * 16 + lk * 4;
            const int off = b * 512 + ((j0 * 2) ^ ((b & 7) << 4));
            *(u16x4*)(hw + off) = hb;
            *(u16x4*)&hcat[((size_t)(b0 + b) * SEQ_ + t) * 512 + dir * 256 + j0] = hb;
        }

        // single per-step barrier: LDS-only drain; vmem stays in flight
        asm volatile("s_waitcnt lgkmcnt(0)" ::: "memory");
        __builtin_amdgcn_s_barrier();
        cur ^= 1;
    }
}

// ---------------------------------------------------------------------------
extern "C" void kernel_launch(void* const* d_in, const int* in_sizes, int n_in,
                              void* d_out, int out_size, void* d_ws, size_t ws_size,
                              hipStream_t stream)
{
    const float* emb   = (const float*)d_in[0];
    const int*   wid   = (const int*)d_in[1];
    const float* w_ih[4] = {(const float*)d_in[2],  (const float*)d_in[6],
                            (const float*)d_in[10], (const float*)d_in[14]};
    const float* w_hh[4] = {(const float*)d_in[3],  (const float*)d_in[7],
                            (const float*)d_in[11], (const float*)d_in[15]};
    const float* b_ih[4] = {(const float*)d_in[4],  (const float*)d_in[8],
                            (const float*)d_in[12], (const float*)d_in[16]};
    const float* b_hh[4] = {(const float*)d_in[5],  (const float*)d_in[9],
                            (const float*)d_in[13], (const float*)d_in[17]};
    const float* w_ff  = (const float*)d_in[18];
    const float* b_ff  = (const float*)d_in[19];
    const float* w_sbd = (const float*)d_in[20];
    const float* b_sbd = (const float*)d_in[21];
    float* out = (float*)d_out;
    char*  ws  = (char*)d_ws;

    const int M = B_ * SEQ_;   // 32768

    const size_t OFF_R1  = 0;
    const size_t OFF_XP  = 100663296;
    const size_t OFF_WC  = OFF_XP + 268435456;
    const size_t OFF_WSW = OFF_WC + 17301504;
    const size_t OFF_BC  = OFF_WSW + 2097152;

    unsigned short* A0   = (unsigned short*)(ws + OFF_R1);
    unsigned short* hcat = (unsigned short*)(ws + OFF_R1);
    unsigned short* xpc  = (unsigned short*)(ws + OFF_XP);
    unsigned short* Wc0  = (unsigned short*)(ws + OFF_WC);
    unsigned short* Wc1  = Wc0 + (size_t)2048 * 1536;
    unsigned short* Wcff = Wc1 + (size_t)2048 * 512;
    short* wsw  = (short*)(ws + OFF_WSW);
    float* bc0  = (float*)(ws + OFF_BC);
    float* bc1  = bc0 + 2048;

    wswz_kernel<<<4096, 256, 0, stream>>>(w_hh[0], w_hh[1], w_hh[2], w_hh[3], wsw);
    convw_kernel<<<(1024 * 768 + 255) / 256, 256, 0, stream>>>(w_ih[0], Wc0, 1024, 768, 2);
    convw_kernel<<<(1024 * 768 + 255) / 256, 256, 0, stream>>>(w_ih[1], Wc0 + (size_t)1024 * 1536, 1024, 768, 2);
    convw_kernel<<<(1024 * 512 + 255) / 256, 256, 0, stream>>>(w_ih[2], Wc1, 1024, 512, 1);
    convw_kernel<<<(1024 * 512 + 255) / 256, 256, 0, stream>>>(w_ih[3], Wc1 + (size_t)1024 * 512, 1024, 512, 1);
    convw_kernel<<<(512 * 512 + 255) / 256, 256, 0, stream>>>(w_ff, Wcff, 512, 512, 1);
    biascat_kernel<<<8, 256, 0, stream>>>(b_ih[0], b_hh[0], b_ih[1], b_hh[1], bc0);
    biascat_kernel<<<8, 256, 0, stream>>>(b_ih[2], b_hh[2], b_ih[3], b_hh[3], bc1);
    outinit_kernel<<<256, 256, 0, stream>>>(b_sbd, out);

    scatter_avg_kernel<<<B_ * 4, 256, 0, stream>>>(emb, wid, A0);

    gemm_bf16_kernel<<<(2048 / 128) * (M / 128), 256, 0, stream>>>(
        A0, Wc0, bc0, xpc, M, 2048, 768, 768, 1536);

    lstm_kernel<<<32, 512, 0, stream>>>(xpc, wsw, wsw + 262144, hcat);

    gemm_bf16_kernel<<<(2048 / 128) * (M / 128), 256, 0, stream>>>(
        hcat, Wc1, bc1, xpc, M, 2048, 512, 512, 512);

    lstm_kernel<<<32, 512, 0, stream>>>(xpc, wsw + 2 * 262144, wsw + 3 * 262144, hcat);

    gemm_ff_logits_kernel<<<(512 / 128) * (M / 128), 256, 0, stream>>>(
        hcat, Wcff, b_ff, w_sbd, out, M, 512, 512);
}

// Round 15
// 1455.312 us; speedup vs baseline: 1.6037x; 1.0972x over previous
//
#include <hip/hip_runtime.h>
#include <cstddef>

#define B_    256
#define TSUB  192
#define SEQ_  128
#define D_    768
#define H_    256
#define G_    1024   // 4*H
#define DH_   512    // 2*H

typedef __attribute__((ext_vector_type(4))) float f32x4;
typedef __attribute__((ext_vector_type(8))) short bf16x8;
typedef __attribute__((ext_vector_type(4))) unsigned short u16x4;

__device__ __forceinline__ float rcpf_(float x) { return __builtin_amdgcn_rcpf(x); }
__device__ __forceinline__ float sigf_(float x)  { return rcpf_(1.0f + __expf(-x)); }
__device__ __forceinline__ float tanhf_(float x) { return 1.0f - 2.0f * rcpf_(__expf(2.0f * x) + 1.0f); }

__device__ __forceinline__ unsigned short f2bf_(float x) {
    unsigned u = __builtin_bit_cast(unsigned, x);
    return (unsigned short)((u + 0x7fffu + ((u >> 16) & 1u)) >> 16);
}
__device__ __forceinline__ float bf2f_(unsigned short h) {
    return __builtin_bit_cast(float, (unsigned)h << 16);
}
__device__ __forceinline__ void gload_lds16(const void* g, void* l) {
    __builtin_amdgcn_global_load_lds(
        (const __attribute__((address_space(1))) unsigned int*)g,
        (__attribute__((address_space(3))) unsigned int*)l, 16, 0, 0);
}

// ---------------------------------------------------------------------------
// Kernel 1: scatter-average -> bf16.  4 blocks per batch (r14-verified).
// ---------------------------------------------------------------------------
__global__ __launch_bounds__(256) void scatter_avg_kernel(
    const float* __restrict__ emb, const int* __restrict__ wid,
    unsigned short* __restrict__ a0)
{
    const int b   = blockIdx.x >> 2;
    const int qo  = (blockIdx.x & 3) * 32;
    const int tid = threadIdx.x;
    __shared__ int s_wid[TSUB];
    __shared__ int s_start[SEQ_ + 1];

    for (int i = tid; i < TSUB; i += 256) s_wid[i] = wid[b * TSUB + i];
    __syncthreads();
    for (int s = tid; s <= SEQ_; s += 256) {
        int cnt = 0;
        for (int t = 0; t < TSUB; ++t) cnt += (s_wid[t] < s) ? 1 : 0;
        s_start[s] = cnt;
    }
    __syncthreads();

    const float* eb = emb + (size_t)b * TSUB * D_;
    for (int s = qo; s < qo + 32; ++s) {
        const int st = s_start[s], en = s_start[s + 1];
        const float inv = (en > st) ? 1.0f / (float)(en - st) : 0.0f;
        unsigned short* o = a0 + ((size_t)b * SEQ_ + s) * D_;
        for (int d = tid; d < D_; d += 256) {
            float sum = 0.0f;
            for (int t = st; t < en; ++t) sum += eb[(size_t)t * D_ + d];
            o[d] = f2bf_(sum * inv);
        }
    }
}

// ---------------------------------------------------------------------------
// Kernel 2: weight conversion  f32 W[N][K] -> bf16 Wcat[N][terms*K]
// ---------------------------------------------------------------------------
__global__ __launch_bounds__(256) void convw_kernel(
    const float* __restrict__ W, unsigned short* __restrict__ out,
    int N, int K, int terms)
{
    const int idx = blockIdx.x * 256 + threadIdx.x;
    if (idx >= N * K) return;
    const int n = idx / K, k = idx - n * K;
    const float x = W[idx];
    const unsigned short hi = f2bf_(x);
    const size_t ro = (size_t)n * terms * K;
    out[ro + k] = hi;
    if (terms == 2) out[ro + K + k] = f2bf_(x - bf2f_(hi));
}

// ---------------------------------------------------------------------------
// Kernel 3: bias concat
// ---------------------------------------------------------------------------
__global__ __launch_bounds__(256) void biascat_kernel(
    const float* __restrict__ bihf, const float* __restrict__ bhhf,
    const float* __restrict__ bihb, const float* __restrict__ bhhb,
    float* __restrict__ o)
{
    const int i = blockIdx.x * 256 + threadIdx.x;
    o[i] = (i < 1024) ? (bihf[i] + bhhf[i]) : (bihb[i - 1024] + bhhb[i - 1024]);
}

// ---------------------------------------------------------------------------
// Kernel 4: out init with class bias.  out (B,2,SEQ) flat.
// ---------------------------------------------------------------------------
__global__ __launch_bounds__(256) void outinit_kernel(
    const float* __restrict__ b_sbd, float* __restrict__ out)
{
    const int i = blockIdx.x * 256 + threadIdx.x;
    out[i] = b_sbd[(i >> 7) & 1];
}

// ---------------------------------------------------------------------------
// Kernel 5: bf16 MFMA GEMM (r11/r13-verified: 128x128, BK=64, gload_lds16,
// XCD swizzle, T2 both-sides XOR swizzle).  ka = kw<K ? kw : kw-K.
// ---------------------------------------------------------------------------
__global__ __launch_bounds__(256) void gemm_bf16_kernel(
    const unsigned short* __restrict__ A, const unsigned short* __restrict__ Wc,
    const float* __restrict__ bias, unsigned short* __restrict__ C,
    int M, int N, int K, int KA, int KW)
{
    const int NT64 = KW >> 6;
    const int ntn  = N >> 7;
    const int id  = blockIdx.x;
    const int cpx = gridDim.x >> 3;
    const int swz = (id & 7) * cpx + (id >> 3);
    const int m0  = (swz / ntn) * 128;
    const int n0  = (swz % ntn) * 128;

    const int tid  = threadIdx.x;
    const int wv   = tid >> 6;
    const int lane = tid & 63;
    const int lm   = lane & 15, lk = lane >> 4;
    const int wr   = wv >> 1,   wc = wv & 1;

    __shared__ unsigned short As[128 * 64];
    __shared__ unsigned short Bs[128 * 64];

    const int sx = lm & 7;

    f32x4 acc[4][4];
#pragma unroll
    for (int i = 0; i < 4; ++i)
#pragma unroll
        for (int j = 0; j < 4; ++j) acc[i][j] = (f32x4){0.f, 0.f, 0.f, 0.f};

    for (int kt = 0; kt < NT64; ++kt) {
        const int kw = kt << 6;
        const int ka = (kw < K) ? kw : kw - K;
        __syncthreads();
#pragma unroll
        for (int l = 0; l < 4; ++l) {
            const int e   = l * 256 + tid;
            const int row = e >> 3;
            const int cs8 = (((e & 7) ^ (row & 7)) << 3);
            gload_lds16(A  + (size_t)(m0 + row) * KA + ka + cs8, As + e * 8);
            gload_lds16(Wc + (size_t)(n0 + row) * KW + kw + cs8, Bs + e * 8);
        }
        __syncthreads();

#pragma unroll
        for (int kh = 0; kh < 2; ++kh) {
            const int q = ((kh * 4 + lk) ^ sx) * 8;
            bf16x8 af[4], bfr[4];
#pragma unroll
            for (int mi = 0; mi < 4; ++mi)
                af[mi] = *(const bf16x8*)&As[(wr * 64 + mi * 16 + lm) * 64 + q];
#pragma unroll
            for (int nj = 0; nj < 4; ++nj)
                bfr[nj] = *(const bf16x8*)&Bs[(wc * 64 + nj * 16 + lm) * 64 + q];
#pragma unroll
            for (int mi = 0; mi < 4; ++mi)
#pragma unroll
                for (int nj = 0; nj < 4; ++nj)
                    acc[mi][nj] = __builtin_amdgcn_mfma_f32_16x16x32_bf16(
                        af[mi], bfr[nj], acc[mi][nj], 0, 0, 0);
        }
    }

#pragma unroll
    for (int mi = 0; mi < 4; ++mi)
#pragma unroll
        for (int nj = 0; nj < 4; ++nj) {
            const int gn = n0 + wc * 64 + nj * 16 + lm;
            const float bv = bias[gn];
#pragma unroll
            for (int r = 0; r < 4; ++r) {
                const int gm = m0 + wr * 64 + mi * 16 + lk * 4 + r;
                C[(size_t)gm * N + gn] = f2bf_(acc[mi][nj][r] + bv);
            }
        }
}

// ---------------------------------------------------------------------------
// Kernel 6: FF GEMM (1-term) with FUSED logits epilogue (r13-verified).
// ---------------------------------------------------------------------------
__global__ __launch_bounds__(256) void gemm_ff_logits_kernel(
    const unsigned short* __restrict__ A, const unsigned short* __restrict__ Wc,
    const float* __restrict__ bias, const float* __restrict__ w_sbd,
    float* __restrict__ out, int M, int N, int K)
{
    const int KA = K, KW = K;
    const int NT64 = KW >> 6;
    const int ntn  = N >> 7;
    const int id  = blockIdx.x;
    const int cpx = gridDim.x >> 3;
    const int swz = (id & 7) * cpx + (id >> 3);
    const int m0  = (swz / ntn) * 128;
    const int n0  = (swz % ntn) * 128;

    const int tid  = threadIdx.x;
    const int wv   = tid >> 6;
    const int lane = tid & 63;
    const int lm   = lane & 15, lk = lane >> 4;
    const int wr   = wv >> 1,   wc = wv & 1;

    __shared__ unsigned short As[128 * 64];
    __shared__ unsigned short Bs[128 * 64];

    const int sx = lm & 7;

    f32x4 acc[4][4];
#pragma unroll
    for (int i = 0; i < 4; ++i)
#pragma unroll
        for (int j = 0; j < 4; ++j) acc[i][j] = (f32x4){0.f, 0.f, 0.f, 0.f};

    for (int kt = 0; kt < NT64; ++kt) {
        const int kw = kt << 6;
        __syncthreads();
#pragma unroll
        for (int l = 0; l < 4; ++l) {
            const int e   = l * 256 + tid;
            const int row = e >> 3;
            const int cs8 = (((e & 7) ^ (row & 7)) << 3);
            gload_lds16(A  + (size_t)(m0 + row) * KA + kw + cs8, As + e * 8);
            gload_lds16(Wc + (size_t)(n0 + row) * KW + kw + cs8, Bs + e * 8);
        }
        __syncthreads();

#pragma unroll
        for (int kh = 0; kh < 2; ++kh) {
            const int q = ((kh * 4 + lk) ^ sx) * 8;
            bf16x8 af[4], bfr[4];
#pragma unroll
            for (int mi = 0; mi < 4; ++mi)
                af[mi] = *(const bf16x8*)&As[(wr * 64 + mi * 16 + lm) * 64 + q];
#pragma unroll
            for (int nj = 0; nj < 4; ++nj)
                bfr[nj] = *(const bf16x8*)&Bs[(wc * 64 + nj * 16 + lm) * 64 + q];
#pragma unroll
            for (int mi = 0; mi < 4; ++mi)
#pragma unroll
                for (int nj = 0; nj < 4; ++nj)
                    acc[mi][nj] = __builtin_amdgcn_mfma_f32_16x16x32_bf16(
                        af[mi], bfr[nj], acc[mi][nj], 0, 0, 0);
        }
    }

#pragma unroll
    for (int mi = 0; mi < 4; ++mi) {
        float ls0[4] = {0.f, 0.f, 0.f, 0.f};
        float ls1[4] = {0.f, 0.f, 0.f, 0.f};
#pragma unroll
        for (int nj = 0; nj < 4; ++nj) {
            const int gn = n0 + wc * 64 + nj * 16 + lm;
            const float bv = bias[gn];
            const float w0 = w_sbd[gn];
            const float w1 = w_sbd[512 + gn];
#pragma unroll
            for (int r = 0; r < 4; ++r) {
                const float v = fmaxf(acc[mi][nj][r] + bv, 0.0f);
                ls0[r] += v * w0;
                ls1[r] += v * w1;
            }
        }
#pragma unroll
        for (int r = 0; r < 4; ++r) {
            float v0 = ls0[r], v1 = ls1[r];
#pragma unroll
            for (int msk = 1; msk < 16; msk <<= 1) {
                v0 += __shfl_xor(v0, msk);
                v1 += __shfl_xor(v1, msk);
            }
            if (lm == 0) {
                const int gm = m0 + wr * 64 + mi * 16 + lk * 4 + r;
                const int base = (gm >> 7) * 256 + (gm & 127);
                atomicAdd(&out[base], v0);
                atomicAdd(&out[base + 128], v1);
            }
        }
    }
}

// ---------------------------------------------------------------------------
// Kernel 7: swizzle four w_hh into LSTM A-fragment order (r6-verified).
// ---------------------------------------------------------------------------
__global__ __launch_bounds__(256) void wswz_kernel(
    const float* __restrict__ w0, const float* __restrict__ w1,
    const float* __restrict__ w2, const float* __restrict__ w3,
    short* __restrict__ out)
{
    const int idx  = blockIdx.x * 256 + threadIdx.x;
    const int mat  = idx >> 18;
    const int i2   = idx & 262143;
    const int e    = i2 & 7;
    const int l    = (i2 >> 3) & 63;
    const int fr   = (i2 >> 9) & 7;
    const int kt   = (i2 >> 12) & 7;
    const int wv   = (i2 >> 15) & 7;
    const int g    = fr >> 1, s = fr & 1;
    const int n    = g * 256 + wv * 32 + s * 16 + (l & 15);
    const int k    = kt * 32 + ((l >> 4) << 3) + e;
    const float* w = (mat == 0) ? w0 : (mat == 1) ? w1 : (mat == 2) ? w2 : w3;
    out[idx] = (short)f2bf_(w[n * H_ + k]);
}

// ---------------------------------------------------------------------------
// Kernel 8: persistent bidirectional LSTM — byte-identical to the r13-verified
// kernel (487 us).  r14's load-hoist reorder REGRESSED (550 us) and is
// reverted: at 2 waves/SIMD the longer live ranges hurt more than the
// latency cover helped.
// ---------------------------------------------------------------------------
__global__ __launch_bounds__(512, 2) void lstm_kernel(
    const unsigned short* __restrict__ xpc,
    const short* __restrict__ wswf, const short* __restrict__ wswb,
    unsigned short* __restrict__ hcat)
{
    const int dir  = blockIdx.x >> 4;
    const int grp  = blockIdx.x & 15;
    const int tid  = threadIdx.x;
    const int wv   = tid >> 6;          // wave 0..7
    const int lane = tid & 63;
    const int lm   = lane & 15;
    const int lk   = lane >> 4;
    const unsigned short* xp = xpc + dir * 1024;
    const short* wsw = dir ? wswb : wswf;
    const int b0 = grp * 16;
    const int b  = lm;                  // this lane's batch column

    __shared__ short lds_w[65536];      // 128 KB: [wv 8][kt2 2][fr 8][512]
    __shared__ short h_lds[2][16 * 256];// 2 x 8 KB, [b][k] bf16, XOR-swizzled

    // ---- one-time staging --------------------------------------------------
    for (int i = tid; i < 16 * 256 / 2; i += 512) ((int*)h_lds[0])[i] = 0;
#pragma unroll
    for (int kt2 = 0; kt2 < 2; ++kt2)
#pragma unroll
        for (int fr = 0; fr < 8; ++fr) {
            const short* src = wsw + (((wv * 8 + 4 + kt2) * 8 + fr) << 9) + lane * 8;
            gload_lds16(src, &lds_w[((wv * 2 + kt2) * 8 + fr) << 9]);
        }
    bf16x8 awr[4][8];
#pragma unroll
    for (int kt = 0; kt < 4; ++kt)
#pragma unroll
        for (int fr = 0; fr < 8; ++fr)
            awr[kt][fr] = *(const bf16x8*)(wsw + (((wv * 8 + kt) * 8 + fr) << 9) + lane * 8);

    float c_st[2][4];
#pragma unroll
    for (int s = 0; s < 2; ++s)
#pragma unroll
        for (int r = 0; r < 4; ++r) c_st[s][r] = 0.0f;

    int nof[8];
#pragma unroll
    for (int fr = 0; fr < 8; ++fr)
        nof[fr] = (fr >> 1) * 256 + wv * 32 + (fr & 1) * 16 + lk * 4;

    __syncthreads();   // one-time: full drain ok

    // prefetch xp for step 0 (bf16)
    u16x4 xpre[8];
    {
        const int t0 = dir ? (SEQ_ - 1) : 0;
        const unsigned short* xr = xp + ((size_t)(b0 + b) * SEQ_ + t0) * 2048;
#pragma unroll
        for (int fr = 0; fr < 8; ++fr) xpre[fr] = *(const u16x4*)(xr + nof[fr]);
    }

    int cur = 0;
    for (int step = 0; step < SEQ_; ++step) {
        const int t = dir ? (SEQ_ - 1 - step) : step;
        const char* hr = (const char*)h_lds[0] + cur * 8192;
        char*       hw = (char*)h_lds[0] + (cur ^ 1) * 8192;

        f32x4 acc[8];
#pragma unroll
        for (int fr = 0; fr < 8; ++fr)
#pragma unroll
            for (int r = 0; r < 4; ++r) acc[fr][r] = bf2f_(xpre[fr][r]);

        // issue streamed kt=6 loads now
        bf16x8 aws6[8];
#pragma unroll
        for (int fr = 0; fr < 8; ++fr)
            aws6[fr] = *(const bf16x8*)(wsw + (((wv * 8 + 6) * 8 + fr) << 9) + lane * 8);

        // kt 0..3: register-resident weights
#pragma unroll
        for (int kt = 0; kt < 4; ++kt) {
            const int off = b * 512 + (((kt * 32 + lk * 8) * 2) ^ ((b & 7) << 4));
            const bf16x8 bh = *(const bf16x8*)(hr + off);
#pragma unroll
            for (int fr = 0; fr < 8; ++fr)
                acc[fr] = __builtin_amdgcn_mfma_f32_16x16x32_bf16(
                    awr[kt][fr], bh, acc[fr], 0, 0, 0);
        }

        // kt 4..5: LDS-resident weights
#pragma unroll
        for (int kt2 = 0; kt2 < 2; ++kt2) {
            const int kt = 4 + kt2;
            const int off = b * 512 + (((kt * 32 + lk * 8) * 2) ^ ((b & 7) << 4));
            const bf16x8 bh = *(const bf16x8*)(hr + off);
            bf16x8 al[8];
#pragma unroll
            for (int fr = 0; fr < 8; ++fr)
                al[fr] = *(const bf16x8*)&lds_w[(((wv * 2 + kt2) * 8 + fr) << 9) + lane * 8];
#pragma unroll
            for (int fr = 0; fr < 8; ++fr)
                acc[fr] = __builtin_amdgcn_mfma_f32_16x16x32_bf16(
                    al[fr], bh, acc[fr], 0, 0, 0);
        }

        // issue streamed kt=7 loads
        bf16x8 aws7[8];
#pragma unroll
        for (int fr = 0; fr < 8; ++fr)
            aws7[fr] = *(const bf16x8*)(wsw + (((wv * 8 + 7) * 8 + fr) << 9) + lane * 8);

        // kt 6
        {
            const int off = b * 512 + (((6 * 32 + lk * 8) * 2) ^ ((b & 7) << 4));
            const bf16x8 bh = *(const bf16x8*)(hr + off);
#pragma unroll
            for (int fr = 0; fr < 8; ++fr)
                acc[fr] = __builtin_amdgcn_mfma_f32_16x16x32_bf16(
                    aws6[fr], bh, acc[fr], 0, 0, 0);
        }
        // kt 7
        {
            const int off = b * 512 + (((7 * 32 + lk * 8) * 2) ^ ((b & 7) << 4));
            const bf16x8 bh = *(const bf16x8*)(hr + off);
#pragma unroll
            for (int fr = 0; fr < 8; ++fr)
                acc[fr] = __builtin_amdgcn_mfma_f32_16x16x32_bf16(
                    aws7[fr], bh, acc[fr], 0, 0, 0);
        }

        // prefetch xp for next step (in flight across the barrier)
        {
            const int tn = dir ? (t > 0 ? t - 1 : 0) : (t < SEQ_ - 1 ? t + 1 : t);
            const unsigned short* xr = xp + ((size_t)(b0 + b) * SEQ_ + tn) * 2048;
#pragma unroll
            for (int fr = 0; fr < 8; ++fr) xpre[fr] = *(const u16x4*)(xr + nof[fr]);
        }

        // pointwise: fr=g*2+s -> i:acc[s], f:acc[2+s], g:acc[4+s], o:acc[6+s]
#pragma unroll
        for (int s = 0; s < 2; ++s) {
            u16x4 hb;
#pragma unroll
            for (int r = 0; r < 4; ++r) {
                const float iv = sigf_(acc[s][r]);
                const float fv = sigf_(acc[2 + s][r]);
                const float gv = tanhf_(acc[4 + s][r]);
                const float ov = sigf_(acc[6 + s][r]);
                const float c  = fv * c_st[s][r] + iv * gv;
                c_st[s][r] = c;
                hb[r] = f2bf_(ov * tanhf_(c));
            }
            const int j0  = wv * 32 + s * 16 + lk * 4;
            const int off = b * 512 + ((j0 * 2) ^ ((b & 7) << 4));
            *(u16x4*)(hw + off) = hb;
            *(u16x4*)&hcat[((size_t)(b0 + b) * SEQ_ + t) * 512 + dir * 256 + j0] = hb;
        }

        // single per-step barrier: LDS-only drain; vmem stays in flight
        asm volatile("s_waitcnt lgkmcnt(0)" ::: "memory");
        __builtin_amdgcn_s_barrier();
        cur ^= 1;
    }
}

// ---------------------------------------------------------------------------
extern "C" void kernel_launch(void* const* d_in, const int* in_sizes, int n_in,
                              void* d_out, int out_size, void* d_ws, size_t ws_size,
                              hipStream_t stream)
{
    const float* emb   = (const float*)d_in[0];
    const int*   wid   = (const int*)d_in[1];
    const float* w_ih[4] = {(const float*)d_in[2],  (const float*)d_in[6],
                            (const float*)d_in[10], (const float*)d_in[14]};
    const float* w_hh[4] = {(const float*)d_in[3],  (const float*)d_in[7],
                            (const float*)d_in[11], (const float*)d_in[15]};
    const float* b_ih[4] = {(const float*)d_in[4],  (const float*)d_in[8],
                            (const float*)d_in[12], (const float*)d_in[16]};
    const float* b_hh[4] = {(const float*)d_in[5],  (const float*)d_in[9],
                            (const float*)d_in[13], (const float*)d_in[17]};
    const float* w_ff  = (const float*)d_in[18];
    const float* b_ff  = (const float*)d_in[19];
    const float* w_sbd = (const float*)d_in[20];
    const float* b_sbd = (const float*)d_in[21];
    float* out = (float*)d_out;
    char*  ws  = (char*)d_ws;

    const int M = B_ * SEQ_;   // 32768

    const size_t OFF_R1  = 0;
    const size_t OFF_XP  = 100663296;
    const size_t OFF_WC  = OFF_XP + 268435456;
    const size_t OFF_WSW = OFF_WC + 17301504;
    const size_t OFF_BC  = OFF_WSW + 2097152;

    unsigned short* A0   = (unsigned short*)(ws + OFF_R1);
    unsigned short* hcat = (unsigned short*)(ws + OFF_R1);
    unsigned short* xpc  = (unsigned short*)(ws + OFF_XP);
    unsigned short* Wc0  = (unsigned short*)(ws + OFF_WC);
    unsigned short* Wc1  = Wc0 + (size_t)2048 * 1536;
    unsigned short* Wcff = Wc1 + (size_t)2048 * 512;
    short* wsw  = (short*)(ws + OFF_WSW);
    float* bc0  = (float*)(ws + OFF_BC);
    float* bc1  = bc0 + 2048;

    wswz_kernel<<<4096, 256, 0, stream>>>(w_hh[0], w_hh[1], w_hh[2], w_hh[3], wsw);
    convw_kernel<<<(1024 * 768 + 255) / 256, 256, 0, stream>>>(w_ih[0], Wc0, 1024, 768, 2);
    convw_kernel<<<(1024 * 768 + 255) / 256, 256, 0, stream>>>(w_ih[1], Wc0 + (size_t)1024 * 1536, 1024, 768, 2);
    convw_kernel<<<(1024 * 512 + 255) / 256, 256, 0, stream>>>(w_ih[2], Wc1, 1024, 512, 1);
    convw_kernel<<<(1024 * 512 + 255) / 256, 256, 0, stream>>>(w_ih[3], Wc1 + (size_t)1024 * 512, 1024, 512, 1);
    convw_kernel<<<(512 * 512 + 255) / 256, 256, 0, stream>>>(w_ff, Wcff, 512, 512, 1);
    biascat_kernel<<<8, 256, 0, stream>>>(b_ih[0], b_hh[0], b_ih[1], b_hh[1], bc0);
    biascat_kernel<<<8, 256, 0, stream>>>(b_ih[2], b_hh[2], b_ih[3], b_hh[3], bc1);
    outinit_kernel<<<256, 256, 0, stream>>>(b_sbd, out);

    scatter_avg_kernel<<<B_ * 4, 256, 0, stream>>>(emb, wid, A0);

    gemm_bf16_kernel<<<(2048 / 128) * (M / 128), 256, 0, stream>>>(
        A0, Wc0, bc0, xpc, M, 2048, 768, 768, 1536);

    lstm_kernel<<<32, 512, 0, stream>>>(xpc, wsw, wsw + 262144, hcat);

    gemm_bf16_kernel<<<(2048 / 128) * (M / 128), 256, 0, stream>>>(
        hcat, Wc1, bc1, xpc, M, 2048, 512, 512, 512);

    lstm_kernel<<<32, 512, 0, stream>>>(xpc, wsw + 2 * 262144, wsw + 3 * 262144, hcat);

    gemm_ff_logits_kernel<<<(512 / 128) * (M / 128), 256, 0, stream>>>(
        hcat, Wcff, b_ff, w_sbd, out, M, 512, 512);
}

// Round 16
// 1353.407 us; speedup vs baseline: 1.7245x; 1.0753x over previous
//
#include <hip/hip_runtime.h>
#include <cstddef>

#define B_    256
#define TSUB  192
#define SEQ_  128
#define D_    768
#define H_    256
#define G_    1024   // 4*H
#define DH_   512    // 2*H

typedef __attribute__((ext_vector_type(4))) float f32x4;
typedef __attribute__((ext_vector_type(8))) short bf16x8;
typedef __attribute__((ext_vector_type(4))) unsigned short u16x4;

__device__ __forceinline__ float rcpf_(float x) { return __builtin_amdgcn_rcpf(x); }
__device__ __forceinline__ float sigf_(float x)  { return rcpf_(1.0f + __expf(-x)); }
__device__ __forceinline__ float tanhf_(float x) { return 1.0f - 2.0f * rcpf_(__expf(2.0f * x) + 1.0f); }

__device__ __forceinline__ unsigned short f2bf_(float x) {
    unsigned u = __builtin_bit_cast(unsigned, x);
    return (unsigned short)((u + 0x7fffu + ((u >> 16) & 1u)) >> 16);
}
__device__ __forceinline__ float bf2f_(unsigned short h) {
    return __builtin_bit_cast(float, (unsigned)h << 16);
}
__device__ __forceinline__ void gload_lds16(const void* g, void* l) {
    __builtin_amdgcn_global_load_lds(
        (const __attribute__((address_space(1))) unsigned int*)g,
        (__attribute__((address_space(3))) unsigned int*)l, 16, 0, 0);
}

// ---------------------------------------------------------------------------
// Kernel 1: scatter-average -> bf16.  4 blocks per batch (r14-verified).
// ---------------------------------------------------------------------------
__global__ __launch_bounds__(256) void scatter_avg_kernel(
    const float* __restrict__ emb, const int* __restrict__ wid,
    unsigned short* __restrict__ a0)
{
    const int b   = blockIdx.x >> 2;
    const int qo  = (blockIdx.x & 3) * 32;
    const int tid = threadIdx.x;
    __shared__ int s_wid[TSUB];
    __shared__ int s_start[SEQ_ + 1];

    for (int i = tid; i < TSUB; i += 256) s_wid[i] = wid[b * TSUB + i];
    __syncthreads();
    for (int s = tid; s <= SEQ_; s += 256) {
        int cnt = 0;
        for (int t = 0; t < TSUB; ++t) cnt += (s_wid[t] < s) ? 1 : 0;
        s_start[s] = cnt;
    }
    __syncthreads();

    const float* eb = emb + (size_t)b * TSUB * D_;
    for (int s = qo; s < qo + 32; ++s) {
        const int st = s_start[s], en = s_start[s + 1];
        const float inv = (en > st) ? 1.0f / (float)(en - st) : 0.0f;
        unsigned short* o = a0 + ((size_t)b * SEQ_ + s) * D_;
        for (int d = tid; d < D_; d += 256) {
            float sum = 0.0f;
            for (int t = st; t < en; ++t) sum += eb[(size_t)t * D_ + d];
            o[d] = f2bf_(sum * inv);
        }
    }
}

// ---------------------------------------------------------------------------
// Kernel 2: weight conversion  f32 W[N][K] -> bf16 Wcat[N][terms*K]
// ---------------------------------------------------------------------------
__global__ __launch_bounds__(256) void convw_kernel(
    const float* __restrict__ W, unsigned short* __restrict__ out,
    int N, int K, int terms)
{
    const int idx = blockIdx.x * 256 + threadIdx.x;
    if (idx >= N * K) return;
    const int n = idx / K, k = idx - n * K;
    const float x = W[idx];
    const unsigned short hi = f2bf_(x);
    const size_t ro = (size_t)n * terms * K;
    out[ro + k] = hi;
    if (terms == 2) out[ro + K + k] = f2bf_(x - bf2f_(hi));
}

// ---------------------------------------------------------------------------
// Kernel 3: bias concat
// ---------------------------------------------------------------------------
__global__ __launch_bounds__(256) void biascat_kernel(
    const float* __restrict__ bihf, const float* __restrict__ bhhf,
    const float* __restrict__ bihb, const float* __restrict__ bhhb,
    float* __restrict__ o)
{
    const int i = blockIdx.x * 256 + threadIdx.x;
    o[i] = (i < 1024) ? (bihf[i] + bhhf[i]) : (bihb[i - 1024] + bhhb[i - 1024]);
}

// ---------------------------------------------------------------------------
// Kernel 4: out init with class bias.  out (B,2,SEQ) flat.
// ---------------------------------------------------------------------------
__global__ __launch_bounds__(256) void outinit_kernel(
    const float* __restrict__ b_sbd, float* __restrict__ out)
{
    const int i = blockIdx.x * 256 + threadIdx.x;
    out[i] = b_sbd[(i >> 7) & 1];
}

// ---------------------------------------------------------------------------
// Kernel 5: bf16 MFMA GEMM (r11/r13-verified: 128x128, BK=64, gload_lds16,
// XCD swizzle, T2 both-sides XOR swizzle).  ka = kw<K ? kw : kw-K.
// KW=2K: 2-term A*(Whi+Wlo).  KW=K: plain bf16 GEMM.
// ---------------------------------------------------------------------------
__global__ __launch_bounds__(256) void gemm_bf16_kernel(
    const unsigned short* __restrict__ A, const unsigned short* __restrict__ Wc,
    const float* __restrict__ bias, unsigned short* __restrict__ C,
    int M, int N, int K, int KA, int KW)
{
    const int NT64 = KW >> 6;
    const int ntn  = N >> 7;
    const int id  = blockIdx.x;
    const int cpx = gridDim.x >> 3;
    const int swz = (id & 7) * cpx + (id >> 3);
    const int m0  = (swz / ntn) * 128;
    const int n0  = (swz % ntn) * 128;

    const int tid  = threadIdx.x;
    const int wv   = tid >> 6;
    const int lane = tid & 63;
    const int lm   = lane & 15, lk = lane >> 4;
    const int wr   = wv >> 1,   wc = wv & 1;

    __shared__ unsigned short As[128 * 64];
    __shared__ unsigned short Bs[128 * 64];

    const int sx = lm & 7;

    f32x4 acc[4][4];
#pragma unroll
    for (int i = 0; i < 4; ++i)
#pragma unroll
        for (int j = 0; j < 4; ++j) acc[i][j] = (f32x4){0.f, 0.f, 0.f, 0.f};

    for (int kt = 0; kt < NT64; ++kt) {
        const int kw = kt << 6;
        const int ka = (kw < K) ? kw : kw - K;
        __syncthreads();
#pragma unroll
        for (int l = 0; l < 4; ++l) {
            const int e   = l * 256 + tid;
            const int row = e >> 3;
            const int cs8 = (((e & 7) ^ (row & 7)) << 3);
            gload_lds16(A  + (size_t)(m0 + row) * KA + ka + cs8, As + e * 8);
            gload_lds16(Wc + (size_t)(n0 + row) * KW + kw + cs8, Bs + e * 8);
        }
        __syncthreads();

#pragma unroll
        for (int kh = 0; kh < 2; ++kh) {
            const int q = ((kh * 4 + lk) ^ sx) * 8;
            bf16x8 af[4], bfr[4];
#pragma unroll
            for (int mi = 0; mi < 4; ++mi)
                af[mi] = *(const bf16x8*)&As[(wr * 64 + mi * 16 + lm) * 64 + q];
#pragma unroll
            for (int nj = 0; nj < 4; ++nj)
                bfr[nj] = *(const bf16x8*)&Bs[(wc * 64 + nj * 16 + lm) * 64 + q];
#pragma unroll
            for (int mi = 0; mi < 4; ++mi)
#pragma unroll
                for (int nj = 0; nj < 4; ++nj)
                    acc[mi][nj] = __builtin_amdgcn_mfma_f32_16x16x32_bf16(
                        af[mi], bfr[nj], acc[mi][nj], 0, 0, 0);
        }
    }

#pragma unroll
    for (int mi = 0; mi < 4; ++mi)
#pragma unroll
        for (int nj = 0; nj < 4; ++nj) {
            const int gn = n0 + wc * 64 + nj * 16 + lm;
            const float bv = bias[gn];
#pragma unroll
            for (int r = 0; r < 4; ++r) {
                const int gm = m0 + wr * 64 + mi * 16 + lk * 4 + r;
                C[(size_t)gm * N + gn] = f2bf_(acc[mi][nj][r] + bv);
            }
        }
}

// ---------------------------------------------------------------------------
// Kernel 6: FF GEMM (1-term) with FUSED logits epilogue (r13-verified).
// ---------------------------------------------------------------------------
__global__ __launch_bounds__(256) void gemm_ff_logits_kernel(
    const unsigned short* __restrict__ A, const unsigned short* __restrict__ Wc,
    const float* __restrict__ bias, const float* __restrict__ w_sbd,
    float* __restrict__ out, int M, int N, int K)
{
    const int KA = K, KW = K;
    const int NT64 = KW >> 6;
    const int ntn  = N >> 7;
    const int id  = blockIdx.x;
    const int cpx = gridDim.x >> 3;
    const int swz = (id & 7) * cpx + (id >> 3);
    const int m0  = (swz / ntn) * 128;
    const int n0  = (swz % ntn) * 128;

    const int tid  = threadIdx.x;
    const int wv   = tid >> 6;
    const int lane = tid & 63;
    const int lm   = lane & 15, lk = lane >> 4;
    const int wr   = wv >> 1,   wc = wv & 1;

    __shared__ unsigned short As[128 * 64];
    __shared__ unsigned short Bs[128 * 64];

    const int sx = lm & 7;

    f32x4 acc[4][4];
#pragma unroll
    for (int i = 0; i < 4; ++i)
#pragma unroll
        for (int j = 0; j < 4; ++j) acc[i][j] = (f32x4){0.f, 0.f, 0.f, 0.f};

    for (int kt = 0; kt < NT64; ++kt) {
        const int kw = kt << 6;
        __syncthreads();
#pragma unroll
        for (int l = 0; l < 4; ++l) {
            const int e   = l * 256 + tid;
            const int row = e >> 3;
            const int cs8 = (((e & 7) ^ (row & 7)) << 3);
            gload_lds16(A  + (size_t)(m0 + row) * KA + kw + cs8, As + e * 8);
            gload_lds16(Wc + (size_t)(n0 + row) * KW + kw + cs8, Bs + e * 8);
        }
        __syncthreads();

#pragma unroll
        for (int kh = 0; kh < 2; ++kh) {
            const int q = ((kh * 4 + lk) ^ sx) * 8;
            bf16x8 af[4], bfr[4];
#pragma unroll
            for (int mi = 0; mi < 4; ++mi)
                af[mi] = *(const bf16x8*)&As[(wr * 64 + mi * 16 + lm) * 64 + q];
#pragma unroll
            for (int nj = 0; nj < 4; ++nj)
                bfr[nj] = *(const bf16x8*)&Bs[(wc * 64 + nj * 16 + lm) * 64 + q];
#pragma unroll
            for (int mi = 0; mi < 4; ++mi)
#pragma unroll
                for (int nj = 0; nj < 4; ++nj)
                    acc[mi][nj] = __builtin_amdgcn_mfma_f32_16x16x32_bf16(
                        af[mi], bfr[nj], acc[mi][nj], 0, 0, 0);
        }
    }

#pragma unroll
    for (int mi = 0; mi < 4; ++mi) {
        float ls0[4] = {0.f, 0.f, 0.f, 0.f};
        float ls1[4] = {0.f, 0.f, 0.f, 0.f};
#pragma unroll
        for (int nj = 0; nj < 4; ++nj) {
            const int gn = n0 + wc * 64 + nj * 16 + lm;
            const float bv = bias[gn];
            const float w0 = w_sbd[gn];
            const float w1 = w_sbd[512 + gn];
#pragma unroll
            for (int r = 0; r < 4; ++r) {
                const float v = fmaxf(acc[mi][nj][r] + bv, 0.0f);
                ls0[r] += v * w0;
                ls1[r] += v * w1;
            }
        }
#pragma unroll
        for (int r = 0; r < 4; ++r) {
            float v0 = ls0[r], v1 = ls1[r];
#pragma unroll
            for (int msk = 1; msk < 16; msk <<= 1) {
                v0 += __shfl_xor(v0, msk);
                v1 += __shfl_xor(v1, msk);
            }
            if (lm == 0) {
                const int gm = m0 + wr * 64 + mi * 16 + lk * 4 + r;
                const int base = (gm >> 7) * 256 + (gm & 127);
                atomicAdd(&out[base], v0);
                atomicAdd(&out[base + 128], v1);
            }
        }
    }
}

// ---------------------------------------------------------------------------
// Kernel 7: swizzle four w_hh into LSTM A-fragment order (r6-verified).
// ---------------------------------------------------------------------------
__global__ __launch_bounds__(256) void wswz_kernel(
    const float* __restrict__ w0, const float* __restrict__ w1,
    const float* __restrict__ w2, const float* __restrict__ w3,
    short* __restrict__ out)
{
    const int idx  = blockIdx.x * 256 + threadIdx.x;
    const int mat  = idx >> 18;
    const int i2   = idx & 262143;
    const int e    = i2 & 7;
    const int l    = (i2 >> 3) & 63;
    const int fr   = (i2 >> 9) & 7;
    const int kt   = (i2 >> 12) & 7;
    const int wv   = (i2 >> 15) & 7;
    const int g    = fr >> 1, s = fr & 1;
    const int n    = g * 256 + wv * 32 + s * 16 + (l & 15);
    const int k    = kt * 32 + ((l >> 4) << 3) + e;
    const float* w = (mat == 0) ? w0 : (mat == 1) ? w1 : (mat == 2) ? w2 : w3;
    out[idx] = (short)f2bf_(w[n * H_ + k]);
}

// ---------------------------------------------------------------------------
// Kernel 8: persistent bidirectional LSTM — byte-identical to the r13/r15-
// verified kernel (485 us, 4 rounds stable).
// ---------------------------------------------------------------------------
__global__ __launch_bounds__(512, 2) void lstm_kernel(
    const unsigned short* __restrict__ xpc,
    const short* __restrict__ wswf, const short* __restrict__ wswb,
    unsigned short* __restrict__ hcat)
{
    const int dir  = blockIdx.x >> 4;
    const int grp  = blockIdx.x & 15;
    const int tid  = threadIdx.x;
    const int wv   = tid >> 6;          // wave 0..7
    const int lane = tid & 63;
    const int lm   = lane & 15;
    const int lk   = lane >> 4;
    const unsigned short* xp = xpc + dir * 1024;
    const short* wsw = dir ? wswb : wswf;
    const int b0 = grp * 16;
    const int b  = lm;                  // this lane's batch column

    __shared__ short lds_w[65536];      // 128 KB: [wv 8][kt2 2][fr 8][512]
    __shared__ short h_lds[2][16 * 256];// 2 x 8 KB, [b][k] bf16, XOR-swizzled

    for (int i = tid; i < 16 * 256 / 2; i += 512) ((int*)h_lds[0])[i] = 0;
#pragma unroll
    for (int kt2 = 0; kt2 < 2; ++kt2)
#pragma unroll
        for (int fr = 0; fr < 8; ++fr) {
            const short* src = wsw + (((wv * 8 + 4 + kt2) * 8 + fr) << 9) + lane * 8;
            gload_lds16(src, &lds_w[((wv * 2 + kt2) * 8 + fr) << 9]);
        }
    bf16x8 awr[4][8];
#pragma unroll
    for (int kt = 0; kt < 4; ++kt)
#pragma unroll
        for (int fr = 0; fr < 8; ++fr)
            awr[kt][fr] = *(const bf16x8*)(wsw + (((wv * 8 + kt) * 8 + fr) << 9) + lane * 8);

    float c_st[2][4];
#pragma unroll
    for (int s = 0; s < 2; ++s)
#pragma unroll
        for (int r = 0; r < 4; ++r) c_st[s][r] = 0.0f;

    int nof[8];
#pragma unroll
    for (int fr = 0; fr < 8; ++fr)
        nof[fr] = (fr >> 1) * 256 + wv * 32 + (fr & 1) * 16 + lk * 4;

    __syncthreads();

    u16x4 xpre[8];
    {
        const int t0 = dir ? (SEQ_ - 1) : 0;
        const unsigned short* xr = xp + ((size_t)(b0 + b) * SEQ_ + t0) * 2048;
#pragma unroll
        for (int fr = 0; fr < 8; ++fr) xpre[fr] = *(const u16x4*)(xr + nof[fr]);
    }

    int cur = 0;
    for (int step = 0; step < SEQ_; ++step) {
        const int t = dir ? (SEQ_ - 1 - step) : step;
        const char* hr = (const char*)h_lds[0] + cur * 8192;
        char*       hw = (char*)h_lds[0] + (cur ^ 1) * 8192;

        f32x4 acc[8];
#pragma unroll
        for (int fr = 0; fr < 8; ++fr)
#pragma unroll
            for (int r = 0; r < 4; ++r) acc[fr][r] = bf2f_(xpre[fr][r]);

        bf16x8 aws6[8];
#pragma unroll
        for (int fr = 0; fr < 8; ++fr)
            aws6[fr] = *(const bf16x8*)(wsw + (((wv * 8 + 6) * 8 + fr) << 9) + lane * 8);

#pragma unroll
        for (int kt = 0; kt < 4; ++kt) {
            const int off = b * 512 + (((kt * 32 + lk * 8) * 2) ^ ((b & 7) << 4));
            const bf16x8 bh = *(const bf16x8*)(hr + off);
#pragma unroll
            for (int fr = 0; fr < 8; ++fr)
                acc[fr] = __builtin_amdgcn_mfma_f32_16x16x32_bf16(
                    awr[kt][fr], bh, acc[fr], 0, 0, 0);
        }

#pragma unroll
        for (int kt2 = 0; kt2 < 2; ++kt2) {
            const int kt = 4 + kt2;
            const int off = b * 512 + (((kt * 32 + lk * 8) * 2) ^ ((b & 7) << 4));
            const bf16x8 bh = *(const bf16x8*)(hr + off);
            bf16x8 al[8];
#pragma unroll
            for (int fr = 0; fr < 8; ++fr)
                al[fr] = *(const bf16x8*)&lds_w[(((wv * 2 + kt2) * 8 + fr) << 9) + lane * 8];
#pragma unroll
            for (int fr = 0; fr < 8; ++fr)
                acc[fr] = __builtin_amdgcn_mfma_f32_16x16x32_bf16(
                    al[fr], bh, acc[fr], 0, 0, 0);
        }

        bf16x8 aws7[8];
#pragma unroll
        for (int fr = 0; fr < 8; ++fr)
            aws7[fr] = *(const bf16x8*)(wsw + (((wv * 8 + 7) * 8 + fr) << 9) + lane * 8);

        {
            const int off = b * 512 + (((6 * 32 + lk * 8) * 2) ^ ((b & 7) << 4));
            const bf16x8 bh = *(const bf16x8*)(hr + off);
#pragma unroll
            for (int fr = 0; fr < 8; ++fr)
                acc[fr] = __builtin_amdgcn_mfma_f32_16x16x32_bf16(
                    aws6[fr], bh, acc[fr], 0, 0, 0);
        }
        {
            const int off = b * 512 + (((7 * 32 + lk * 8) * 2) ^ ((b & 7) << 4));
            const bf16x8 bh = *(const bf16x8*)(hr + off);
#pragma unroll
            for (int fr = 0; fr < 8; ++fr)
                acc[fr] = __builtin_amdgcn_mfma_f32_16x16x32_bf16(
                    aws7[fr], bh, acc[fr], 0, 0, 0);
        }

        {
            const int tn = dir ? (t > 0 ? t - 1 : 0) : (t < SEQ_ - 1 ? t + 1 : t);
            const unsigned short* xr = xp + ((size_t)(b0 + b) * SEQ_ + tn) * 2048;
#pragma unroll
            for (int fr = 0; fr < 8; ++fr) xpre[fr] = *(const u16x4*)(xr + nof[fr]);
        }

#pragma unroll
        for (int s = 0; s < 2; ++s) {
            u16x4 hb;
#pragma unroll
            for (int r = 0; r < 4; ++r) {
                const float iv = sigf_(acc[s][r]);
                const float fv = sigf_(acc[2 + s][r]);
                const float gv = tanhf_(acc[4 + s][r]);
                const float ov = sigf_(acc[6 + s][r]);
                const float c  = fv * c_st[s][r] + iv * gv;
                c_st[s][r] = c;
                hb[r] = f2bf_(ov * tanhf_(c));
            }
            const int j0  = wv * 32 + s * 16 + lk * 4;
            const int off = b * 512 + ((j0 * 2) ^ ((b & 7) << 4));
            *(u16x4*)(hw + off) = hb;
            *(u16x4*)&hcat[((size_t)(b0 + b) * SEQ_ + t) * 512 + dir * 256 + j0] = hb;
        }

        asm volatile("s_waitcnt lgkmcnt(0)" ::: "memory");
        __builtin_amdgcn_s_barrier();
        cur ^= 1;
    }
}

// ---------------------------------------------------------------------------
extern "C" void kernel_launch(void* const* d_in, const int* in_sizes, int n_in,
                              void* d_out, int out_size, void* d_ws, size_t ws_size,
                              hipStream_t stream)
{
    const float* emb   = (const float*)d_in[0];
    const int*   wid   = (const int*)d_in[1];
    const float* w_ih[4] = {(const float*)d_in[2],  (const float*)d_in[6],
                            (const float*)d_in[10], (const float*)d_in[14]};
    const float* w_hh[4] = {(const float*)d_in[3],  (const float*)d_in[7],
                            (const float*)d_in[11], (const float*)d_in[15]};
    const float* b_ih[4] = {(const float*)d_in[4],  (const float*)d_in[8],
                            (const float*)d_in[12], (const float*)d_in[16]};
    const float* b_hh[4] = {(const float*)d_in[5],  (const float*)d_in[9],
                            (const float*)d_in[13], (const float*)d_in[17]};
    const float* w_ff  = (const float*)d_in[18];
    const float* b_ff  = (const float*)d_in[19];
    const float* w_sbd = (const float*)d_in[20];
    const float* b_sbd = (const float*)d_in[21];
    float* out = (float*)d_out;
    char*  ws  = (char*)d_ws;

    const int M = B_ * SEQ_;   // 32768

    const size_t OFF_R1  = 0;
    const size_t OFF_XP  = 100663296;
    const size_t OFF_WC  = OFF_XP + 268435456;
    const size_t OFF_WSW = OFF_WC + 17301504;
    const size_t OFF_BC  = OFF_WSW + 2097152;

    unsigned short* A0   = (unsigned short*)(ws + OFF_R1);
    unsigned short* hcat = (unsigned short*)(ws + OFF_R1);
    unsigned short* xpc  = (unsigned short*)(ws + OFF_XP);
    unsigned short* Wc0  = (unsigned short*)(ws + OFF_WC);      // 2048x768 (1-term)
    unsigned short* Wc1  = Wc0 + (size_t)2048 * 768;            // 2048x512 (1-term)
    unsigned short* Wcff = Wc1 + (size_t)2048 * 512;            // 512x512  (1-term)
    short* wsw  = (short*)(ws + OFF_WSW);
    float* bc0  = (float*)(ws + OFF_BC);
    float* bc1  = bc0 + 2048;

    wswz_kernel<<<4096, 256, 0, stream>>>(w_hh[0], w_hh[1], w_hh[2], w_hh[3], wsw);
    convw_kernel<<<(1024 * 768 + 255) / 256, 256, 0, stream>>>(w_ih[0], Wc0, 1024, 768, 1);
    convw_kernel<<<(1024 * 768 + 255) / 256, 256, 0, stream>>>(w_ih[1], Wc0 + (size_t)1024 * 768, 1024, 768, 1);
    convw_kernel<<<(1024 * 512 + 255) / 256, 256, 0, stream>>>(w_ih[2], Wc1, 1024, 512, 1);
    convw_kernel<<<(1024 * 512 + 255) / 256, 256, 0, stream>>>(w_ih[3], Wc1 + (size_t)1024 * 512, 1024, 512, 1);
    convw_kernel<<<(512 * 512 + 255) / 256, 256, 0, stream>>>(w_ff, Wcff, 512, 512, 1);
    biascat_kernel<<<8, 256, 0, stream>>>(b_ih[0], b_hh[0], b_ih[1], b_hh[1], bc0);
    biascat_kernel<<<8, 256, 0, stream>>>(b_ih[2], b_hh[2], b_ih[3], b_hh[3], bc1);
    outinit_kernel<<<256, 256, 0, stream>>>(b_sbd, out);

    scatter_avg_kernel<<<B_ * 4, 256, 0, stream>>>(emb, wid, A0);

    // layer-0 merged projection (1-term: K=KA=KW=768): [M][2048] bf16
    gemm_bf16_kernel<<<(2048 / 128) * (M / 128), 256, 0, stream>>>(
        A0, Wc0, bc0, xpc, M, 2048, 768, 768, 768);

    lstm_kernel<<<32, 512, 0, stream>>>(xpc, wsw, wsw + 262144, hcat);

    // layer-1 merged projection (1-term: K=KA=KW=512)
    gemm_bf16_kernel<<<(2048 / 128) * (M / 128), 256, 0, stream>>>(
        hcat, Wc1, bc1, xpc, M, 2048, 512, 512, 512);

    lstm_kernel<<<32, 512, 0, stream>>>(xpc, wsw + 2 * 262144, wsw + 3 * 262144, hcat);

    gemm_ff_logits_kernel<<<(512 / 128) * (M / 128), 256, 0, stream>>>(
        hcat, Wcff, b_ff, w_sbd, out, M, 512, 512);
}